// Round 6
// baseline (728.455 us; speedup 1.0000x reference)
//
#include <hip/hip_runtime.h>

typedef unsigned short u16;
typedef __attribute__((ext_vector_type(8))) short s8v;
typedef __attribute__((ext_vector_type(4))) float f4v;

#define DEV static __device__ __forceinline__

DEV u16 f2bf(float f) {
  union { float f; unsigned u; } v; v.f = f;
  unsigned r = v.u + 0x7FFFu + ((v.u >> 16) & 1u);
  return (u16)(r >> 16);
}
DEV float bf2f(u16 b) { union { unsigned u; float f; } v; v.u = ((unsigned)b) << 16; return v.f; }

DEV f4v mfma16(s8v a, s8v b, f4v c) {
  return __builtin_amdgcn_mfma_f32_16x16x32_bf16(a, b, c, 0, 0, 0);
}

// ---------------- transpose + cast ----------------
// in: [z][R][C] f32  -> out: [z][C][R] bf16
__global__ __launch_bounds__(256) void transpose_cast(const float* __restrict__ in,
                                                      u16* __restrict__ out, int R, int C) {
  __shared__ float tile[32][33];
  int z = blockIdx.z;
  const float* inp = in + (size_t)z * R * C;
  u16* op = out + (size_t)z * R * C;
  int c0 = blockIdx.x * 32, r0 = blockIdx.y * 32;
  int tx = threadIdx.x & 31, ty = threadIdx.x >> 5;
  for (int i = ty; i < 32; i += 8) {
    int r = r0 + i, c = c0 + tx;
    tile[i][tx] = (r < R && c < C) ? inp[(size_t)r * C + c] : 0.f;
  }
  __syncthreads();
  for (int i = ty; i < 32; i += 8) {
    int c = c0 + i, r = r0 + tx;
    if (c < C && r < R) op[(size_t)c * R + r] = f2bf(tile[tx][i]);
  }
}

__global__ __launch_bounds__(256) void transpose_cast_split(const float* __restrict__ in,
                                                            u16* __restrict__ outH, u16* __restrict__ outL,
                                                            int R, int C) {
  __shared__ float tile[32][33];
  int z = blockIdx.z;
  const float* inp = in + (size_t)z * R * C;
  u16* oH = outH + (size_t)z * R * C;
  u16* oL = outL + (size_t)z * R * C;
  int c0 = blockIdx.x * 32, r0 = blockIdx.y * 32;
  int tx = threadIdx.x & 31, ty = threadIdx.x >> 5;
  for (int i = ty; i < 32; i += 8) {
    int r = r0 + i, c = c0 + tx;
    tile[i][tx] = (r < R && c < C) ? inp[(size_t)r * C + c] : 0.f;
  }
  __syncthreads();
  for (int i = ty; i < 32; i += 8) {
    int c = c0 + i, r = r0 + tx;
    if (c < C && r < R) {
      float f = tile[tx][i];
      u16 hi = f2bf(f);
      oH[(size_t)c * R + r] = hi;
      oL[(size_t)c * R + r] = f2bf(f - bf2f(hi));
    }
  }
}

// ---------------- rmsnorm ----------------
__global__ __launch_bounds__(256) void rmsnorm_kernel(const float* __restrict__ xin,
                                                      const float* __restrict__ w,
                                                      u16* __restrict__ outH, u16* __restrict__ outL,
                                                      float* __restrict__ outF) {
  int n = blockIdx.x;
  int t = threadIdx.x;
  const float* xr = xin + (size_t)n * 1024;
  float4 v = ((const float4*)xr)[t];
  float ss = v.x*v.x + v.y*v.y + v.z*v.z + v.w*v.w;
  #pragma unroll
  for (int o = 1; o < 64; o <<= 1) ss += __shfl_xor(ss, o, 64);
  __shared__ float wsum[4];
  if ((t & 63) == 0) wsum[t >> 6] = ss;
  __syncthreads();
  float tot = wsum[0] + wsum[1] + wsum[2] + wsum[3];
  float rs = rsqrtf(tot * (1.0f/1024.0f) + 1e-6f);
  float4 wv = ((const float4*)w)[t];
  float o0 = v.x*rs*wv.x, o1 = v.y*rs*wv.y, o2 = v.z*rs*wv.z, o3 = v.w*rs*wv.w;
  if (outF) {
    float4 of = {o0, o1, o2, o3};
    ((float4*)(outF + (size_t)n*1024))[t] = of;
  }
  u16 h0 = f2bf(o0), h1 = f2bf(o1), h2 = f2bf(o2), h3 = f2bf(o3);
  ushort4 oh = {h0, h1, h2, h3};
  ((ushort4*)(outH + (size_t)n*1024))[t] = oh;
  if (outL) {
    ushort4 ol = { f2bf(o0 - bf2f(h0)), f2bf(o1 - bf2f(h1)),
                   f2bf(o2 - bf2f(h2)), f2bf(o3 - bf2f(h3)) };
    ((ushort4*)(outL + (size_t)n*1024))[t] = ol;
  }
}

// ---------------- generic GEMM: C[M][N](f32) = A[M][K](bf16) x BT[N][K](bf16)^T ----------------
// SPLIT: A,B hi/lo planes; acc = Ah*Bh + Ah*Bl + Al*Bh.
// BM: M-tile (64 or 128). BN=64, BK=64, 256 threads / 4 waves.
// BM=128: each wave owns 32x64 output (2 row-fragments) -> 2x MFMA per
// A-fragment read, half the barrier-steps per FLOP vs BM=64. Used where the
// grid stays >=256 blocks; BM=64 kept for small-N GEMMs.
// T14 async staging: global loads for K-tile t+1 issued into registers before
// the MFMA phase of tile t, ds_written after the read-barrier.
// counts!=null: MoE mode (blockIdx.z = expert).
template <bool SPLIT, int BM>
__global__ __launch_bounds__(256) void gemm_kernel(
    const u16* __restrict__ Ah, const u16* __restrict__ Al,
    const u16* __restrict__ Bh, const u16* __restrict__ Bl,
    float* __restrict__ C, const float* __restrict__ resid,
    const int* __restrict__ rowIdx, const int* __restrict__ counts,
    const int* __restrict__ offsets,
    int M, int N, int K, int strideBTe) {
  constexpr int RF = BM / 64;  // row-fragments per wave (1 or 2)
  int M_ = M;
  const int* rIdx = rowIdx;
  int aOff = 0;
  if (counts) {
    int e = blockIdx.z;
    M_ = counts[e];
    if ((int)blockIdx.y * BM >= M_) return;
    aOff = offsets[e];
    Bh += (size_t)e * strideBTe;
    C += (size_t)aOff * N;
    if (rIdx) rIdx += aOff;
  }
  __shared__ u16 AtH[BM*72];
  __shared__ u16 BtH[64*72];
  __shared__ u16 AtL[SPLIT ? BM*72 : 8];
  __shared__ u16 BtL[SPLIT ? 64*72 : 8];

  int tid = threadIdx.x;
  int wid = tid >> 6, lane = tid & 63;
  int lo16 = lane & 15, hi4 = lane >> 4;
  int m0 = blockIdx.y * BM, n0 = blockIdx.x * 64;

  // staging geometry: thread stages A row arowS cols [acolS, acolS+16*RF),
  // B row browS cols [bcolS, bcolS+16).
  int arowS, acolS;
  if constexpr (BM == 64) { arowS = tid >> 2; acolS = (tid & 3) * 16; }
  else                    { arowS = tid >> 1; acolS = (tid & 1) * 32; }
  int browS = tid >> 2, bcolS = (tid & 3) * 16;

  int am = m0 + arowS;
  int arow;
  if (counts) {
    int mm = (am < M_) ? am : (M_ - 1);
    arow = rIdx ? rIdx[mm] : (aOff + mm);
  } else {
    arow = am;
  }
  const u16* aPH = Ah + (size_t)arow * K + acolS;
  const u16* aPL = SPLIT ? (Al + (size_t)arow * K + acolS) : nullptr;
  const u16* bPH = Bh + (size_t)(n0 + browS) * K + bcolS;
  const u16* bPL = SPLIT ? (Bl + (size_t)(n0 + browS) * K + bcolS) : nullptr;

  // prefetch registers (one K-tile ahead)
  uint4 aR[2*RF], bR[2];
  uint4 alR[SPLIT ? 2*RF : 1], blR[SPLIT ? 2 : 1];
  auto GLOAD = [&](int kb) {
    #pragma unroll
    for (int i = 0; i < 2*RF; ++i) aR[i] = *(const uint4*)(aPH + kb + 8*i);
    #pragma unroll
    for (int i = 0; i < 2; ++i) bR[i] = *(const uint4*)(bPH + kb + 8*i);
    if constexpr (SPLIT) {
      #pragma unroll
      for (int i = 0; i < 2*RF; ++i) alR[i] = *(const uint4*)(aPL + kb + 8*i);
      #pragma unroll
      for (int i = 0; i < 2; ++i) blR[i] = *(const uint4*)(bPL + kb + 8*i);
    }
  };
  auto GSTORE = [&]() {
    #pragma unroll
    for (int i = 0; i < 2*RF; ++i) *(uint4*)&AtH[arowS*72 + acolS + 8*i] = aR[i];
    #pragma unroll
    for (int i = 0; i < 2; ++i) *(uint4*)&BtH[browS*72 + bcolS + 8*i] = bR[i];
    if constexpr (SPLIT) {
      #pragma unroll
      for (int i = 0; i < 2*RF; ++i) *(uint4*)&AtL[arowS*72 + acolS + 8*i] = alR[i];
      #pragma unroll
      for (int i = 0; i < 2; ++i) *(uint4*)&BtL[browS*72 + bcolS + 8*i] = blR[i];
    }
  };

  f4v acc[RF][4];
  #pragma unroll
  for (int rf = 0; rf < RF; ++rf)
    #pragma unroll
    for (int j = 0; j < 4; ++j) { acc[rf][j][0]=0.f; acc[rf][j][1]=0.f; acc[rf][j][2]=0.f; acc[rf][j][3]=0.f; }

  GLOAD(0); GSTORE();
  for (int kb = 0; kb < K; kb += 64) {
    __syncthreads();                  // staged tile visible
    if (kb + 64 < K) GLOAD(kb + 64);  // prefetch next tile under this tile's MFMAs
    s8v ah[RF][2], al[RF][2];
    #pragma unroll
    for (int rf = 0; rf < RF; ++rf) {
      int ar = wid*(16*RF) + rf*16 + lo16;
      ah[rf][0] = *(const s8v*)&AtH[ar*72 + 8*hi4];
      ah[rf][1] = *(const s8v*)&AtH[ar*72 + 32 + 8*hi4];
      if constexpr (SPLIT) {
        al[rf][0] = *(const s8v*)&AtL[ar*72 + 8*hi4];
        al[rf][1] = *(const s8v*)&AtL[ar*72 + 32 + 8*hi4];
      }
    }
    #pragma unroll
    for (int j = 0; j < 4; ++j) {
      int br = j*16 + lo16;
      s8v bh0 = *(const s8v*)&BtH[br*72 + 8*hi4];
      s8v bh1 = *(const s8v*)&BtH[br*72 + 32 + 8*hi4];
      s8v bl0, bl1;
      if constexpr (SPLIT) {
        bl0 = *(const s8v*)&BtL[br*72 + 8*hi4];
        bl1 = *(const s8v*)&BtL[br*72 + 32 + 8*hi4];
      }
      #pragma unroll
      for (int rf = 0; rf < RF; ++rf) {
        acc[rf][j] = mfma16(ah[rf][0], bh0, acc[rf][j]);
        acc[rf][j] = mfma16(ah[rf][1], bh1, acc[rf][j]);
        if constexpr (SPLIT) {
          acc[rf][j] = mfma16(ah[rf][0], bl0, acc[rf][j]);
          acc[rf][j] = mfma16(ah[rf][1], bl1, acc[rf][j]);
          acc[rf][j] = mfma16(al[rf][0], bh0, acc[rf][j]);
          acc[rf][j] = mfma16(al[rf][1], bh1, acc[rf][j]);
        }
      }
    }
    __syncthreads();                  // all waves done reading LDS
    if (kb + 64 < K) GSTORE();        // write next tile (vmcnt drained under MFMAs)
  }
  #pragma unroll
  for (int rf = 0; rf < RF; ++rf) {
    #pragma unroll
    for (int r = 0; r < 4; ++r) {
      int rg = m0 + wid*(16*RF) + rf*16 + 4*hi4 + r;
      if (rg < M_) {
        size_t rb = (size_t)rg * N;
        #pragma unroll
        for (int j = 0; j < 4; ++j) {
          int cg = n0 + j*16 + lo16;
          float v = acc[rf][j][r];
          if (resid) v += resid[rb + cg];
          C[rb + cg] = v;
        }
      }
    }
  }
}

// ---------------- RoPE (f32 -> split bf16, [b][NH][t][64] layout) ----------------
__global__ __launch_bounds__(256) void rope_split_kernel(const float* __restrict__ src, int ldsrc, int colOff,
                                                         const float* __restrict__ fc, const float* __restrict__ fs,
                                                         u16* __restrict__ outH, u16* __restrict__ outL, int NH) {
  int idx = blockIdx.x * 256 + threadIdx.x;
  int i = idx & 31; int tmp = idx >> 5;
  int hh = tmp % NH; int bt = tmp / NH;
  if (bt >= 2048) return;
  int t = bt & 1023, b = bt >> 10;
  const float* sp = src + (size_t)bt * ldsrc + colOff + hh*64 + 2*i;
  float a = sp[0], bb = sp[1];
  float c = fc[t*32 + i], s = fs[t*32 + i];
  float o0 = a*c - bb*s, o1 = a*s + bb*c;
  size_t o = (((size_t)(b*NH + hh))*1024 + t)*64 + 2*i;
  u16 h0 = f2bf(o0), h1 = f2bf(o1);
  outH[o] = h0; outH[o+1] = h1;
  outL[o] = f2bf(o0 - bf2f(h0)); outL[o+1] = f2bf(o1 - bf2f(h1));
}

// ---------------- V transpose (f32 -> split bf16, [b][kv][hd][t]) ----------------
__global__ __launch_bounds__(256) void vtrans_split_kernel(const float* __restrict__ src, int ldsrc, int colOff,
                                                           u16* __restrict__ outH, u16* __restrict__ outL) {
  int idx = blockIdx.x * 256 + threadIdx.x;
  if (idx >= 2*4*64*1024) return;
  int t = idx & 1023; int tmp = idx >> 10;
  int hd = tmp & 63; int kv = (tmp >> 6) & 3; int b = tmp >> 8;
  float f = src[(size_t)(b*1024 + t) * ldsrc + colOff + kv*64 + hd];
  u16 hi = f2bf(f);
  outH[idx] = hi; outL[idx] = f2bf(f - bf2f(hi));
}

// ---------------- flash attention (causal, GQA, split-bf16) ----------------
// LDS-staged K/V; complement qb mapping for XCD causal balance; T14 async
// staging (load t+1 into regs before compute of t, ds_write after barrier);
// base-2 softmax; diagonal-only masking; setprio around MFMA clusters.
__global__ __launch_bounds__(256) void attn_kernel(
    const u16* __restrict__ Qh, const u16* __restrict__ Ql,
    const u16* __restrict__ Kh_, const u16* __restrict__ Kl_,
    const u16* __restrict__ Vh_, const u16* __restrict__ Vl_,
    u16* __restrict__ Oh, u16* __restrict__ Ol) {
  int b = blockIdx.z, h = blockIdx.y;
  int qb = (b == 0) ? (int)blockIdx.x : (15 - (int)blockIdx.x);
  int kv = h >> 2;
  size_t qoff = ((size_t)(b*16 + h)) * 65536;
  size_t koff = ((size_t)(b*4 + kv)) * 65536;

  __shared__ u16 KtH[64*72], KtL[64*72], VtH[64*72], VtL[64*72];
  __shared__ u16 PtH[4][16*72], PtL[4][16*72];

  int tid = threadIdx.x, wid = tid >> 6, lane = tid & 63;
  int lo16 = lane & 15, hi4 = lane >> 4;
  int srow = tid >> 2, sseg = (tid & 3) * 16;

  int qrow = qb*64 + wid*16 + lo16;
  const u16* qbh_ = Qh + qoff + (size_t)qrow*64;
  const u16* qbl_ = Ql + qoff + (size_t)qrow*64;
  s8v qh0 = *(const s8v*)(qbh_ + 8*hi4);
  s8v qh1 = *(const s8v*)(qbh_ + 32 + 8*hi4);
  s8v ql0 = *(const s8v*)(qbl_ + 8*hi4);
  s8v ql1 = *(const s8v*)(qbl_ + 32 + 8*hi4);

  const u16* Kh = Kh_ + koff;
  const u16* Kl = Kl_ + koff;
  const u16* Vh = Vh_ + koff;
  const u16* Vl = Vl_ + koff;

  // one-tile-ahead register staging
  uint4 kh0r, kh1r, kl0r, kl1r, vh0r, vh1r, vl0r, vl1r;
  #define LOADT(kb) { \
    const u16* kh = Kh + (size_t)((kb)*64 + srow)*64 + sseg; \
    const u16* kl = Kl + (size_t)((kb)*64 + srow)*64 + sseg; \
    const u16* vh = Vh + (size_t)srow*1024 + (kb)*64 + sseg; \
    const u16* vl = Vl + (size_t)srow*1024 + (kb)*64 + sseg; \
    kh0r = *(const uint4*)(kh); kh1r = *(const uint4*)(kh + 8); \
    kl0r = *(const uint4*)(kl); kl1r = *(const uint4*)(kl + 8); \
    vh0r = *(const uint4*)(vh); vh1r = *(const uint4*)(vh + 8); \
    vl0r = *(const uint4*)(vl); vl1r = *(const uint4*)(vl + 8); }
  #define STORET() { \
    *(uint4*)&KtH[srow*72 + sseg]     = kh0r; *(uint4*)&KtH[srow*72 + sseg + 8] = kh1r; \
    *(uint4*)&KtL[srow*72 + sseg]     = kl0r; *(uint4*)&KtL[srow*72 + sseg + 8] = kl1r; \
    *(uint4*)&VtH[srow*72 + sseg]     = vh0r; *(uint4*)&VtH[srow*72 + sseg + 8] = vh1r; \
    *(uint4*)&VtL[srow*72 + sseg]     = vl0r; *(uint4*)&VtL[srow*72 + sseg + 8] = vl1r; }

  f4v oacc[4];
  #pragma unroll
  for (int j = 0; j < 4; ++j) { oacc[j][0]=0.f; oacc[j][1]=0.f; oacc[j][2]=0.f; oacc[j][3]=0.f; }
  float mrow[4] = {-1e30f, -1e30f, -1e30f, -1e30f};
  float lrow[4] = {0.f, 0.f, 0.f, 0.f};
  int qmy = qb*64 + wid*16 + 4*hi4;
  u16* PwH = PtH[wid];
  u16* PwL = PtL[wid];

  // base-2 softmax: scores scaled by 1/sqrt(64)*log2(e); exp2f = 1 v_exp_f32
  const float SC = 0.125f * 1.44269504088896f;

  LOADT(0); STORET();
  for (int kblk = 0; kblk <= qb; ++kblk) {
    __syncthreads();                 // staged tile visible to all waves
    if (kblk < qb) LOADT(kblk + 1);  // prefetch next tile under this tile's compute

    // ---- S = Q K^T ----
    f4v sfr[4];
    __builtin_amdgcn_s_setprio(1);
    #pragma unroll
    for (int j = 0; j < 4; ++j) {
      int kr = j*16 + lo16;
      s8v kh0 = *(const s8v*)&KtH[kr*72 + 8*hi4];
      s8v kh1 = *(const s8v*)&KtH[kr*72 + 32 + 8*hi4];
      s8v kl0 = *(const s8v*)&KtL[kr*72 + 8*hi4];
      s8v kl1 = *(const s8v*)&KtL[kr*72 + 32 + 8*hi4];
      f4v s; s[0]=0.f; s[1]=0.f; s[2]=0.f; s[3]=0.f;
      s = mfma16(qh0, kh0, s);
      s = mfma16(qh1, kh1, s);
      s = mfma16(qh0, kl0, s);
      s = mfma16(qh1, kl1, s);
      s = mfma16(ql0, kh0, s);
      s = mfma16(ql1, kh1, s);
      sfr[j] = s;
    }
    __builtin_amdgcn_s_setprio(0);

    // ---- online softmax (base-2); mask only the diagonal tile ----
    bool diag = (kblk == qb);
    float scl[4];
    #pragma unroll
    for (int r = 0; r < 4; ++r) {
      int qr = qmy + r;
      #pragma unroll
      for (int j = 0; j < 4; ++j) {
        float v = sfr[j][r] * SC;
        if (diag) {
          int kc = kblk*64 + j*16 + lo16;
          v = (kc > qr) ? -1e30f : v;
        }
        sfr[j][r] = v;
      }
      float mx = fmaxf(fmaxf(sfr[0][r], sfr[1][r]), fmaxf(sfr[2][r], sfr[3][r]));
      #pragma unroll
      for (int o = 1; o < 16; o <<= 1) mx = fmaxf(mx, __shfl_xor(mx, o, 64));
      float mnew = fmaxf(mrow[r], mx);
      scl[r] = exp2f(mrow[r] - mnew);
      mrow[r] = mnew;
      float sum = 0.f;
      #pragma unroll
      for (int j = 0; j < 4; ++j) {
        float pv = exp2f(sfr[j][r] - mnew);
        sfr[j][r] = pv;
        sum += pv;
      }
      #pragma unroll
      for (int o = 1; o < 16; o <<= 1) sum += __shfl_xor(sum, o, 64);
      lrow[r] = lrow[r] * scl[r] + sum;
    }
    #pragma unroll
    for (int j = 0; j < 4; ++j) {
      #pragma unroll
      for (int r = 0; r < 4; ++r) oacc[j][r] *= scl[r];
    }

    // ---- P transpose through per-wave LDS (split bf16) ----
    #pragma unroll
    for (int r = 0; r < 4; ++r) {
      #pragma unroll
      for (int j = 0; j < 4; ++j) {
        float pv = sfr[j][r];
        u16 hi = f2bf(pv);
        PwH[(4*hi4 + r)*72 + j*16 + lo16] = hi;
        PwL[(4*hi4 + r)*72 + j*16 + lo16] = f2bf(pv - bf2f(hi));
      }
    }
    asm volatile("s_waitcnt lgkmcnt(0)" ::: "memory");
    s8v ph0 = *(const s8v*)&PwH[lo16*72 + 8*hi4];
    s8v ph1 = *(const s8v*)&PwH[lo16*72 + 32 + 8*hi4];
    s8v pl0 = *(const s8v*)&PwL[lo16*72 + 8*hi4];
    s8v pl1 = *(const s8v*)&PwL[lo16*72 + 32 + 8*hi4];

    // ---- O += P V ----
    __builtin_amdgcn_s_setprio(1);
    #pragma unroll
    for (int j = 0; j < 4; ++j) {
      int vr = j*16 + lo16;
      s8v vh0 = *(const s8v*)&VtH[vr*72 + 8*hi4];
      s8v vh1 = *(const s8v*)&VtH[vr*72 + 32 + 8*hi4];
      s8v vl0 = *(const s8v*)&VtL[vr*72 + 8*hi4];
      s8v vl1 = *(const s8v*)&VtL[vr*72 + 32 + 8*hi4];
      oacc[j] = mfma16(ph0, vh0, oacc[j]);
      oacc[j] = mfma16(ph1, vh1, oacc[j]);
      oacc[j] = mfma16(ph0, vl0, oacc[j]);
      oacc[j] = mfma16(ph1, vl1, oacc[j]);
      oacc[j] = mfma16(pl0, vh0, oacc[j]);
      oacc[j] = mfma16(pl1, vh1, oacc[j]);
    }
    __builtin_amdgcn_s_setprio(0);

    __syncthreads();                 // all waves done reading K/V LDS
    if (kblk < qb) STORET();         // vmcnt mostly drained by now
  }
  #undef LOADT
  #undef STORET

  #pragma unroll
  for (int r = 0; r < 4; ++r) {
    float inv = 1.f / lrow[r];
    int tq = qb*64 + wid*16 + 4*hi4 + r;
    size_t base = ((size_t)(b*1024 + tq))*1024 + h*64;
    #pragma unroll
    for (int j = 0; j < 4; ++j) {
      float ov = oacc[j][r] * inv;
      u16 hi = f2bf(ov);
      Oh[base + j*16 + lo16] = hi;
      Ol[base + j*16 + lo16] = f2bf(ov - bf2f(hi));
    }
  }
}

// ---------------- router: logits(fp32) -> softmax -> top4 ----------------
// LDS-tiled: 256 blocks x 8 rows; h rows (32KB) + rw chunks (16KB) staged via
// coalesced float4; inner loop pure LDS+FMA (conflict-free). R4: 58 -> ~8us.
__global__ __launch_bounds__(256) void router_kernel(const float* __restrict__ h2,
                                                     const float* __restrict__ rw,
                                                     int* __restrict__ topIdx, float* __restrict__ topW,
                                                     int* __restrict__ counts) {
  __shared__ float hs[8*1024];    // 8 h rows
  __shared__ float rws[128*32];   // rw chunk [128 d][32 e]
  __shared__ int hist[32];
  int t = threadIdx.x;
  int row0 = blockIdx.x * 8;
  if (t < 32) hist[t] = 0;

  // stage 8 h rows: 2048 float4, coalesced
  {
    const float4* hsrc = (const float4*)(h2 + (size_t)row0 * 1024);
    float4* hdst = (float4*)hs;
    #pragma unroll
    for (int i = 0; i < 8; ++i) hdst[t + 256*i] = hsrc[t + 256*i];
  }

  int e = t & 31, rq = t >> 5;    // thread owns (row rq, expert e); 32-lane group = one row
  float acc = 0.f;
  for (int c = 0; c < 8; ++c) {
    __syncthreads();              // prev chunk fully consumed (and h staged, 1st iter)
    const float4* rsrc = (const float4*)(rw + (size_t)c * 4096);
    float4* rdst = (float4*)rws;
    #pragma unroll
    for (int i = 0; i < 4; ++i) rdst[t + 256*i] = rsrc[t + 256*i];
    __syncthreads();
    const float* hp = hs + rq*1024 + c*128;
    float b0 = 0.f, b1 = 0.f, b2 = 0.f, b3 = 0.f;
    #pragma unroll
    for (int d = 0; d < 128; d += 4) {
      b0 += hp[d+0] * rws[(d+0)*32 + e];
      b1 += hp[d+1] * rws[(d+1)*32 + e];
      b2 += hp[d+2] * rws[(d+2)*32 + e];
      b3 += hp[d+3] * rws[(d+3)*32 + e];
    }
    acc += (b0 + b1) + (b2 + b3);
  }

  // softmax over the 32-lane group (xor offsets <32 stay within the group)
  float mx = acc;
  #pragma unroll
  for (int o = 1; o < 32; o <<= 1) mx = fmaxf(mx, __shfl_xor(mx, o, 64));
  float ex = expf(acc - mx);
  float sm = ex;
  #pragma unroll
  for (int o = 1; o < 32; o <<= 1) sm += __shfl_xor(sm, o, 64);
  float prob = ex / sm;

  // top-4 within the group; tie -> smaller index (matches jax top_k)
  float pv = prob; int pi = e;
  int myRow = row0 + rq;
  for (int k = 0; k < 4; ++k) {
    float bv = pv; int bi = pi;
    #pragma unroll
    for (int o = 1; o < 32; o <<= 1) {
      float ov = __shfl_xor(bv, o, 64); int oi = __shfl_xor(bi, o, 64);
      if (ov > bv || (ov == bv && oi < bi)) { bv = ov; bi = oi; }
    }
    if (e == 0) {
      topIdx[myRow*4 + k] = bi; topW[myRow*4 + k] = bv;
      atomicAdd(&hist[bi], 1);   // LDS atomic
    }
    if (pi == bi) pv = -1.f;
  }
  __syncthreads();
  if (t < 32 && hist[t] > 0) atomicAdd(&counts[t], hist[t]);
}

__global__ void zero_counts(int* counts) { if (threadIdx.x < 32) counts[threadIdx.x] = 0; }

__global__ void scan_kernel(const int* __restrict__ counts, int* __restrict__ offsets, int* __restrict__ cursor) {
  if (threadIdx.x == 0) {
    int acc = 0;
    for (int e = 0; e < 32; ++e) { offsets[e] = acc; cursor[e] = acc; acc += counts[e]; }
    offsets[32] = acc;
  }
}

__global__ __launch_bounds__(256) void scatter_kernel(const int* __restrict__ topIdx, const float* __restrict__ topW,
                                                      int* __restrict__ cursor, int* __restrict__ rows,
                                                      float* __restrict__ wtp, int* __restrict__ pslot) {
  int i = blockIdx.x * 256 + threadIdx.x;
  if (i >= 2048*4) return;
  int e = topIdx[i];
  int slot = atomicAdd(&cursor[e], 1);
  rows[slot] = i >> 2;
  wtp[slot] = topW[i];
  pslot[i] = slot;
}

// ---------------- silu(g)*u [* wt_per_row256] -> bf16 ----------------
__global__ __launch_bounds__(256) void silu_mul_kernel(const float* __restrict__ g, const float* __restrict__ u,
                                                       const float* __restrict__ wtp, u16* __restrict__ out, int total) {
  int i = blockIdx.x * 256 + threadIdx.x;
  if (i >= total) return;
  float gv = g[i], uv = u[i];
  float s = gv / (1.f + expf(-gv));
  float r = s * uv;
  if (wtp) r *= wtp[i >> 8];
  out[i] = f2bf(r);
}

// ---------------- final: out = x1 + shared + sum_k pairOut[slot_k] ----------------
__global__ __launch_bounds__(256) void final_kernel(const float* __restrict__ x1, const float* __restrict__ shOut,
                                                    const float* __restrict__ pairOut, const int* __restrict__ pslot,
                                                    float* __restrict__ out) {
  int n = blockIdx.x;
  int t = threadIdx.x;
  int s0 = pslot[n*4], s1 = pslot[n*4+1], s2 = pslot[n*4+2], s3 = pslot[n*4+3];
  float4 a  = ((const float4*)(x1 + (size_t)n*1024))[t];
  float4 sh = ((const float4*)(shOut + (size_t)n*1024))[t];
  float4 p0 = ((const float4*)(pairOut + (size_t)s0*1024))[t];
  float4 p1 = ((const float4*)(pairOut + (size_t)s1*1024))[t];
  float4 p2 = ((const float4*)(pairOut + (size_t)s2*1024))[t];
  float4 p3 = ((const float4*)(pairOut + (size_t)s3*1024))[t];
  float4 o;
  o.x = a.x + sh.x + p0.x + p1.x + p2.x + p3.x;
  o.y = a.y + sh.y + p0.y + p1.y + p2.y + p3.y;
  o.z = a.z + sh.z + p0.z + p1.z + p2.z + p3.z;
  o.w = a.w + sh.w + p0.w + p1.w + p2.w + p3.w;
  ((float4*)(out + (size_t)n*1024))[t] = o;
}

// ---------------- host ----------------
extern "C" void kernel_launch(void* const* d_in, const int* in_sizes, int n_in,
                              void* d_out, int out_size, void* d_ws, size_t ws_size,
                              hipStream_t stream) {
  const float* x   = (const float*)d_in[0];
  const float* fc  = (const float*)d_in[1];
  const float* fs  = (const float*)d_in[2];
  const float* n1w = (const float*)d_in[3];
  const float* n2w = (const float*)d_in[4];
  const float* wq  = (const float*)d_in[5];
  const float* wk  = (const float*)d_in[6];
  const float* wv  = (const float*)d_in[7];
  const float* wo  = (const float*)d_in[8];
  const float* rw  = (const float*)d_in[9];
  const float* wg  = (const float*)d_in[10];
  const float* wu  = (const float*)d_in[11];
  const float* wd  = (const float*)d_in[12];
  const float* shg = (const float*)d_in[13];
  const float* shu = (const float*)d_in[14];
  const float* shd = (const float*)d_in[15];
  float* out = (float*)d_out;
  (void)in_sizes; (void)n_in; (void)out_size;

  char* p = (char*)d_ws;
  auto alloc = [&](size_t n) { char* r = p; p += (n + 255) & ~(size_t)255; return r; };

  u16* wqkvTh = (u16*)alloc((size_t)1536*1024*2);
  u16* wqkvTl = (u16*)alloc((size_t)1536*1024*2);
  u16* woTh   = (u16*)alloc((size_t)1024*1024*2);
  u16* woTl   = (u16*)alloc((size_t)1024*1024*2);
  u16* shgT   = (u16*)alloc((size_t)512*1024*2);
  u16* shuT   = (u16*)alloc((size_t)512*1024*2);
  u16* shdT   = (u16*)alloc((size_t)1024*512*2);
  u16* wgT    = (u16*)alloc((size_t)32*256*1024*2);
  u16* wuT    = (u16*)alloc((size_t)32*256*1024*2);
  u16* wdT    = (u16*)alloc((size_t)32*1024*256*2);
  u16* hH     = (u16*)alloc((size_t)2048*1024*2);
  u16* hL     = (u16*)alloc((size_t)2048*1024*2);
  float* x1   = (float*)alloc((size_t)2048*1024*4);
  float* h2f  = (float*)alloc((size_t)2048*1024*4);
  u16* h2b    = (u16*)alloc((size_t)2048*1024*2);
  float* pairG = (float*)alloc((size_t)8192*256*4);
  float* pairU = (float*)alloc((size_t)8192*256*4);
  u16* actb   = (u16*)alloc((size_t)8192*256*2);
  float* sg   = (float*)alloc((size_t)2048*512*4);
  float* su   = (float*)alloc((size_t)2048*512*4);
  u16* sactb  = (u16*)alloc((size_t)2048*512*2);
  float* shOut = (float*)alloc((size_t)2048*1024*4);
  int* topIdx = (int*)alloc(2048*4*4);
  float* topW = (float*)alloc(2048*4*4);
  int* counts = (int*)alloc(32*4);
  int* offsets = (int*)alloc(33*4);
  int* cursor = (int*)alloc(32*4);
  int* rows   = (int*)alloc(8192*4);
  float* wtp  = (float*)alloc(8192*4);
  int* pslot  = (int*)alloc(8192*4);
  // alias region: qkv/rope/attention temporaries, later reused as pairOut
  char* regionStart = p;
  float* qkvf = (float*)alloc((size_t)2048*1536*4);
  u16* qbh = (u16*)alloc((size_t)2048*1024*2);
  u16* qbl = (u16*)alloc((size_t)2048*1024*2);
  u16* kbh = (u16*)alloc((size_t)524288*2);
  u16* kbl = (u16*)alloc((size_t)524288*2);
  u16* vth = (u16*)alloc((size_t)524288*2);
  u16* vtl = (u16*)alloc((size_t)524288*2);
  u16* attnH = (u16*)alloc((size_t)2048*1024*2);
  u16* attnL = (u16*)alloc((size_t)2048*1024*2);
  float* pairOut = (float*)regionStart;  // 32MB, region is exactly 32MB

  size_t needed = (size_t)(p - (char*)d_ws);
  if (needed > ws_size) return;  // insufficient workspace; fail clean

  dim3 blk(256);
  // weight transposes (+bf16 cast; split for pre-router path)
  transpose_cast_split<<<dim3(32,32,1), blk, 0, stream>>>(wq, wqkvTh, wqkvTl, 1024, 1024);
  transpose_cast_split<<<dim3(8,32,1),  blk, 0, stream>>>(wk, wqkvTh + (size_t)1024*1024, wqkvTl + (size_t)1024*1024, 1024, 256);
  transpose_cast_split<<<dim3(8,32,1),  blk, 0, stream>>>(wv, wqkvTh + (size_t)1280*1024, wqkvTl + (size_t)1280*1024, 1024, 256);
  transpose_cast_split<<<dim3(32,32,1), blk, 0, stream>>>(wo, woTh, woTl, 1024, 1024);
  transpose_cast<<<dim3(16,32,1), blk, 0, stream>>>(shg, shgT, 1024, 512);
  transpose_cast<<<dim3(16,32,1), blk, 0, stream>>>(shu, shuT, 1024, 512);
  transpose_cast<<<dim3(32,16,1), blk, 0, stream>>>(shd, shdT, 512, 1024);
  transpose_cast<<<dim3(8,32,32), blk, 0, stream>>>(wg, wgT, 1024, 256);
  transpose_cast<<<dim3(8,32,32), blk, 0, stream>>>(wu, wuT, 1024, 256);
  transpose_cast<<<dim3(32,8,32), blk, 0, stream>>>(wd, wdT, 256, 1024);

  // norm1 -> split h
  rmsnorm_kernel<<<2048, blk, 0, stream>>>(x, n1w, hH, hL, nullptr);
  // fused QKV projection (split): [2048 x 1536], BM=128
  gemm_kernel<true,128><<<dim3(24, 16), blk, 0, stream>>>(hH, hL, wqkvTh, wqkvTl, qkvf,
      nullptr, nullptr, nullptr, nullptr, 2048, 1536, 1024, 0);
  // RoPE + V transpose
  rope_split_kernel<<<4096, blk, 0, stream>>>(qkvf, 1536, 0,    fc, fs, qbh, qbl, 16);
  rope_split_kernel<<<1024, blk, 0, stream>>>(qkvf, 1536, 1024, fc, fs, kbh, kbl, 4);
  vtrans_split_kernel<<<2048, blk, 0, stream>>>(qkvf, 1536, 1280, vth, vtl);
  // attention
  attn_kernel<<<dim3(16,16,2), blk, 0, stream>>>(qbh, qbl, kbh, kbl, vth, vtl, attnH, attnL);
  // output projection + residual, BM=128
  gemm_kernel<true,128><<<dim3(16, 16), blk, 0, stream>>>(attnH, attnL, woTh, woTl, x1,
      x, nullptr, nullptr, nullptr, 2048, 1024, 1024, 0);
  // norm2 -> fp32 (router) + bf16 (experts)
  rmsnorm_kernel<<<2048, blk, 0, stream>>>(x1, n2w, h2b, nullptr, h2f);
  // router + grouping
  zero_counts<<<1, 64, 0, stream>>>(counts);
  router_kernel<<<256, blk, 0, stream>>>(h2f, rw, topIdx, topW, counts);
  scan_kernel<<<1, 64, 0, stream>>>(counts, offsets, cursor);
  scatter_kernel<<<32, blk, 0, stream>>>(topIdx, topW, cursor, rows, wtp, pslot);
  // shared MLP (g/u keep BM=64: BM=128 would underfill the grid at N=512)
  gemm_kernel<false,64><<<dim3(8, 32), blk, 0, stream>>>(h2b, nullptr, shgT, nullptr, sg,
      nullptr, nullptr, nullptr, nullptr, 2048, 512, 1024, 0);
  gemm_kernel<false,64><<<dim3(8, 32), blk, 0, stream>>>(h2b, nullptr, shuT, nullptr, su,
      nullptr, nullptr, nullptr, nullptr, 2048, 512, 1024, 0);
  silu_mul_kernel<<<4096, blk, 0, stream>>>(sg, su, nullptr, sactb, 2048*512);
  gemm_kernel<false,128><<<dim3(16, 16), blk, 0, stream>>>(sactb, nullptr, shdT, nullptr, shOut,
      nullptr, nullptr, nullptr, nullptr, 2048, 1024, 512, 0);
  // MoE expert GEMMs (grouped), BM=128
  gemm_kernel<false,128><<<dim3(4, 16, 32), blk, 0, stream>>>(h2b, nullptr, wgT, nullptr, pairG,
      nullptr, rows, counts, offsets, 0, 256, 1024, 256*1024);
  gemm_kernel<false,128><<<dim3(4, 16, 32), blk, 0, stream>>>(h2b, nullptr, wuT, nullptr, pairU,
      nullptr, rows, counts, offsets, 0, 256, 1024, 256*1024);
  silu_mul_kernel<<<8192, blk, 0, stream>>>(pairG, pairU, wtp, actb, 8192*256);
  gemm_kernel<false,128><<<dim3(16, 16, 32), blk, 0, stream>>>(actb, nullptr, wdT, nullptr, pairOut,
      nullptr, nullptr, counts, offsets, 0, 1024, 256, 1024*256);
  // final residual + combine
  final_kernel<<<2048, blk, 0, stream>>>(x1, shOut, pairOut, pslot, out);
}

// Round 7
// 406.149 us; speedup vs baseline: 1.7936x; 1.7936x over previous
//
#include <hip/hip_runtime.h>

typedef unsigned short u16;
typedef __attribute__((ext_vector_type(8))) short s8v;
typedef __attribute__((ext_vector_type(4))) float f4v;

#define DEV static __device__ __forceinline__

DEV u16 f2bf(float f) {
  union { float f; unsigned u; } v; v.f = f;
  unsigned r = v.u + 0x7FFFu + ((v.u >> 16) & 1u);
  return (u16)(r >> 16);
}
DEV float bf2f(u16 b) { union { unsigned u; float f; } v; v.u = ((unsigned)b) << 16; return v.f; }

DEV f4v mfma16(s8v a, s8v b, f4v c) {
  return __builtin_amdgcn_mfma_f32_16x16x32_bf16(a, b, c, 0, 0, 0);
}

// ---------------- transpose + cast ----------------
// in: [z][R][C] f32  -> out: [z][C][R] bf16
__global__ __launch_bounds__(256) void transpose_cast(const float* __restrict__ in,
                                                      u16* __restrict__ out, int R, int C) {
  __shared__ float tile[32][33];
  int z = blockIdx.z;
  const float* inp = in + (size_t)z * R * C;
  u16* op = out + (size_t)z * R * C;
  int c0 = blockIdx.x * 32, r0 = blockIdx.y * 32;
  int tx = threadIdx.x & 31, ty = threadIdx.x >> 5;
  for (int i = ty; i < 32; i += 8) {
    int r = r0 + i, c = c0 + tx;
    tile[i][tx] = (r < R && c < C) ? inp[(size_t)r * C + c] : 0.f;
  }
  __syncthreads();
  for (int i = ty; i < 32; i += 8) {
    int c = c0 + i, r = r0 + tx;
    if (c < C && r < R) op[(size_t)c * R + r] = f2bf(tile[tx][i]);
  }
}

__global__ __launch_bounds__(256) void transpose_cast_split(const float* __restrict__ in,
                                                            u16* __restrict__ outH, u16* __restrict__ outL,
                                                            int R, int C) {
  __shared__ float tile[32][33];
  int z = blockIdx.z;
  const float* inp = in + (size_t)z * R * C;
  u16* oH = outH + (size_t)z * R * C;
  u16* oL = outL + (size_t)z * R * C;
  int c0 = blockIdx.x * 32, r0 = blockIdx.y * 32;
  int tx = threadIdx.x & 31, ty = threadIdx.x >> 5;
  for (int i = ty; i < 32; i += 8) {
    int r = r0 + i, c = c0 + tx;
    tile[i][tx] = (r < R && c < C) ? inp[(size_t)r * C + c] : 0.f;
  }
  __syncthreads();
  for (int i = ty; i < 32; i += 8) {
    int c = c0 + i, r = r0 + tx;
    if (c < C && r < R) {
      float f = tile[tx][i];
      u16 hi = f2bf(f);
      oH[(size_t)c * R + r] = hi;
      oL[(size_t)c * R + r] = f2bf(f - bf2f(hi));
    }
  }
}

// ---------------- rmsnorm ----------------
__global__ __launch_bounds__(256) void rmsnorm_kernel(const float* __restrict__ xin,
                                                      const float* __restrict__ w,
                                                      u16* __restrict__ outH, u16* __restrict__ outL,
                                                      float* __restrict__ outF) {
  int n = blockIdx.x;
  int t = threadIdx.x;
  const float* xr = xin + (size_t)n * 1024;
  float4 v = ((const float4*)xr)[t];
  float ss = v.x*v.x + v.y*v.y + v.z*v.z + v.w*v.w;
  #pragma unroll
  for (int o = 1; o < 64; o <<= 1) ss += __shfl_xor(ss, o, 64);
  __shared__ float wsum[4];
  if ((t & 63) == 0) wsum[t >> 6] = ss;
  __syncthreads();
  float tot = wsum[0] + wsum[1] + wsum[2] + wsum[3];
  float rs = rsqrtf(tot * (1.0f/1024.0f) + 1e-6f);
  float4 wv = ((const float4*)w)[t];
  float o0 = v.x*rs*wv.x, o1 = v.y*rs*wv.y, o2 = v.z*rs*wv.z, o3 = v.w*rs*wv.w;
  if (outF) {
    float4 of = {o0, o1, o2, o3};
    ((float4*)(outF + (size_t)n*1024))[t] = of;
  }
  u16 h0 = f2bf(o0), h1 = f2bf(o1), h2 = f2bf(o2), h3 = f2bf(o3);
  ushort4 oh = {h0, h1, h2, h3};
  ((ushort4*)(outH + (size_t)n*1024))[t] = oh;
  if (outL) {
    ushort4 ol = { f2bf(o0 - bf2f(h0)), f2bf(o1 - bf2f(h1)),
                   f2bf(o2 - bf2f(h2)), f2bf(o3 - bf2f(h3)) };
    ((ushort4*)(outL + (size_t)n*1024))[t] = ol;
  }
}

// ---------------- GEMM BM=64 (R5-proven): C[M][N] = A[M][K] x BT[N][K]^T ----------------
// Named-register T14 prefetch (NO arrays/lambdas in staging -> no scratch).
template <bool SPLIT>
__global__ __launch_bounds__(256) void gemm_kernel(
    const u16* __restrict__ Ah, const u16* __restrict__ Al,
    const u16* __restrict__ Bh, const u16* __restrict__ Bl,
    float* __restrict__ C, const float* __restrict__ resid,
    const int* __restrict__ rowIdx, const int* __restrict__ counts,
    const int* __restrict__ offsets,
    int M, int N, int K, int strideBTe) {
  int M_ = M;
  const int* rIdx = rowIdx;
  int aOff = 0;
  if (counts) {
    int e = blockIdx.z;
    M_ = counts[e];
    if ((int)blockIdx.y * 64 >= M_) return;
    aOff = offsets[e];
    Bh += (size_t)e * strideBTe;
    C += (size_t)aOff * N;
    if (rIdx) rIdx += aOff;
  }
  __shared__ u16 AtH[64*72];
  __shared__ u16 BtH[64*72];
  __shared__ u16 AtL[SPLIT ? 64*72 : 8];
  __shared__ u16 BtL[SPLIT ? 64*72 : 8];

  int tid = threadIdx.x;
  int wid = tid >> 6, lane = tid & 63;
  int lo16 = lane & 15, hi4 = lane >> 4;
  int m0 = blockIdx.y * 64, n0 = blockIdx.x * 64;
  int srow = tid >> 2, sseg = (tid & 3) * 16;

  int am = m0 + srow;
  int arow;
  if (counts) {
    int mm = (am < M_) ? am : (M_ - 1);
    arow = rIdx ? rIdx[mm] : (aOff + mm);
  } else {
    arow = am;
  }
  const u16* aPH = Ah + (size_t)arow * K;
  const u16* aPL = SPLIT ? (Al + (size_t)arow * K) : nullptr;
  const u16* bPH = Bh + (size_t)(n0 + srow) * K;
  const u16* bPL = SPLIT ? (Bl + (size_t)(n0 + srow) * K) : nullptr;

  uint4 a0r, a1r, b0r, b1r, al0r, al1r, bl0r, bl1r;
  #define GLOAD(kb) { \
    a0r = *(const uint4*)(aPH + (kb) + sseg); a1r = *(const uint4*)(aPH + (kb) + sseg + 8); \
    b0r = *(const uint4*)(bPH + (kb) + sseg); b1r = *(const uint4*)(bPH + (kb) + sseg + 8); \
    if constexpr (SPLIT) { \
      al0r = *(const uint4*)(aPL + (kb) + sseg); al1r = *(const uint4*)(aPL + (kb) + sseg + 8); \
      bl0r = *(const uint4*)(bPL + (kb) + sseg); bl1r = *(const uint4*)(bPL + (kb) + sseg + 8); \
    } }
  #define GSTORE() { \
    *(uint4*)&AtH[srow*72 + sseg] = a0r; *(uint4*)&AtH[srow*72 + sseg + 8] = a1r; \
    *(uint4*)&BtH[srow*72 + sseg] = b0r; *(uint4*)&BtH[srow*72 + sseg + 8] = b1r; \
    if constexpr (SPLIT) { \
      *(uint4*)&AtL[srow*72 + sseg] = al0r; *(uint4*)&AtL[srow*72 + sseg + 8] = al1r; \
      *(uint4*)&BtL[srow*72 + sseg] = bl0r; *(uint4*)&BtL[srow*72 + sseg + 8] = bl1r; \
    } }

  f4v acc[4];
  #pragma unroll
  for (int j = 0; j < 4; ++j) { acc[j][0]=0.f; acc[j][1]=0.f; acc[j][2]=0.f; acc[j][3]=0.f; }

  GLOAD(0); GSTORE();
  for (int kb = 0; kb < K; kb += 64) {
    __syncthreads();                  // staged tile visible
    if (kb + 64 < K) GLOAD(kb + 64);  // prefetch next tile under this tile's MFMAs
    int ar = wid*16 + lo16;
    s8v ah0 = *(const s8v*)&AtH[ar*72 + 8*hi4];
    s8v ah1 = *(const s8v*)&AtH[ar*72 + 32 + 8*hi4];
    s8v al0, al1;
    if constexpr (SPLIT) {
      al0 = *(const s8v*)&AtL[ar*72 + 8*hi4];
      al1 = *(const s8v*)&AtL[ar*72 + 32 + 8*hi4];
    }
    #pragma unroll
    for (int j = 0; j < 4; ++j) {
      int br = j*16 + lo16;
      s8v bh0 = *(const s8v*)&BtH[br*72 + 8*hi4];
      s8v bh1 = *(const s8v*)&BtH[br*72 + 32 + 8*hi4];
      acc[j] = mfma16(ah0, bh0, acc[j]);
      acc[j] = mfma16(ah1, bh1, acc[j]);
      if constexpr (SPLIT) {
        s8v bl0 = *(const s8v*)&BtL[br*72 + 8*hi4];
        s8v bl1 = *(const s8v*)&BtL[br*72 + 32 + 8*hi4];
        acc[j] = mfma16(ah0, bl0, acc[j]);
        acc[j] = mfma16(ah1, bl1, acc[j]);
        acc[j] = mfma16(al0, bh0, acc[j]);
        acc[j] = mfma16(al1, bh1, acc[j]);
      }
    }
    __syncthreads();                  // all waves done reading LDS
    if (kb + 64 < K) GSTORE();        // write next tile (vmcnt drained under MFMAs)
  }
  #undef GLOAD
  #undef GSTORE
  #pragma unroll
  for (int r = 0; r < 4; ++r) {
    int rg = m0 + wid*16 + 4*hi4 + r;
    if (rg < M_) {
      size_t rb = (size_t)rg * N;
      #pragma unroll
      for (int j = 0; j < 4; ++j) {
        int cg = n0 + j*16 + lo16;
        float v = acc[j][r];
        if (resid) v += resid[rb + cg];
        C[rb + cg] = v;
      }
    }
  }
}

// ---------------- GEMM BM=128: each wave owns 32x64 output (2 row-fragments) ----------------
// 2x MFMA per A-fragment read, half the barrier-steps per FLOP vs BM=64.
// ALL staging registers are NAMED scalars (R6's array/lambda form spilled to
// scratch: VGPR 88/56 reported, 53MB scratch writes, 728us total).
template <bool SPLIT>
__global__ __launch_bounds__(256) void gemm128_kernel(
    const u16* __restrict__ Ah, const u16* __restrict__ Al,
    const u16* __restrict__ Bh, const u16* __restrict__ Bl,
    float* __restrict__ C, const float* __restrict__ resid,
    const int* __restrict__ rowIdx, const int* __restrict__ counts,
    const int* __restrict__ offsets,
    int M, int N, int K, int strideBTe) {
  int M_ = M;
  const int* rIdx = rowIdx;
  int aOff = 0;
  if (counts) {
    int e = blockIdx.z;
    M_ = counts[e];
    if ((int)blockIdx.y * 128 >= M_) return;
    aOff = offsets[e];
    Bh += (size_t)e * strideBTe;
    C += (size_t)aOff * N;
    if (rIdx) rIdx += aOff;
  }
  __shared__ u16 AtH[128*72];
  __shared__ u16 BtH[64*72];
  __shared__ u16 AtL[SPLIT ? 128*72 : 8];
  __shared__ u16 BtL[SPLIT ? 64*72 : 8];

  int tid = threadIdx.x;
  int wid = tid >> 6, lane = tid & 63;
  int lo16 = lane & 15, hi4 = lane >> 4;
  int m0 = blockIdx.y * 128, n0 = blockIdx.x * 64;

  // A staging: 2 threads/row, 32 cols each. B staging: 4 threads/row, 16 cols.
  int arowS = tid >> 1, acolS = (tid & 1) * 32;
  int browS = tid >> 2, bcolS = (tid & 3) * 16;

  int am = m0 + arowS;
  int arow;
  if (counts) {
    int mm = (am < M_) ? am : (M_ - 1);
    arow = rIdx ? rIdx[mm] : (aOff + mm);
  } else {
    arow = am;
  }
  const u16* aPH = Ah + (size_t)arow * K + acolS;
  const u16* aPL = SPLIT ? (Al + (size_t)arow * K + acolS) : nullptr;
  const u16* bPH = Bh + (size_t)(n0 + browS) * K + bcolS;
  const u16* bPL = SPLIT ? (Bl + (size_t)(n0 + browS) * K + bcolS) : nullptr;

  uint4 a0r, a1r, a2r, a3r, b0r, b1r;
  uint4 al0r, al1r, al2r, al3r, bl0r, bl1r;
  #define GLOAD(kb) { \
    a0r = *(const uint4*)(aPH + (kb));      a1r = *(const uint4*)(aPH + (kb) + 8); \
    a2r = *(const uint4*)(aPH + (kb) + 16); a3r = *(const uint4*)(aPH + (kb) + 24); \
    b0r = *(const uint4*)(bPH + (kb));      b1r = *(const uint4*)(bPH + (kb) + 8); \
    if constexpr (SPLIT) { \
      al0r = *(const uint4*)(aPL + (kb));      al1r = *(const uint4*)(aPL + (kb) + 8); \
      al2r = *(const uint4*)(aPL + (kb) + 16); al3r = *(const uint4*)(aPL + (kb) + 24); \
      bl0r = *(const uint4*)(bPL + (kb));      bl1r = *(const uint4*)(bPL + (kb) + 8); \
    } }
  #define GSTORE() { \
    *(uint4*)&AtH[arowS*72 + acolS]      = a0r; *(uint4*)&AtH[arowS*72 + acolS + 8]  = a1r; \
    *(uint4*)&AtH[arowS*72 + acolS + 16] = a2r; *(uint4*)&AtH[arowS*72 + acolS + 24] = a3r; \
    *(uint4*)&BtH[browS*72 + bcolS] = b0r; *(uint4*)&BtH[browS*72 + bcolS + 8] = b1r; \
    if constexpr (SPLIT) { \
      *(uint4*)&AtL[arowS*72 + acolS]      = al0r; *(uint4*)&AtL[arowS*72 + acolS + 8]  = al1r; \
      *(uint4*)&AtL[arowS*72 + acolS + 16] = al2r; *(uint4*)&AtL[arowS*72 + acolS + 24] = al3r; \
      *(uint4*)&BtL[browS*72 + bcolS] = bl0r; *(uint4*)&BtL[browS*72 + bcolS + 8] = bl1r; \
    } }

  f4v acc0[4], acc1[4];
  #pragma unroll
  for (int j = 0; j < 4; ++j) {
    acc0[j][0]=0.f; acc0[j][1]=0.f; acc0[j][2]=0.f; acc0[j][3]=0.f;
    acc1[j][0]=0.f; acc1[j][1]=0.f; acc1[j][2]=0.f; acc1[j][3]=0.f;
  }

  GLOAD(0); GSTORE();
  for (int kb = 0; kb < K; kb += 64) {
    __syncthreads();                  // staged tile visible
    if (kb + 64 < K) GLOAD(kb + 64);  // prefetch next tile under this tile's MFMAs
    int ar0 = wid*32 + lo16;          // row-fragment 0
    int ar1 = ar0 + 16;               // row-fragment 1
    s8v ah00 = *(const s8v*)&AtH[ar0*72 + 8*hi4];
    s8v ah01 = *(const s8v*)&AtH[ar0*72 + 32 + 8*hi4];
    s8v ah10 = *(const s8v*)&AtH[ar1*72 + 8*hi4];
    s8v ah11 = *(const s8v*)&AtH[ar1*72 + 32 + 8*hi4];
    s8v al00, al01, al10, al11;
    if constexpr (SPLIT) {
      al00 = *(const s8v*)&AtL[ar0*72 + 8*hi4];
      al01 = *(const s8v*)&AtL[ar0*72 + 32 + 8*hi4];
      al10 = *(const s8v*)&AtL[ar1*72 + 8*hi4];
      al11 = *(const s8v*)&AtL[ar1*72 + 32 + 8*hi4];
    }
    #pragma unroll
    for (int j = 0; j < 4; ++j) {
      int br = j*16 + lo16;
      s8v bh0 = *(const s8v*)&BtH[br*72 + 8*hi4];
      s8v bh1 = *(const s8v*)&BtH[br*72 + 32 + 8*hi4];
      acc0[j] = mfma16(ah00, bh0, acc0[j]);
      acc0[j] = mfma16(ah01, bh1, acc0[j]);
      acc1[j] = mfma16(ah10, bh0, acc1[j]);
      acc1[j] = mfma16(ah11, bh1, acc1[j]);
      if constexpr (SPLIT) {
        s8v bl0 = *(const s8v*)&BtL[br*72 + 8*hi4];
        s8v bl1 = *(const s8v*)&BtL[br*72 + 32 + 8*hi4];
        acc0[j] = mfma16(ah00, bl0, acc0[j]);
        acc0[j] = mfma16(ah01, bl1, acc0[j]);
        acc0[j] = mfma16(al00, bh0, acc0[j]);
        acc0[j] = mfma16(al01, bh1, acc0[j]);
        acc1[j] = mfma16(ah10, bl0, acc1[j]);
        acc1[j] = mfma16(ah11, bl1, acc1[j]);
        acc1[j] = mfma16(al10, bh0, acc1[j]);
        acc1[j] = mfma16(al11, bh1, acc1[j]);
      }
    }
    __syncthreads();                  // all waves done reading LDS
    if (kb + 64 < K) GSTORE();        // write next tile (vmcnt drained under MFMAs)
  }
  #undef GLOAD
  #undef GSTORE
  #pragma unroll
  for (int r = 0; r < 4; ++r) {
    int rg0 = m0 + wid*32 + 4*hi4 + r;
    if (rg0 < M_) {
      size_t rb = (size_t)rg0 * N;
      #pragma unroll
      for (int j = 0; j < 4; ++j) {
        int cg = n0 + j*16 + lo16;
        float v = acc0[j][r];
        if (resid) v += resid[rb + cg];
        C[rb + cg] = v;
      }
    }
    int rg1 = rg0 + 16;
    if (rg1 < M_) {
      size_t rb = (size_t)rg1 * N;
      #pragma unroll
      for (int j = 0; j < 4; ++j) {
        int cg = n0 + j*16 + lo16;
        float v = acc1[j][r];
        if (resid) v += resid[rb + cg];
        C[rb + cg] = v;
      }
    }
  }
}

// ---------------- RoPE (f32 -> split bf16, [b][NH][t][64] layout) ----------------
__global__ __launch_bounds__(256) void rope_split_kernel(const float* __restrict__ src, int ldsrc, int colOff,
                                                         const float* __restrict__ fc, const float* __restrict__ fs,
                                                         u16* __restrict__ outH, u16* __restrict__ outL, int NH) {
  int idx = blockIdx.x * 256 + threadIdx.x;
  int i = idx & 31; int tmp = idx >> 5;
  int hh = tmp % NH; int bt = tmp / NH;
  if (bt >= 2048) return;
  int t = bt & 1023, b = bt >> 10;
  const float* sp = src + (size_t)bt * ldsrc + colOff + hh*64 + 2*i;
  float a = sp[0], bb = sp[1];
  float c = fc[t*32 + i], s = fs[t*32 + i];
  float o0 = a*c - bb*s, o1 = a*s + bb*c;
  size_t o = (((size_t)(b*NH + hh))*1024 + t)*64 + 2*i;
  u16 h0 = f2bf(o0), h1 = f2bf(o1);
  outH[o] = h0; outH[o+1] = h1;
  outL[o] = f2bf(o0 - bf2f(h0)); outL[o+1] = f2bf(o1 - bf2f(h1));
}

// ---------------- V transpose (f32 -> split bf16, [b][kv][hd][t]) ----------------
__global__ __launch_bounds__(256) void vtrans_split_kernel(const float* __restrict__ src, int ldsrc, int colOff,
                                                           u16* __restrict__ outH, u16* __restrict__ outL) {
  int idx = blockIdx.x * 256 + threadIdx.x;
  if (idx >= 2*4*64*1024) return;
  int t = idx & 1023; int tmp = idx >> 10;
  int hd = tmp & 63; int kv = (tmp >> 6) & 3; int b = tmp >> 8;
  float f = src[(size_t)(b*1024 + t) * ldsrc + colOff + kv*64 + hd];
  u16 hi = f2bf(f);
  outH[idx] = hi; outL[idx] = f2bf(f - bf2f(hi));
}

// ---------------- flash attention (causal, GQA, split-bf16) ----------------
// LDS-staged K/V; complement qb mapping for XCD causal balance; T14 async
// staging (load t+1 into regs before compute of t, ds_write after barrier);
// base-2 softmax; diagonal-only masking; setprio around MFMA clusters.
__global__ __launch_bounds__(256) void attn_kernel(
    const u16* __restrict__ Qh, const u16* __restrict__ Ql,
    const u16* __restrict__ Kh_, const u16* __restrict__ Kl_,
    const u16* __restrict__ Vh_, const u16* __restrict__ Vl_,
    u16* __restrict__ Oh, u16* __restrict__ Ol) {
  int b = blockIdx.z, h = blockIdx.y;
  int qb = (b == 0) ? (int)blockIdx.x : (15 - (int)blockIdx.x);
  int kv = h >> 2;
  size_t qoff = ((size_t)(b*16 + h)) * 65536;
  size_t koff = ((size_t)(b*4 + kv)) * 65536;

  __shared__ u16 KtH[64*72], KtL[64*72], VtH[64*72], VtL[64*72];
  __shared__ u16 PtH[4][16*72], PtL[4][16*72];

  int tid = threadIdx.x, wid = tid >> 6, lane = tid & 63;
  int lo16 = lane & 15, hi4 = lane >> 4;
  int srow = tid >> 2, sseg = (tid & 3) * 16;

  int qrow = qb*64 + wid*16 + lo16;
  const u16* qbh_ = Qh + qoff + (size_t)qrow*64;
  const u16* qbl_ = Ql + qoff + (size_t)qrow*64;
  s8v qh0 = *(const s8v*)(qbh_ + 8*hi4);
  s8v qh1 = *(const s8v*)(qbh_ + 32 + 8*hi4);
  s8v ql0 = *(const s8v*)(qbl_ + 8*hi4);
  s8v ql1 = *(const s8v*)(qbl_ + 32 + 8*hi4);

  const u16* Kh = Kh_ + koff;
  const u16* Kl = Kl_ + koff;
  const u16* Vh = Vh_ + koff;
  const u16* Vl = Vl_ + koff;

  // one-tile-ahead register staging
  uint4 kh0r, kh1r, kl0r, kl1r, vh0r, vh1r, vl0r, vl1r;
  #define LOADT(kb) { \
    const u16* kh = Kh + (size_t)((kb)*64 + srow)*64 + sseg; \
    const u16* kl = Kl + (size_t)((kb)*64 + srow)*64 + sseg; \
    const u16* vh = Vh + (size_t)srow*1024 + (kb)*64 + sseg; \
    const u16* vl = Vl + (size_t)srow*1024 + (kb)*64 + sseg; \
    kh0r = *(const uint4*)(kh); kh1r = *(const uint4*)(kh + 8); \
    kl0r = *(const uint4*)(kl); kl1r = *(const uint4*)(kl + 8); \
    vh0r = *(const uint4*)(vh); vh1r = *(const uint4*)(vh + 8); \
    vl0r = *(const uint4*)(vl); vl1r = *(const uint4*)(vl + 8); }
  #define STORET() { \
    *(uint4*)&KtH[srow*72 + sseg]     = kh0r; *(uint4*)&KtH[srow*72 + sseg + 8] = kh1r; \
    *(uint4*)&KtL[srow*72 + sseg]     = kl0r; *(uint4*)&KtL[srow*72 + sseg + 8] = kl1r; \
    *(uint4*)&VtH[srow*72 + sseg]     = vh0r; *(uint4*)&VtH[srow*72 + sseg + 8] = vh1r; \
    *(uint4*)&VtL[srow*72 + sseg]     = vl0r; *(uint4*)&VtL[srow*72 + sseg + 8] = vl1r; }

  f4v oacc[4];
  #pragma unroll
  for (int j = 0; j < 4; ++j) { oacc[j][0]=0.f; oacc[j][1]=0.f; oacc[j][2]=0.f; oacc[j][3]=0.f; }
  float mrow[4] = {-1e30f, -1e30f, -1e30f, -1e30f};
  float lrow[4] = {0.f, 0.f, 0.f, 0.f};
  int qmy = qb*64 + wid*16 + 4*hi4;
  u16* PwH = PtH[wid];
  u16* PwL = PtL[wid];

  // base-2 softmax: scores scaled by 1/sqrt(64)*log2(e); exp2f = 1 v_exp_f32
  const float SC = 0.125f * 1.44269504088896f;

  LOADT(0); STORET();
  for (int kblk = 0; kblk <= qb; ++kblk) {
    __syncthreads();                 // staged tile visible to all waves
    if (kblk < qb) LOADT(kblk + 1);  // prefetch next tile under this tile's compute

    // ---- S = Q K^T ----
    f4v sfr[4];
    __builtin_amdgcn_s_setprio(1);
    #pragma unroll
    for (int j = 0; j < 4; ++j) {
      int kr = j*16 + lo16;
      s8v kh0 = *(const s8v*)&KtH[kr*72 + 8*hi4];
      s8v kh1 = *(const s8v*)&KtH[kr*72 + 32 + 8*hi4];
      s8v kl0 = *(const s8v*)&KtL[kr*72 + 8*hi4];
      s8v kl1 = *(const s8v*)&KtL[kr*72 + 32 + 8*hi4];
      f4v s; s[0]=0.f; s[1]=0.f; s[2]=0.f; s[3]=0.f;
      s = mfma16(qh0, kh0, s);
      s = mfma16(qh1, kh1, s);
      s = mfma16(qh0, kl0, s);
      s = mfma16(qh1, kl1, s);
      s = mfma16(ql0, kh0, s);
      s = mfma16(ql1, kh1, s);
      sfr[j] = s;
    }
    __builtin_amdgcn_s_setprio(0);

    // ---- online softmax (base-2); mask only the diagonal tile ----
    bool diag = (kblk == qb);
    float scl[4];
    #pragma unroll
    for (int r = 0; r < 4; ++r) {
      int qr = qmy + r;
      #pragma unroll
      for (int j = 0; j < 4; ++j) {
        float v = sfr[j][r] * SC;
        if (diag) {
          int kc = kblk*64 + j*16 + lo16;
          v = (kc > qr) ? -1e30f : v;
        }
        sfr[j][r] = v;
      }
      float mx = fmaxf(fmaxf(sfr[0][r], sfr[1][r]), fmaxf(sfr[2][r], sfr[3][r]));
      #pragma unroll
      for (int o = 1; o < 16; o <<= 1) mx = fmaxf(mx, __shfl_xor(mx, o, 64));
      float mnew = fmaxf(mrow[r], mx);
      scl[r] = exp2f(mrow[r] - mnew);
      mrow[r] = mnew;
      float sum = 0.f;
      #pragma unroll
      for (int j = 0; j < 4; ++j) {
        float pv = exp2f(sfr[j][r] - mnew);
        sfr[j][r] = pv;
        sum += pv;
      }
      #pragma unroll
      for (int o = 1; o < 16; o <<= 1) sum += __shfl_xor(sum, o, 64);
      lrow[r] = lrow[r] * scl[r] + sum;
    }
    #pragma unroll
    for (int j = 0; j < 4; ++j) {
      #pragma unroll
      for (int r = 0; r < 4; ++r) oacc[j][r] *= scl[r];
    }

    // ---- P transpose through per-wave LDS (split bf16) ----
    #pragma unroll
    for (int r = 0; r < 4; ++r) {
      #pragma unroll
      for (int j = 0; j < 4; ++j) {
        float pv = sfr[j][r];
        u16 hi = f2bf(pv);
        PwH[(4*hi4 + r)*72 + j*16 + lo16] = hi;
        PwL[(4*hi4 + r)*72 + j*16 + lo16] = f2bf(pv - bf2f(hi));
      }
    }
    asm volatile("s_waitcnt lgkmcnt(0)" ::: "memory");
    s8v ph0 = *(const s8v*)&PwH[lo16*72 + 8*hi4];
    s8v ph1 = *(const s8v*)&PwH[lo16*72 + 32 + 8*hi4];
    s8v pl0 = *(const s8v*)&PwL[lo16*72 + 8*hi4];
    s8v pl1 = *(const s8v*)&PwL[lo16*72 + 32 + 8*hi4];

    // ---- O += P V ----
    __builtin_amdgcn_s_setprio(1);
    #pragma unroll
    for (int j = 0; j < 4; ++j) {
      int vr = j*16 + lo16;
      s8v vh0 = *(const s8v*)&VtH[vr*72 + 8*hi4];
      s8v vh1 = *(const s8v*)&VtH[vr*72 + 32 + 8*hi4];
      s8v vl0 = *(const s8v*)&VtL[vr*72 + 8*hi4];
      s8v vl1 = *(const s8v*)&VtL[vr*72 + 32 + 8*hi4];
      oacc[j] = mfma16(ph0, vh0, oacc[j]);
      oacc[j] = mfma16(ph1, vh1, oacc[j]);
      oacc[j] = mfma16(ph0, vl0, oacc[j]);
      oacc[j] = mfma16(ph1, vl1, oacc[j]);
      oacc[j] = mfma16(pl0, vh0, oacc[j]);
      oacc[j] = mfma16(pl1, vh1, oacc[j]);
    }
    __builtin_amdgcn_s_setprio(0);

    __syncthreads();                 // all waves done reading K/V LDS
    if (kblk < qb) STORET();         // vmcnt mostly drained by now
  }
  #undef LOADT
  #undef STORET

  #pragma unroll
  for (int r = 0; r < 4; ++r) {
    float inv = 1.f / lrow[r];
    int tq = qb*64 + wid*16 + 4*hi4 + r;
    size_t base = ((size_t)(b*1024 + tq))*1024 + h*64;
    #pragma unroll
    for (int j = 0; j < 4; ++j) {
      float ov = oacc[j][r] * inv;
      u16 hi = f2bf(ov);
      Oh[base + j*16 + lo16] = hi;
      Ol[base + j*16 + lo16] = f2bf(ov - bf2f(hi));
    }
  }
}

// ---------------- router: logits(fp32) -> softmax -> top4 ----------------
// LDS-tiled: 256 blocks x 8 rows; h rows (32KB) + rw chunks (16KB) staged via
// coalesced float4; inner loop pure LDS+FMA (conflict-free). R4: 58 -> ~8us.
__global__ __launch_bounds__(256) void router_kernel(const float* __restrict__ h2,
                                                     const float* __restrict__ rw,
                                                     int* __restrict__ topIdx, float* __restrict__ topW,
                                                     int* __restrict__ counts) {
  __shared__ float hs[8*1024];    // 8 h rows
  __shared__ float rws[128*32];   // rw chunk [128 d][32 e]
  __shared__ int hist[32];
  int t = threadIdx.x;
  int row0 = blockIdx.x * 8;
  if (t < 32) hist[t] = 0;

  // stage 8 h rows: 2048 float4, coalesced
  {
    const float4* hsrc = (const float4*)(h2 + (size_t)row0 * 1024);
    float4* hdst = (float4*)hs;
    #pragma unroll
    for (int i = 0; i < 8; ++i) hdst[t + 256*i] = hsrc[t + 256*i];
  }

  int e = t & 31, rq = t >> 5;    // thread owns (row rq, expert e); 32-lane group = one row
  float acc = 0.f;
  for (int c = 0; c < 8; ++c) {
    __syncthreads();              // prev chunk fully consumed (and h staged, 1st iter)
    const float4* rsrc = (const float4*)(rw + (size_t)c * 4096);
    float4* rdst = (float4*)rws;
    #pragma unroll
    for (int i = 0; i < 4; ++i) rdst[t + 256*i] = rsrc[t + 256*i];
    __syncthreads();
    const float* hp = hs + rq*1024 + c*128;
    float b0 = 0.f, b1 = 0.f, b2 = 0.f, b3 = 0.f;
    #pragma unroll
    for (int d = 0; d < 128; d += 4) {
      b0 += hp[d+0] * rws[(d+0)*32 + e];
      b1 += hp[d+1] * rws[(d+1)*32 + e];
      b2 += hp[d+2] * rws[(d+2)*32 + e];
      b3 += hp[d+3] * rws[(d+3)*32 + e];
    }
    acc += (b0 + b1) + (b2 + b3);
  }

  // softmax over the 32-lane group (xor offsets <32 stay within the group)
  float mx = acc;
  #pragma unroll
  for (int o = 1; o < 32; o <<= 1) mx = fmaxf(mx, __shfl_xor(mx, o, 64));
  float ex = expf(acc - mx);
  float sm = ex;
  #pragma unroll
  for (int o = 1; o < 32; o <<= 1) sm += __shfl_xor(sm, o, 64);
  float prob = ex / sm;

  // top-4 within the group; tie -> smaller index (matches jax top_k)
  float pv = prob; int pi = e;
  int myRow = row0 + rq;
  for (int k = 0; k < 4; ++k) {
    float bv = pv; int bi = pi;
    #pragma unroll
    for (int o = 1; o < 32; o <<= 1) {
      float ov = __shfl_xor(bv, o, 64); int oi = __shfl_xor(bi, o, 64);
      if (ov > bv || (ov == bv && oi < bi)) { bv = ov; bi = oi; }
    }
    if (e == 0) {
      topIdx[myRow*4 + k] = bi; topW[myRow*4 + k] = bv;
      atomicAdd(&hist[bi], 1);   // LDS atomic
    }
    if (pi == bi) pv = -1.f;
  }
  __syncthreads();
  if (t < 32 && hist[t] > 0) atomicAdd(&counts[t], hist[t]);
}

__global__ void zero_counts(int* counts) { if (threadIdx.x < 32) counts[threadIdx.x] = 0; }

__global__ void scan_kernel(const int* __restrict__ counts, int* __restrict__ offsets, int* __restrict__ cursor) {
  if (threadIdx.x == 0) {
    int acc = 0;
    for (int e = 0; e < 32; ++e) { offsets[e] = acc; cursor[e] = acc; acc += counts[e]; }
    offsets[32] = acc;
  }
}

__global__ __launch_bounds__(256) void scatter_kernel(const int* __restrict__ topIdx, const float* __restrict__ topW,
                                                      int* __restrict__ cursor, int* __restrict__ rows,
                                                      float* __restrict__ wtp, int* __restrict__ pslot) {
  int i = blockIdx.x * 256 + threadIdx.x;
  if (i >= 2048*4) return;
  int e = topIdx[i];
  int slot = atomicAdd(&cursor[e], 1);
  rows[slot] = i >> 2;
  wtp[slot] = topW[i];
  pslot[i] = slot;
}

// ---------------- silu(g)*u [* wt_per_row256] -> bf16 ----------------
__global__ __launch_bounds__(256) void silu_mul_kernel(const float* __restrict__ g, const float* __restrict__ u,
                                                       const float* __restrict__ wtp, u16* __restrict__ out, int total) {
  int i = blockIdx.x * 256 + threadIdx.x;
  if (i >= total) return;
  float gv = g[i], uv = u[i];
  float s = gv / (1.f + expf(-gv));
  float r = s * uv;
  if (wtp) r *= wtp[i >> 8];
  out[i] = f2bf(r);
}

// ---------------- final: out = x1 + shared + sum_k pairOut[slot_k] ----------------
__global__ __launch_bounds__(256) void final_kernel(const float* __restrict__ x1, const float* __restrict__ shOut,
                                                    const float* __restrict__ pairOut, const int* __restrict__ pslot,
                                                    float* __restrict__ out) {
  int n = blockIdx.x;
  int t = threadIdx.x;
  int s0 = pslot[n*4], s1 = pslot[n*4+1], s2 = pslot[n*4+2], s3 = pslot[n*4+3];
  float4 a  = ((const float4*)(x1 + (size_t)n*1024))[t];
  float4 sh = ((const float4*)(shOut + (size_t)n*1024))[t];
  float4 p0 = ((const float4*)(pairOut + (size_t)s0*1024))[t];
  float4 p1 = ((const float4*)(pairOut + (size_t)s1*1024))[t];
  float4 p2 = ((const float4*)(pairOut + (size_t)s2*1024))[t];
  float4 p3 = ((const float4*)(pairOut + (size_t)s3*1024))[t];
  float4 o;
  o.x = a.x + sh.x + p0.x + p1.x + p2.x + p3.x;
  o.y = a.y + sh.y + p0.y + p1.y + p2.y + p3.y;
  o.z = a.z + sh.z + p0.z + p1.z + p2.z + p3.z;
  o.w = a.w + sh.w + p0.w + p1.w + p2.w + p3.w;
  ((float4*)(out + (size_t)n*1024))[t] = o;
}

// ---------------- host ----------------
extern "C" void kernel_launch(void* const* d_in, const int* in_sizes, int n_in,
                              void* d_out, int out_size, void* d_ws, size_t ws_size,
                              hipStream_t stream) {
  const float* x   = (const float*)d_in[0];
  const float* fc  = (const float*)d_in[1];
  const float* fs  = (const float*)d_in[2];
  const float* n1w = (const float*)d_in[3];
  const float* n2w = (const float*)d_in[4];
  const float* wq  = (const float*)d_in[5];
  const float* wk  = (const float*)d_in[6];
  const float* wv  = (const float*)d_in[7];
  const float* wo  = (const float*)d_in[8];
  const float* rw  = (const float*)d_in[9];
  const float* wg  = (const float*)d_in[10];
  const float* wu  = (const float*)d_in[11];
  const float* wd  = (const float*)d_in[12];
  const float* shg = (const float*)d_in[13];
  const float* shu = (const float*)d_in[14];
  const float* shd = (const float*)d_in[15];
  float* out = (float*)d_out;
  (void)in_sizes; (void)n_in; (void)out_size;

  char* p = (char*)d_ws;
  auto alloc = [&](size_t n) { char* r = p; p += (n + 255) & ~(size_t)255; return r; };

  u16* wqkvTh = (u16*)alloc((size_t)1536*1024*2);
  u16* wqkvTl = (u16*)alloc((size_t)1536*1024*2);
  u16* woTh   = (u16*)alloc((size_t)1024*1024*2);
  u16* woTl   = (u16*)alloc((size_t)1024*1024*2);
  u16* shgT   = (u16*)alloc((size_t)512*1024*2);
  u16* shuT   = (u16*)alloc((size_t)512*1024*2);
  u16* shdT   = (u16*)alloc((size_t)1024*512*2);
  u16* wgT    = (u16*)alloc((size_t)32*256*1024*2);
  u16* wuT    = (u16*)alloc((size_t)32*256*1024*2);
  u16* wdT    = (u16*)alloc((size_t)32*1024*256*2);
  u16* hH     = (u16*)alloc((size_t)2048*1024*2);
  u16* hL     = (u16*)alloc((size_t)2048*1024*2);
  float* x1   = (float*)alloc((size_t)2048*1024*4);
  float* h2f  = (float*)alloc((size_t)2048*1024*4);
  u16* h2b    = (u16*)alloc((size_t)2048*1024*2);
  float* pairG = (float*)alloc((size_t)8192*256*4);
  float* pairU = (float*)alloc((size_t)8192*256*4);
  u16* actb   = (u16*)alloc((size_t)8192*256*2);
  float* sg   = (float*)alloc((size_t)2048*512*4);
  float* su   = (float*)alloc((size_t)2048*512*4);
  u16* sactb  = (u16*)alloc((size_t)2048*512*2);
  float* shOut = (float*)alloc((size_t)2048*1024*4);
  int* topIdx = (int*)alloc(2048*4*4);
  float* topW = (float*)alloc(2048*4*4);
  int* counts = (int*)alloc(32*4);
  int* offsets = (int*)alloc(33*4);
  int* cursor = (int*)alloc(32*4);
  int* rows   = (int*)alloc(8192*4);
  float* wtp  = (float*)alloc(8192*4);
  int* pslot  = (int*)alloc(8192*4);
  // alias region: qkv/rope/attention temporaries, later reused as pairOut
  char* regionStart = p;
  float* qkvf = (float*)alloc((size_t)2048*1536*4);
  u16* qbh = (u16*)alloc((size_t)2048*1024*2);
  u16* qbl = (u16*)alloc((size_t)2048*1024*2);
  u16* kbh = (u16*)alloc((size_t)524288*2);
  u16* kbl = (u16*)alloc((size_t)524288*2);
  u16* vth = (u16*)alloc((size_t)524288*2);
  u16* vtl = (u16*)alloc((size_t)524288*2);
  u16* attnH = (u16*)alloc((size_t)2048*1024*2);
  u16* attnL = (u16*)alloc((size_t)2048*1024*2);
  float* pairOut = (float*)regionStart;  // 32MB, region is exactly 32MB

  size_t needed = (size_t)(p - (char*)d_ws);
  if (needed > ws_size) return;  // insufficient workspace; fail clean

  dim3 blk(256);
  // weight transposes (+bf16 cast; split for pre-router path)
  transpose_cast_split<<<dim3(32,32,1), blk, 0, stream>>>(wq, wqkvTh, wqkvTl, 1024, 1024);
  transpose_cast_split<<<dim3(8,32,1),  blk, 0, stream>>>(wk, wqkvTh + (size_t)1024*1024, wqkvTl + (size_t)1024*1024, 1024, 256);
  transpose_cast_split<<<dim3(8,32,1),  blk, 0, stream>>>(wv, wqkvTh + (size_t)1280*1024, wqkvTl + (size_t)1280*1024, 1024, 256);
  transpose_cast_split<<<dim3(32,32,1), blk, 0, stream>>>(wo, woTh, woTl, 1024, 1024);
  transpose_cast<<<dim3(16,32,1), blk, 0, stream>>>(shg, shgT, 1024, 512);
  transpose_cast<<<dim3(16,32,1), blk, 0, stream>>>(shu, shuT, 1024, 512);
  transpose_cast<<<dim3(32,16,1), blk, 0, stream>>>(shd, shdT, 512, 1024);
  transpose_cast<<<dim3(8,32,32), blk, 0, stream>>>(wg, wgT, 1024, 256);
  transpose_cast<<<dim3(8,32,32), blk, 0, stream>>>(wu, wuT, 1024, 256);
  transpose_cast<<<dim3(32,8,32), blk, 0, stream>>>(wd, wdT, 256, 1024);

  // norm1 -> split h
  rmsnorm_kernel<<<2048, blk, 0, stream>>>(x, n1w, hH, hL, nullptr);
  // fused QKV projection (split): [2048 x 1536], BM=128
  gemm128_kernel<true><<<dim3(24, 16), blk, 0, stream>>>(hH, hL, wqkvTh, wqkvTl, qkvf,
      nullptr, nullptr, nullptr, nullptr, 2048, 1536, 1024, 0);
  // RoPE + V transpose
  rope_split_kernel<<<4096, blk, 0, stream>>>(qkvf, 1536, 0,    fc, fs, qbh, qbl, 16);
  rope_split_kernel<<<1024, blk, 0, stream>>>(qkvf, 1536, 1024, fc, fs, kbh, kbl, 4);
  vtrans_split_kernel<<<2048, blk, 0, stream>>>(qkvf, 1536, 1280, vth, vtl);
  // attention
  attn_kernel<<<dim3(16,16,2), blk, 0, stream>>>(qbh, qbl, kbh, kbl, vth, vtl, attnH, attnL);
  // output projection + residual, BM=128
  gemm128_kernel<true><<<dim3(16, 16), blk, 0, stream>>>(attnH, attnL, woTh, woTl, x1,
      x, nullptr, nullptr, nullptr, 2048, 1024, 1024, 0);
  // norm2 -> fp32 (router) + bf16 (experts)
  rmsnorm_kernel<<<2048, blk, 0, stream>>>(x1, n2w, h2b, nullptr, h2f);
  // router + grouping
  zero_counts<<<1, 64, 0, stream>>>(counts);
  router_kernel<<<256, blk, 0, stream>>>(h2f, rw, topIdx, topW, counts);
  scan_kernel<<<1, 64, 0, stream>>>(counts, offsets, cursor);
  scatter_kernel<<<32, blk, 0, stream>>>(topIdx, topW, cursor, rows, wtp, pslot);
  // shared MLP (g/u keep BM=64: BM=128 would underfill the grid at N=512)
  gemm_kernel<false><<<dim3(8, 32), blk, 0, stream>>>(h2b, nullptr, shgT, nullptr, sg,
      nullptr, nullptr, nullptr, nullptr, 2048, 512, 1024, 0);
  gemm_kernel<false><<<dim3(8, 32), blk, 0, stream>>>(h2b, nullptr, shuT, nullptr, su,
      nullptr, nullptr, nullptr, nullptr, 2048, 512, 1024, 0);
  silu_mul_kernel<<<4096, blk, 0, stream>>>(sg, su, nullptr, sactb, 2048*512);
  gemm128_kernel<false><<<dim3(16, 16), blk, 0, stream>>>(sactb, nullptr, shdT, nullptr, shOut,
      nullptr, nullptr, nullptr, nullptr, 2048, 1024, 512, 0);
  // MoE expert GEMMs (grouped), BM=128
  gemm128_kernel<false><<<dim3(4, 16, 32), blk, 0, stream>>>(h2b, nullptr, wgT, nullptr, pairG,
      nullptr, rows, counts, offsets, 0, 256, 1024, 256*1024);
  gemm128_kernel<false><<<dim3(4, 16, 32), blk, 0, stream>>>(h2b, nullptr, wuT, nullptr, pairU,
      nullptr, rows, counts, offsets, 0, 256, 1024, 256*1024);
  silu_mul_kernel<<<8192, blk, 0, stream>>>(pairG, pairU, wtp, actb, 8192*256);
  gemm128_kernel<false><<<dim3(16, 16, 32), blk, 0, stream>>>(actb, nullptr, wdT, nullptr, pairOut,
      nullptr, nullptr, counts, offsets, 0, 1024, 256, 1024*256);
  // final residual + combine
  final_kernel<<<2048, blk, 0, stream>>>(x1, shOut, pairOut, pslot, out);
}

// Round 8
// 378.941 us; speedup vs baseline: 1.9223x; 1.0718x over previous
//
#include <hip/hip_runtime.h>

typedef unsigned short u16;
typedef __attribute__((ext_vector_type(8))) short s8v;
typedef __attribute__((ext_vector_type(4))) float f4v;

#define DEV static __device__ __forceinline__

DEV u16 f2bf(float f) {
  union { float f; unsigned u; } v; v.f = f;
  unsigned r = v.u + 0x7FFFu + ((v.u >> 16) & 1u);
  return (u16)(r >> 16);
}
DEV float bf2f(u16 b) { union { unsigned u; float f; } v; v.u = ((unsigned)b) << 16; return v.f; }

DEV f4v mfma16(s8v a, s8v b, f4v c) {
  return __builtin_amdgcn_mfma_f32_16x16x32_bf16(a, b, c, 0, 0, 0);
}

// ---------------- transpose + cast ----------------
// in: [z][R][C] f32  -> out: [z][C][R] bf16
__global__ __launch_bounds__(256) void transpose_cast(const float* __restrict__ in,
                                                      u16* __restrict__ out, int R, int C) {
  __shared__ float tile[32][33];
  int z = blockIdx.z;
  const float* inp = in + (size_t)z * R * C;
  u16* op = out + (size_t)z * R * C;
  int c0 = blockIdx.x * 32, r0 = blockIdx.y * 32;
  int tx = threadIdx.x & 31, ty = threadIdx.x >> 5;
  for (int i = ty; i < 32; i += 8) {
    int r = r0 + i, c = c0 + tx;
    tile[i][tx] = (r < R && c < C) ? inp[(size_t)r * C + c] : 0.f;
  }
  __syncthreads();
  for (int i = ty; i < 32; i += 8) {
    int c = c0 + i, r = r0 + tx;
    if (c < C && r < R) op[(size_t)c * R + r] = f2bf(tile[tx][i]);
  }
}

__global__ __launch_bounds__(256) void transpose_cast_split(const float* __restrict__ in,
                                                            u16* __restrict__ outH, u16* __restrict__ outL,
                                                            int R, int C) {
  __shared__ float tile[32][33];
  int z = blockIdx.z;
  const float* inp = in + (size_t)z * R * C;
  u16* oH = outH + (size_t)z * R * C;
  u16* oL = outL + (size_t)z * R * C;
  int c0 = blockIdx.x * 32, r0 = blockIdx.y * 32;
  int tx = threadIdx.x & 31, ty = threadIdx.x >> 5;
  for (int i = ty; i < 32; i += 8) {
    int r = r0 + i, c = c0 + tx;
    tile[i][tx] = (r < R && c < C) ? inp[(size_t)r * C + c] : 0.f;
  }
  __syncthreads();
  for (int i = ty; i < 32; i += 8) {
    int c = c0 + i, r = r0 + tx;
    if (c < C && r < R) {
      float f = tile[tx][i];
      u16 hi = f2bf(f);
      oH[(size_t)c * R + r] = hi;
      oL[(size_t)c * R + r] = f2bf(f - bf2f(hi));
    }
  }
}

// ---------------- rmsnorm ----------------
__global__ __launch_bounds__(256) void rmsnorm_kernel(const float* __restrict__ xin,
                                                      const float* __restrict__ w,
                                                      u16* __restrict__ outH, u16* __restrict__ outL,
                                                      float* __restrict__ outF) {
  int n = blockIdx.x;
  int t = threadIdx.x;
  const float* xr = xin + (size_t)n * 1024;
  float4 v = ((const float4*)xr)[t];
  float ss = v.x*v.x + v.y*v.y + v.z*v.z + v.w*v.w;
  #pragma unroll
  for (int o = 1; o < 64; o <<= 1) ss += __shfl_xor(ss, o, 64);
  __shared__ float wsum[4];
  if ((t & 63) == 0) wsum[t >> 6] = ss;
  __syncthreads();
  float tot = wsum[0] + wsum[1] + wsum[2] + wsum[3];
  float rs = rsqrtf(tot * (1.0f/1024.0f) + 1e-6f);
  float4 wv = ((const float4*)w)[t];
  float o0 = v.x*rs*wv.x, o1 = v.y*rs*wv.y, o2 = v.z*rs*wv.z, o3 = v.w*rs*wv.w;
  if (outF) {
    float4 of = {o0, o1, o2, o3};
    ((float4*)(outF + (size_t)n*1024))[t] = of;
  }
  u16 h0 = f2bf(o0), h1 = f2bf(o1), h2 = f2bf(o2), h3 = f2bf(o3);
  ushort4 oh = {h0, h1, h2, h3};
  ((ushort4*)(outH + (size_t)n*1024))[t] = oh;
  if (outL) {
    ushort4 ol = { f2bf(o0 - bf2f(h0)), f2bf(o1 - bf2f(h1)),
                   f2bf(o2 - bf2f(h2)), f2bf(o3 - bf2f(h3)) };
    ((ushort4*)(outL + (size_t)n*1024))[t] = ol;
  }
}

// ---------------- GEMM BM=64 (R5-proven): C[M][N] = A[M][K] x BT[N][K]^T ----------------
// Named-register T14 prefetch (NO arrays/lambdas in staging -> no scratch).
// BM=128 variant tried in R6/R7: scratch-spill disaster, then grid/occupancy
// regression (WO/shD fell to 1 block/CU). BM=64 is the proven config.
template <bool SPLIT>
__global__ __launch_bounds__(256) void gemm_kernel(
    const u16* __restrict__ Ah, const u16* __restrict__ Al,
    const u16* __restrict__ Bh, const u16* __restrict__ Bl,
    float* __restrict__ C, const float* __restrict__ resid,
    const int* __restrict__ rowIdx, const int* __restrict__ counts,
    const int* __restrict__ offsets,
    int M, int N, int K, int strideBTe) {
  int M_ = M;
  const int* rIdx = rowIdx;
  int aOff = 0;
  if (counts) {
    int e = blockIdx.z;
    M_ = counts[e];
    if ((int)blockIdx.y * 64 >= M_) return;
    aOff = offsets[e];
    Bh += (size_t)e * strideBTe;
    C += (size_t)aOff * N;
    if (rIdx) rIdx += aOff;
  }
  __shared__ u16 AtH[64*72];
  __shared__ u16 BtH[64*72];
  __shared__ u16 AtL[SPLIT ? 64*72 : 8];
  __shared__ u16 BtL[SPLIT ? 64*72 : 8];

  int tid = threadIdx.x;
  int wid = tid >> 6, lane = tid & 63;
  int lo16 = lane & 15, hi4 = lane >> 4;
  int m0 = blockIdx.y * 64, n0 = blockIdx.x * 64;
  int srow = tid >> 2, sseg = (tid & 3) * 16;

  int am = m0 + srow;
  int arow;
  if (counts) {
    int mm = (am < M_) ? am : (M_ - 1);
    arow = rIdx ? rIdx[mm] : (aOff + mm);
  } else {
    arow = am;
  }
  const u16* aPH = Ah + (size_t)arow * K;
  const u16* aPL = SPLIT ? (Al + (size_t)arow * K) : nullptr;
  const u16* bPH = Bh + (size_t)(n0 + srow) * K;
  const u16* bPL = SPLIT ? (Bl + (size_t)(n0 + srow) * K) : nullptr;

  uint4 a0r, a1r, b0r, b1r, al0r, al1r, bl0r, bl1r;
  #define GLOAD(kb) { \
    a0r = *(const uint4*)(aPH + (kb) + sseg); a1r = *(const uint4*)(aPH + (kb) + sseg + 8); \
    b0r = *(const uint4*)(bPH + (kb) + sseg); b1r = *(const uint4*)(bPH + (kb) + sseg + 8); \
    if constexpr (SPLIT) { \
      al0r = *(const uint4*)(aPL + (kb) + sseg); al1r = *(const uint4*)(aPL + (kb) + sseg + 8); \
      bl0r = *(const uint4*)(bPL + (kb) + sseg); bl1r = *(const uint4*)(bPL + (kb) + sseg + 8); \
    } }
  #define GSTORE() { \
    *(uint4*)&AtH[srow*72 + sseg] = a0r; *(uint4*)&AtH[srow*72 + sseg + 8] = a1r; \
    *(uint4*)&BtH[srow*72 + sseg] = b0r; *(uint4*)&BtH[srow*72 + sseg + 8] = b1r; \
    if constexpr (SPLIT) { \
      *(uint4*)&AtL[srow*72 + sseg] = al0r; *(uint4*)&AtL[srow*72 + sseg + 8] = al1r; \
      *(uint4*)&BtL[srow*72 + sseg] = bl0r; *(uint4*)&BtL[srow*72 + sseg + 8] = bl1r; \
    } }

  f4v acc[4];
  #pragma unroll
  for (int j = 0; j < 4; ++j) { acc[j][0]=0.f; acc[j][1]=0.f; acc[j][2]=0.f; acc[j][3]=0.f; }

  GLOAD(0); GSTORE();
  for (int kb = 0; kb < K; kb += 64) {
    __syncthreads();                  // staged tile visible
    if (kb + 64 < K) GLOAD(kb + 64);  // prefetch next tile under this tile's MFMAs
    int ar = wid*16 + lo16;
    s8v ah0 = *(const s8v*)&AtH[ar*72 + 8*hi4];
    s8v ah1 = *(const s8v*)&AtH[ar*72 + 32 + 8*hi4];
    s8v al0, al1;
    if constexpr (SPLIT) {
      al0 = *(const s8v*)&AtL[ar*72 + 8*hi4];
      al1 = *(const s8v*)&AtL[ar*72 + 32 + 8*hi4];
    }
    #pragma unroll
    for (int j = 0; j < 4; ++j) {
      int br = j*16 + lo16;
      s8v bh0 = *(const s8v*)&BtH[br*72 + 8*hi4];
      s8v bh1 = *(const s8v*)&BtH[br*72 + 32 + 8*hi4];
      acc[j] = mfma16(ah0, bh0, acc[j]);
      acc[j] = mfma16(ah1, bh1, acc[j]);
      if constexpr (SPLIT) {
        s8v bl0 = *(const s8v*)&BtL[br*72 + 8*hi4];
        s8v bl1 = *(const s8v*)&BtL[br*72 + 32 + 8*hi4];
        acc[j] = mfma16(ah0, bl0, acc[j]);
        acc[j] = mfma16(ah1, bl1, acc[j]);
        acc[j] = mfma16(al0, bh0, acc[j]);
        acc[j] = mfma16(al1, bh1, acc[j]);
      }
    }
    __syncthreads();                  // all waves done reading LDS
    if (kb + 64 < K) GSTORE();        // write next tile (vmcnt drained under MFMAs)
  }
  #undef GLOAD
  #undef GSTORE
  #pragma unroll
  for (int r = 0; r < 4; ++r) {
    int rg = m0 + wid*16 + 4*hi4 + r;
    if (rg < M_) {
      size_t rb = (size_t)rg * N;
      #pragma unroll
      for (int j = 0; j < 4; ++j) {
        int cg = n0 + j*16 + lo16;
        float v = acc[j][r];
        if (resid) v += resid[rb + cg];
        C[rb + cg] = v;
      }
    }
  }
}

// ---------------- RoPE (f32 -> split bf16, [b][NH][t][64] layout) ----------------
__global__ __launch_bounds__(256) void rope_split_kernel(const float* __restrict__ src, int ldsrc, int colOff,
                                                         const float* __restrict__ fc, const float* __restrict__ fs,
                                                         u16* __restrict__ outH, u16* __restrict__ outL, int NH) {
  int idx = blockIdx.x * 256 + threadIdx.x;
  int i = idx & 31; int tmp = idx >> 5;
  int hh = tmp % NH; int bt = tmp / NH;
  if (bt >= 2048) return;
  int t = bt & 1023, b = bt >> 10;
  const float* sp = src + (size_t)bt * ldsrc + colOff + hh*64 + 2*i;
  float a = sp[0], bb = sp[1];
  float c = fc[t*32 + i], s = fs[t*32 + i];
  float o0 = a*c - bb*s, o1 = a*s + bb*c;
  size_t o = (((size_t)(b*NH + hh))*1024 + t)*64 + 2*i;
  u16 h0 = f2bf(o0), h1 = f2bf(o1);
  outH[o] = h0; outH[o+1] = h1;
  outL[o] = f2bf(o0 - bf2f(h0)); outL[o+1] = f2bf(o1 - bf2f(h1));
}

// ---------------- V transpose (f32 -> bf16 hi [+ optional lo], [b][kv][hd][t]) ----------------
__global__ __launch_bounds__(256) void vtrans_split_kernel(const float* __restrict__ src, int ldsrc, int colOff,
                                                           u16* __restrict__ outH, u16* __restrict__ outL) {
  int idx = blockIdx.x * 256 + threadIdx.x;
  if (idx >= 2*4*64*1024) return;
  int t = idx & 1023; int tmp = idx >> 10;
  int hd = tmp & 63; int kv = (tmp >> 6) & 3; int b = tmp >> 8;
  float f = src[(size_t)(b*1024 + t) * ldsrc + colOff + kv*64 + hd];
  u16 hi = f2bf(f);
  outH[idx] = hi;
  if (outL) outL[idx] = f2bf(f - bf2f(hi));
}

// ---------------- flash attention (causal, GQA, split-bf16 QK / bf16 PV) ----------------
// LDS-staged K/V; complement qb mapping for XCD causal balance; T14 async
// staging; base-2 softmax; diagonal-only masking; setprio around MFMA.
// R8: PV lo-plane terms dropped (P in (0,1] -> |P-Ph| <= 2^-9 P; dropped-term
// error on O ~2e-3 absolute, negligible vs 0.031 absmax). QK keeps full split
// (score errors get exponentiated). Removes VtL/PtL (LDS 55296->36864),
// 4 of 6 PV MFMAs per j, the Pl write path, and V-lo staging traffic.
__global__ __launch_bounds__(256) void attn_kernel(
    const u16* __restrict__ Qh, const u16* __restrict__ Ql,
    const u16* __restrict__ Kh_, const u16* __restrict__ Kl_,
    const u16* __restrict__ Vh_,
    u16* __restrict__ Oh, u16* __restrict__ Ol) {
  int b = blockIdx.z, h = blockIdx.y;
  int qb = (b == 0) ? (int)blockIdx.x : (15 - (int)blockIdx.x);
  int kv = h >> 2;
  size_t qoff = ((size_t)(b*16 + h)) * 65536;
  size_t koff = ((size_t)(b*4 + kv)) * 65536;

  __shared__ u16 KtH[64*72], KtL[64*72], VtH[64*72];
  __shared__ u16 PtH[4][16*72];

  int tid = threadIdx.x, wid = tid >> 6, lane = tid & 63;
  int lo16 = lane & 15, hi4 = lane >> 4;
  int srow = tid >> 2, sseg = (tid & 3) * 16;

  int qrow = qb*64 + wid*16 + lo16;
  const u16* qbh_ = Qh + qoff + (size_t)qrow*64;
  const u16* qbl_ = Ql + qoff + (size_t)qrow*64;
  s8v qh0 = *(const s8v*)(qbh_ + 8*hi4);
  s8v qh1 = *(const s8v*)(qbh_ + 32 + 8*hi4);
  s8v ql0 = *(const s8v*)(qbl_ + 8*hi4);
  s8v ql1 = *(const s8v*)(qbl_ + 32 + 8*hi4);

  const u16* Kh = Kh_ + koff;
  const u16* Kl = Kl_ + koff;
  const u16* Vh = Vh_ + koff;

  // one-tile-ahead register staging (named regs only)
  uint4 kh0r, kh1r, kl0r, kl1r, vh0r, vh1r;
  #define LOADT(kb) { \
    const u16* kh = Kh + (size_t)((kb)*64 + srow)*64 + sseg; \
    const u16* kl = Kl + (size_t)((kb)*64 + srow)*64 + sseg; \
    const u16* vh = Vh + (size_t)srow*1024 + (kb)*64 + sseg; \
    kh0r = *(const uint4*)(kh); kh1r = *(const uint4*)(kh + 8); \
    kl0r = *(const uint4*)(kl); kl1r = *(const uint4*)(kl + 8); \
    vh0r = *(const uint4*)(vh); vh1r = *(const uint4*)(vh + 8); }
  #define STORET() { \
    *(uint4*)&KtH[srow*72 + sseg]     = kh0r; *(uint4*)&KtH[srow*72 + sseg + 8] = kh1r; \
    *(uint4*)&KtL[srow*72 + sseg]     = kl0r; *(uint4*)&KtL[srow*72 + sseg + 8] = kl1r; \
    *(uint4*)&VtH[srow*72 + sseg]     = vh0r; *(uint4*)&VtH[srow*72 + sseg + 8] = vh1r; }

  f4v oacc[4];
  #pragma unroll
  for (int j = 0; j < 4; ++j) { oacc[j][0]=0.f; oacc[j][1]=0.f; oacc[j][2]=0.f; oacc[j][3]=0.f; }
  float mrow[4] = {-1e30f, -1e30f, -1e30f, -1e30f};
  float lrow[4] = {0.f, 0.f, 0.f, 0.f};
  int qmy = qb*64 + wid*16 + 4*hi4;
  u16* PwH = PtH[wid];

  // base-2 softmax: scores scaled by 1/sqrt(64)*log2(e); exp2f = 1 v_exp_f32
  const float SC = 0.125f * 1.44269504088896f;

  LOADT(0); STORET();
  for (int kblk = 0; kblk <= qb; ++kblk) {
    __syncthreads();                 // staged tile visible to all waves
    if (kblk < qb) LOADT(kblk + 1);  // prefetch next tile under this tile's compute

    // ---- S = Q K^T (full hi/lo split) ----
    f4v sfr[4];
    __builtin_amdgcn_s_setprio(1);
    #pragma unroll
    for (int j = 0; j < 4; ++j) {
      int kr = j*16 + lo16;
      s8v kh0 = *(const s8v*)&KtH[kr*72 + 8*hi4];
      s8v kh1 = *(const s8v*)&KtH[kr*72 + 32 + 8*hi4];
      s8v kl0 = *(const s8v*)&KtL[kr*72 + 8*hi4];
      s8v kl1 = *(const s8v*)&KtL[kr*72 + 32 + 8*hi4];
      f4v s; s[0]=0.f; s[1]=0.f; s[2]=0.f; s[3]=0.f;
      s = mfma16(qh0, kh0, s);
      s = mfma16(qh1, kh1, s);
      s = mfma16(qh0, kl0, s);
      s = mfma16(qh1, kl1, s);
      s = mfma16(ql0, kh0, s);
      s = mfma16(ql1, kh1, s);
      sfr[j] = s;
    }
    __builtin_amdgcn_s_setprio(0);

    // ---- online softmax (base-2); mask only the diagonal tile ----
    bool diag = (kblk == qb);
    float scl[4];
    #pragma unroll
    for (int r = 0; r < 4; ++r) {
      int qr = qmy + r;
      #pragma unroll
      for (int j = 0; j < 4; ++j) {
        float v = sfr[j][r] * SC;
        if (diag) {
          int kc = kblk*64 + j*16 + lo16;
          v = (kc > qr) ? -1e30f : v;
        }
        sfr[j][r] = v;
      }
      float mx = fmaxf(fmaxf(sfr[0][r], sfr[1][r]), fmaxf(sfr[2][r], sfr[3][r]));
      #pragma unroll
      for (int o = 1; o < 16; o <<= 1) mx = fmaxf(mx, __shfl_xor(mx, o, 64));
      float mnew = fmaxf(mrow[r], mx);
      scl[r] = exp2f(mrow[r] - mnew);
      mrow[r] = mnew;
      float sum = 0.f;
      #pragma unroll
      for (int j = 0; j < 4; ++j) {
        float pv = exp2f(sfr[j][r] - mnew);
        sfr[j][r] = pv;
        sum += pv;
      }
      #pragma unroll
      for (int o = 1; o < 16; o <<= 1) sum += __shfl_xor(sum, o, 64);
      lrow[r] = lrow[r] * scl[r] + sum;
    }
    #pragma unroll
    for (int j = 0; j < 4; ++j) {
      #pragma unroll
      for (int r = 0; r < 4; ++r) oacc[j][r] *= scl[r];
    }

    // ---- P transpose through per-wave LDS (hi plane only) ----
    #pragma unroll
    for (int r = 0; r < 4; ++r) {
      #pragma unroll
      for (int j = 0; j < 4; ++j) {
        PwH[(4*hi4 + r)*72 + j*16 + lo16] = f2bf(sfr[j][r]);
      }
    }
    asm volatile("s_waitcnt lgkmcnt(0)" ::: "memory");
    s8v ph0 = *(const s8v*)&PwH[lo16*72 + 8*hi4];
    s8v ph1 = *(const s8v*)&PwH[lo16*72 + 32 + 8*hi4];

    // ---- O += P V (hi x hi only; lo terms ~2e-3, below noise) ----
    __builtin_amdgcn_s_setprio(1);
    #pragma unroll
    for (int j = 0; j < 4; ++j) {
      int vr = j*16 + lo16;
      s8v vh0 = *(const s8v*)&VtH[vr*72 + 8*hi4];
      s8v vh1 = *(const s8v*)&VtH[vr*72 + 32 + 8*hi4];
      oacc[j] = mfma16(ph0, vh0, oacc[j]);
      oacc[j] = mfma16(ph1, vh1, oacc[j]);
    }
    __builtin_amdgcn_s_setprio(0);

    __syncthreads();                 // all waves done reading K/V LDS
    if (kblk < qb) STORET();         // vmcnt mostly drained by now
  }
  #undef LOADT
  #undef STORET

  #pragma unroll
  for (int r = 0; r < 4; ++r) {
    float inv = 1.f / lrow[r];
    int tq = qb*64 + wid*16 + 4*hi4 + r;
    size_t base = ((size_t)(b*1024 + tq))*1024 + h*64;
    #pragma unroll
    for (int j = 0; j < 4; ++j) {
      float ov = oacc[j][r] * inv;
      u16 hi = f2bf(ov);
      Oh[base + j*16 + lo16] = hi;
      Ol[base + j*16 + lo16] = f2bf(ov - bf2f(hi));
    }
  }
}

// ---------------- router: logits(fp32) -> softmax -> top4 ----------------
// LDS-tiled: 256 blocks x 8 rows; h rows (32KB) + rw chunks (16KB) staged via
// coalesced float4; inner loop pure LDS+FMA (conflict-free). R4: 58 -> ~8us.
__global__ __launch_bounds__(256) void router_kernel(const float* __restrict__ h2,
                                                     const float* __restrict__ rw,
                                                     int* __restrict__ topIdx, float* __restrict__ topW,
                                                     int* __restrict__ counts) {
  __shared__ float hs[8*1024];    // 8 h rows
  __shared__ float rws[128*32];   // rw chunk [128 d][32 e]
  __shared__ int hist[32];
  int t = threadIdx.x;
  int row0 = blockIdx.x * 8;
  if (t < 32) hist[t] = 0;

  // stage 8 h rows: 2048 float4, coalesced
  {
    const float4* hsrc = (const float4*)(h2 + (size_t)row0 * 1024);
    float4* hdst = (float4*)hs;
    #pragma unroll
    for (int i = 0; i < 8; ++i) hdst[t + 256*i] = hsrc[t + 256*i];
  }

  int e = t & 31, rq = t >> 5;    // thread owns (row rq, expert e); 32-lane group = one row
  float acc = 0.f;
  for (int c = 0; c < 8; ++c) {
    __syncthreads();              // prev chunk fully consumed (and h staged, 1st iter)
    const float4* rsrc = (const float4*)(rw + (size_t)c * 4096);
    float4* rdst = (float4*)rws;
    #pragma unroll
    for (int i = 0; i < 4; ++i) rdst[t + 256*i] = rsrc[t + 256*i];
    __syncthreads();
    const float* hp = hs + rq*1024 + c*128;
    float b0 = 0.f, b1 = 0.f, b2 = 0.f, b3 = 0.f;
    #pragma unroll
    for (int d = 0; d < 128; d += 4) {
      b0 += hp[d+0] * rws[(d+0)*32 + e];
      b1 += hp[d+1] * rws[(d+1)*32 + e];
      b2 += hp[d+2] * rws[(d+2)*32 + e];
      b3 += hp[d+3] * rws[(d+3)*32 + e];
    }
    acc += (b0 + b1) + (b2 + b3);
  }

  // softmax over the 32-lane group (xor offsets <32 stay within the group)
  float mx = acc;
  #pragma unroll
  for (int o = 1; o < 32; o <<= 1) mx = fmaxf(mx, __shfl_xor(mx, o, 64));
  float ex = expf(acc - mx);
  float sm = ex;
  #pragma unroll
  for (int o = 1; o < 32; o <<= 1) sm += __shfl_xor(sm, o, 64);
  float prob = ex / sm;

  // top-4 within the group; tie -> smaller index (matches jax top_k)
  float pv = prob; int pi = e;
  int myRow = row0 + rq;
  for (int k = 0; k < 4; ++k) {
    float bv = pv; int bi = pi;
    #pragma unroll
    for (int o = 1; o < 32; o <<= 1) {
      float ov = __shfl_xor(bv, o, 64); int oi = __shfl_xor(bi, o, 64);
      if (ov > bv || (ov == bv && oi < bi)) { bv = ov; bi = oi; }
    }
    if (e == 0) {
      topIdx[myRow*4 + k] = bi; topW[myRow*4 + k] = bv;
      atomicAdd(&hist[bi], 1);   // LDS atomic
    }
    if (pi == bi) pv = -1.f;
  }
  __syncthreads();
  if (t < 32 && hist[t] > 0) atomicAdd(&counts[t], hist[t]);
}

__global__ void zero_counts(int* counts) { if (threadIdx.x < 32) counts[threadIdx.x] = 0; }

__global__ void scan_kernel(const int* __restrict__ counts, int* __restrict__ offsets, int* __restrict__ cursor) {
  if (threadIdx.x == 0) {
    int acc = 0;
    for (int e = 0; e < 32; ++e) { offsets[e] = acc; cursor[e] = acc; acc += counts[e]; }
    offsets[32] = acc;
  }
}

__global__ __launch_bounds__(256) void scatter_kernel(const int* __restrict__ topIdx, const float* __restrict__ topW,
                                                      int* __restrict__ cursor, int* __restrict__ rows,
                                                      float* __restrict__ wtp, int* __restrict__ pslot) {
  int i = blockIdx.x * 256 + threadIdx.x;
  if (i >= 2048*4) return;
  int e = topIdx[i];
  int slot = atomicAdd(&cursor[e], 1);
  rows[slot] = i >> 2;
  wtp[slot] = topW[i];
  pslot[i] = slot;
}

// ---------------- silu(g)*u [* wt_per_row256] -> bf16 ----------------
__global__ __launch_bounds__(256) void silu_mul_kernel(const float* __restrict__ g, const float* __restrict__ u,
                                                       const float* __restrict__ wtp, u16* __restrict__ out, int total) {
  int i = blockIdx.x * 256 + threadIdx.x;
  if (i >= total) return;
  float gv = g[i], uv = u[i];
  float s = gv / (1.f + expf(-gv));
  float r = s * uv;
  if (wtp) r *= wtp[i >> 8];
  out[i] = f2bf(r);
}

// ---------------- final: out = x1 + shared + sum_k pairOut[slot_k] ----------------
__global__ __launch_bounds__(256) void final_kernel(const float* __restrict__ x1, const float* __restrict__ shOut,
                                                    const float* __restrict__ pairOut, const int* __restrict__ pslot,
                                                    float* __restrict__ out) {
  int n = blockIdx.x;
  int t = threadIdx.x;
  int s0 = pslot[n*4], s1 = pslot[n*4+1], s2 = pslot[n*4+2], s3 = pslot[n*4+3];
  float4 a  = ((const float4*)(x1 + (size_t)n*1024))[t];
  float4 sh = ((const float4*)(shOut + (size_t)n*1024))[t];
  float4 p0 = ((const float4*)(pairOut + (size_t)s0*1024))[t];
  float4 p1 = ((const float4*)(pairOut + (size_t)s1*1024))[t];
  float4 p2 = ((const float4*)(pairOut + (size_t)s2*1024))[t];
  float4 p3 = ((const float4*)(pairOut + (size_t)s3*1024))[t];
  float4 o;
  o.x = a.x + sh.x + p0.x + p1.x + p2.x + p3.x;
  o.y = a.y + sh.y + p0.y + p1.y + p2.y + p3.y;
  o.z = a.z + sh.z + p0.z + p1.z + p2.z + p3.z;
  o.w = a.w + sh.w + p0.w + p1.w + p2.w + p3.w;
  ((float4*)(out + (size_t)n*1024))[t] = o;
}

// ---------------- host ----------------
extern "C" void kernel_launch(void* const* d_in, const int* in_sizes, int n_in,
                              void* d_out, int out_size, void* d_ws, size_t ws_size,
                              hipStream_t stream) {
  const float* x   = (const float*)d_in[0];
  const float* fc  = (const float*)d_in[1];
  const float* fs  = (const float*)d_in[2];
  const float* n1w = (const float*)d_in[3];
  const float* n2w = (const float*)d_in[4];
  const float* wq  = (const float*)d_in[5];
  const float* wk  = (const float*)d_in[6];
  const float* wv  = (const float*)d_in[7];
  const float* wo  = (const float*)d_in[8];
  const float* rw  = (const float*)d_in[9];
  const float* wg  = (const float*)d_in[10];
  const float* wu  = (const float*)d_in[11];
  const float* wd  = (const float*)d_in[12];
  const float* shg = (const float*)d_in[13];
  const float* shu = (const float*)d_in[14];
  const float* shd = (const float*)d_in[15];
  float* out = (float*)d_out;
  (void)in_sizes; (void)n_in; (void)out_size;

  char* p = (char*)d_ws;
  auto alloc = [&](size_t n) { char* r = p; p += (n + 255) & ~(size_t)255; return r; };

  u16* wqkvTh = (u16*)alloc((size_t)1536*1024*2);
  u16* wqkvTl = (u16*)alloc((size_t)1536*1024*2);
  u16* woTh   = (u16*)alloc((size_t)1024*1024*2);
  u16* woTl   = (u16*)alloc((size_t)1024*1024*2);
  u16* shgT   = (u16*)alloc((size_t)512*1024*2);
  u16* shuT   = (u16*)alloc((size_t)512*1024*2);
  u16* shdT   = (u16*)alloc((size_t)1024*512*2);
  u16* wgT    = (u16*)alloc((size_t)32*256*1024*2);
  u16* wuT    = (u16*)alloc((size_t)32*256*1024*2);
  u16* wdT    = (u16*)alloc((size_t)32*1024*256*2);
  u16* hH     = (u16*)alloc((size_t)2048*1024*2);
  u16* hL     = (u16*)alloc((size_t)2048*1024*2);
  float* x1   = (float*)alloc((size_t)2048*1024*4);
  float* h2f  = (float*)alloc((size_t)2048*1024*4);
  u16* h2b    = (u16*)alloc((size_t)2048*1024*2);
  float* pairG = (float*)alloc((size_t)8192*256*4);
  float* pairU = (float*)alloc((size_t)8192*256*4);
  u16* actb   = (u16*)alloc((size_t)8192*256*2);
  float* sg   = (float*)alloc((size_t)2048*512*4);
  float* su   = (float*)alloc((size_t)2048*512*4);
  u16* sactb  = (u16*)alloc((size_t)2048*512*2);
  float* shOut = (float*)alloc((size_t)2048*1024*4);
  int* topIdx = (int*)alloc(2048*4*4);
  float* topW = (float*)alloc(2048*4*4);
  int* counts = (int*)alloc(32*4);
  int* offsets = (int*)alloc(33*4);
  int* cursor = (int*)alloc(32*4);
  int* rows   = (int*)alloc(8192*4);
  float* wtp  = (float*)alloc(8192*4);
  int* pslot  = (int*)alloc(8192*4);
  // alias region: qkv/rope/attention temporaries, later reused as pairOut
  char* regionStart = p;
  float* qkvf = (float*)alloc((size_t)2048*1536*4);
  u16* qbh = (u16*)alloc((size_t)2048*1024*2);
  u16* qbl = (u16*)alloc((size_t)2048*1024*2);
  u16* kbh = (u16*)alloc((size_t)524288*2);
  u16* kbl = (u16*)alloc((size_t)524288*2);
  u16* vth = (u16*)alloc((size_t)524288*2);
  u16* attnH = (u16*)alloc((size_t)2048*1024*2);
  u16* attnL = (u16*)alloc((size_t)2048*1024*2);
  float* pairOut = (float*)regionStart;  // 32MB, region is exactly 32MB

  size_t needed = (size_t)(p - (char*)d_ws);
  if (needed > ws_size) return;  // insufficient workspace; fail clean

  dim3 blk(256);
  // weight transposes (+bf16 cast; split for pre-router path)
  transpose_cast_split<<<dim3(32,32,1), blk, 0, stream>>>(wq, wqkvTh, wqkvTl, 1024, 1024);
  transpose_cast_split<<<dim3(8,32,1),  blk, 0, stream>>>(wk, wqkvTh + (size_t)1024*1024, wqkvTl + (size_t)1024*1024, 1024, 256);
  transpose_cast_split<<<dim3(8,32,1),  blk, 0, stream>>>(wv, wqkvTh + (size_t)1280*1024, wqkvTl + (size_t)1280*1024, 1024, 256);
  transpose_cast_split<<<dim3(32,32,1), blk, 0, stream>>>(wo, woTh, woTl, 1024, 1024);
  transpose_cast<<<dim3(16,32,1), blk, 0, stream>>>(shg, shgT, 1024, 512);
  transpose_cast<<<dim3(16,32,1), blk, 0, stream>>>(shu, shuT, 1024, 512);
  transpose_cast<<<dim3(32,16,1), blk, 0, stream>>>(shd, shdT, 512, 1024);
  transpose_cast<<<dim3(8,32,32), blk, 0, stream>>>(wg, wgT, 1024, 256);
  transpose_cast<<<dim3(8,32,32), blk, 0, stream>>>(wu, wuT, 1024, 256);
  transpose_cast<<<dim3(32,8,32), blk, 0, stream>>>(wd, wdT, 256, 1024);

  // norm1 -> split h
  rmsnorm_kernel<<<2048, blk, 0, stream>>>(x, n1w, hH, hL, nullptr);
  // fused QKV projection (split): [2048 x 1536]  (R5-proven BM=64 config)
  gemm_kernel<true><<<dim3(24, 32), blk, 0, stream>>>(hH, hL, wqkvTh, wqkvTl, qkvf,
      nullptr, nullptr, nullptr, nullptr, 2048, 1536, 1024, 0);
  // RoPE + V transpose (V lo plane no longer consumed by attn)
  rope_split_kernel<<<4096, blk, 0, stream>>>(qkvf, 1536, 0,    fc, fs, qbh, qbl, 16);
  rope_split_kernel<<<1024, blk, 0, stream>>>(qkvf, 1536, 1024, fc, fs, kbh, kbl, 4);
  vtrans_split_kernel<<<2048, blk, 0, stream>>>(qkvf, 1536, 1280, vth, nullptr);
  // attention
  attn_kernel<<<dim3(16,16,2), blk, 0, stream>>>(qbh, qbl, kbh, kbl, vth, attnH, attnL);
  // output projection + residual
  gemm_kernel<true><<<dim3(16, 32), blk, 0, stream>>>(attnH, attnL, woTh, woTl, x1,
      x, nullptr, nullptr, nullptr, 2048, 1024, 1024, 0);
  // norm2 -> fp32 (router) + bf16 (experts)
  rmsnorm_kernel<<<2048, blk, 0, stream>>>(x1, n2w, h2b, nullptr, h2f);
  // router + grouping
  zero_counts<<<1, 64, 0, stream>>>(counts);
  router_kernel<<<256, blk, 0, stream>>>(h2f, rw, topIdx, topW, counts);
  scan_kernel<<<1, 64, 0, stream>>>(counts, offsets, cursor);
  scatter_kernel<<<32, blk, 0, stream>>>(topIdx, topW, cursor, rows, wtp, pslot);
  // shared MLP
  gemm_kernel<false><<<dim3(8, 32), blk, 0, stream>>>(h2b, nullptr, shgT, nullptr, sg,
      nullptr, nullptr, nullptr, nullptr, 2048, 512, 1024, 0);
  gemm_kernel<false><<<dim3(8, 32), blk, 0, stream>>>(h2b, nullptr, shuT, nullptr, su,
      nullptr, nullptr, nullptr, nullptr, 2048, 512, 1024, 0);
  silu_mul_kernel<<<4096, blk, 0, stream>>>(sg, su, nullptr, sactb, 2048*512);
  gemm_kernel<false><<<dim3(16, 32), blk, 0, stream>>>(sactb, nullptr, shdT, nullptr, shOut,
      nullptr, nullptr, nullptr, nullptr, 2048, 1024, 512, 0);
  // MoE expert GEMMs (grouped)
  gemm_kernel<false><<<dim3(4, 32, 32), blk, 0, stream>>>(h2b, nullptr, wgT, nullptr, pairG,
      nullptr, rows, counts, offsets, 0, 256, 1024, 256*1024);
  gemm_kernel<false><<<dim3(4, 32, 32), blk, 0, stream>>>(h2b, nullptr, wuT, nullptr, pairU,
      nullptr, rows, counts, offsets, 0, 256, 1024, 256*1024);
  silu_mul_kernel<<<8192, blk, 0, stream>>>(pairG, pairU, wtp, actb, 8192*256);
  gemm_kernel<false><<<dim3(16, 32, 32), blk, 0, stream>>>(actb, nullptr, wdT, nullptr, pairOut,
      nullptr, nullptr, counts, offsets, 0, 1024, 256, 1024*256);
  // final residual + combine
  final_kernel<<<2048, blk, 0, stream>>>(x1, shOut, pairOut, pslot, out);
}

// Round 9
// 348.132 us; speedup vs baseline: 2.0925x; 1.0885x over previous
//
#include <hip/hip_runtime.h>

typedef unsigned short u16;
typedef __attribute__((ext_vector_type(8))) short s8v;
typedef __attribute__((ext_vector_type(4))) float f4v;

#define DEV static __device__ __forceinline__

DEV u16 f2bf(float f) {
  union { float f; unsigned u; } v; v.f = f;
  unsigned r = v.u + 0x7FFFu + ((v.u >> 16) & 1u);
  return (u16)(r >> 16);
}
DEV float bf2f(u16 b) { union { unsigned u; float f; } v; v.u = ((unsigned)b) << 16; return v.f; }

DEV f4v mfma16(s8v a, s8v b, f4v c) {
  return __builtin_amdgcn_mfma_f32_16x16x32_bf16(a, b, c, 0, 0, 0);
}

// ---------------- transpose + cast ----------------
// in: [z][R][C] f32 -> out: [z (stride ozs)][C][R] bf16
// ozs lets two weight tensors interleave into one fused buffer (gate|up).
__global__ __launch_bounds__(256) void transpose_cast(const float* __restrict__ in,
                                                      u16* __restrict__ out, int R, int C,
                                                      long long ozs) {
  __shared__ float tile[32][33];
  int z = blockIdx.z;
  const float* inp = in + (size_t)z * R * C;
  u16* op = out + (size_t)z * ozs;
  int c0 = blockIdx.x * 32, r0 = blockIdx.y * 32;
  int tx = threadIdx.x & 31, ty = threadIdx.x >> 5;
  for (int i = ty; i < 32; i += 8) {
    int r = r0 + i, c = c0 + tx;
    tile[i][tx] = (r < R && c < C) ? inp[(size_t)r * C + c] : 0.f;
  }
  __syncthreads();
  for (int i = ty; i < 32; i += 8) {
    int c = c0 + i, r = r0 + tx;
    if (c < C && r < R) op[(size_t)c * R + r] = f2bf(tile[tx][i]);
  }
}

__global__ __launch_bounds__(256) void transpose_cast_split(const float* __restrict__ in,
                                                            u16* __restrict__ outH, u16* __restrict__ outL,
                                                            int R, int C) {
  __shared__ float tile[32][33];
  int z = blockIdx.z;
  const float* inp = in + (size_t)z * R * C;
  u16* oH = outH + (size_t)z * R * C;
  u16* oL = outL + (size_t)z * R * C;
  int c0 = blockIdx.x * 32, r0 = blockIdx.y * 32;
  int tx = threadIdx.x & 31, ty = threadIdx.x >> 5;
  for (int i = ty; i < 32; i += 8) {
    int r = r0 + i, c = c0 + tx;
    tile[i][tx] = (r < R && c < C) ? inp[(size_t)r * C + c] : 0.f;
  }
  __syncthreads();
  for (int i = ty; i < 32; i += 8) {
    int c = c0 + i, r = r0 + tx;
    if (c < C && r < R) {
      float f = tile[tx][i];
      u16 hi = f2bf(f);
      oH[(size_t)c * R + r] = hi;
      oL[(size_t)c * R + r] = f2bf(f - bf2f(hi));
    }
  }
}

// ---------------- rmsnorm ----------------
__global__ __launch_bounds__(256) void rmsnorm_kernel(const float* __restrict__ xin,
                                                      const float* __restrict__ w,
                                                      u16* __restrict__ outH, u16* __restrict__ outL,
                                                      float* __restrict__ outF) {
  int n = blockIdx.x;
  int t = threadIdx.x;
  const float* xr = xin + (size_t)n * 1024;
  float4 v = ((const float4*)xr)[t];
  float ss = v.x*v.x + v.y*v.y + v.z*v.z + v.w*v.w;
  #pragma unroll
  for (int o = 1; o < 64; o <<= 1) ss += __shfl_xor(ss, o, 64);
  __shared__ float wsum[4];
  if ((t & 63) == 0) wsum[t >> 6] = ss;
  __syncthreads();
  float tot = wsum[0] + wsum[1] + wsum[2] + wsum[3];
  float rs = rsqrtf(tot * (1.0f/1024.0f) + 1e-6f);
  float4 wv = ((const float4*)w)[t];
  float o0 = v.x*rs*wv.x, o1 = v.y*rs*wv.y, o2 = v.z*rs*wv.z, o3 = v.w*rs*wv.w;
  if (outF) {
    float4 of = {o0, o1, o2, o3};
    ((float4*)(outF + (size_t)n*1024))[t] = of;
  }
  u16 h0 = f2bf(o0), h1 = f2bf(o1), h2 = f2bf(o2), h3 = f2bf(o3);
  ushort4 oh = {h0, h1, h2, h3};
  ((ushort4*)(outH + (size_t)n*1024))[t] = oh;
  if (outL) {
    ushort4 ol = { f2bf(o0 - bf2f(h0)), f2bf(o1 - bf2f(h1)),
                   f2bf(o2 - bf2f(h2)), f2bf(o3 - bf2f(h3)) };
    ((ushort4*)(outL + (size_t)n*1024))[t] = ol;
  }
}

// ---------------- GEMM BM=64 (R5-proven): C[M][N] = A[M][K] x BT[N][K]^T ----------------
// Named-register T14 prefetch (NO arrays/lambdas in staging -> no scratch).
// BM=128 variant tried in R6/R7: scratch-spill disaster, then grid/occupancy
// regression (WO/shD fell to 1 block/CU). BM=64 is the proven config.
template <bool SPLIT>
__global__ __launch_bounds__(256) void gemm_kernel(
    const u16* __restrict__ Ah, const u16* __restrict__ Al,
    const u16* __restrict__ Bh, const u16* __restrict__ Bl,
    float* __restrict__ C, const float* __restrict__ resid,
    const int* __restrict__ rowIdx, const int* __restrict__ counts,
    const int* __restrict__ offsets,
    int M, int N, int K, int strideBTe) {
  int M_ = M;
  const int* rIdx = rowIdx;
  int aOff = 0;
  if (counts) {
    int e = blockIdx.z;
    M_ = counts[e];
    if ((int)blockIdx.y * 64 >= M_) return;
    aOff = offsets[e];
    Bh += (size_t)e * strideBTe;
    C += (size_t)aOff * N;
    if (rIdx) rIdx += aOff;
  }
  __shared__ u16 AtH[64*72];
  __shared__ u16 BtH[64*72];
  __shared__ u16 AtL[SPLIT ? 64*72 : 8];
  __shared__ u16 BtL[SPLIT ? 64*72 : 8];

  int tid = threadIdx.x;
  int wid = tid >> 6, lane = tid & 63;
  int lo16 = lane & 15, hi4 = lane >> 4;
  int m0 = blockIdx.y * 64, n0 = blockIdx.x * 64;
  int srow = tid >> 2, sseg = (tid & 3) * 16;

  int am = m0 + srow;
  int arow;
  if (counts) {
    int mm = (am < M_) ? am : (M_ - 1);
    arow = rIdx ? rIdx[mm] : (aOff + mm);
  } else {
    arow = am;
  }
  const u16* aPH = Ah + (size_t)arow * K;
  const u16* aPL = SPLIT ? (Al + (size_t)arow * K) : nullptr;
  const u16* bPH = Bh + (size_t)(n0 + srow) * K;
  const u16* bPL = SPLIT ? (Bl + (size_t)(n0 + srow) * K) : nullptr;

  uint4 a0r, a1r, b0r, b1r, al0r, al1r, bl0r, bl1r;
  #define GLOAD(kb) { \
    a0r = *(const uint4*)(aPH + (kb) + sseg); a1r = *(const uint4*)(aPH + (kb) + sseg + 8); \
    b0r = *(const uint4*)(bPH + (kb) + sseg); b1r = *(const uint4*)(bPH + (kb) + sseg + 8); \
    if constexpr (SPLIT) { \
      al0r = *(const uint4*)(aPL + (kb) + sseg); al1r = *(const uint4*)(aPL + (kb) + sseg + 8); \
      bl0r = *(const uint4*)(bPL + (kb) + sseg); bl1r = *(const uint4*)(bPL + (kb) + sseg + 8); \
    } }
  #define GSTORE() { \
    *(uint4*)&AtH[srow*72 + sseg] = a0r; *(uint4*)&AtH[srow*72 + sseg + 8] = a1r; \
    *(uint4*)&BtH[srow*72 + sseg] = b0r; *(uint4*)&BtH[srow*72 + sseg + 8] = b1r; \
    if constexpr (SPLIT) { \
      *(uint4*)&AtL[srow*72 + sseg] = al0r; *(uint4*)&AtL[srow*72 + sseg + 8] = al1r; \
      *(uint4*)&BtL[srow*72 + sseg] = bl0r; *(uint4*)&BtL[srow*72 + sseg + 8] = bl1r; \
    } }

  f4v acc[4];
  #pragma unroll
  for (int j = 0; j < 4; ++j) { acc[j][0]=0.f; acc[j][1]=0.f; acc[j][2]=0.f; acc[j][3]=0.f; }

  GLOAD(0); GSTORE();
  for (int kb = 0; kb < K; kb += 64) {
    __syncthreads();                  // staged tile visible
    if (kb + 64 < K) GLOAD(kb + 64);  // prefetch next tile under this tile's MFMAs
    int ar = wid*16 + lo16;
    s8v ah0 = *(const s8v*)&AtH[ar*72 + 8*hi4];
    s8v ah1 = *(const s8v*)&AtH[ar*72 + 32 + 8*hi4];
    s8v al0, al1;
    if constexpr (SPLIT) {
      al0 = *(const s8v*)&AtL[ar*72 + 8*hi4];
      al1 = *(const s8v*)&AtL[ar*72 + 32 + 8*hi4];
    }
    #pragma unroll
    for (int j = 0; j < 4; ++j) {
      int br = j*16 + lo16;
      s8v bh0 = *(const s8v*)&BtH[br*72 + 8*hi4];
      s8v bh1 = *(const s8v*)&BtH[br*72 + 32 + 8*hi4];
      acc[j] = mfma16(ah0, bh0, acc[j]);
      acc[j] = mfma16(ah1, bh1, acc[j]);
      if constexpr (SPLIT) {
        s8v bl0 = *(const s8v*)&BtL[br*72 + 8*hi4];
        s8v bl1 = *(const s8v*)&BtL[br*72 + 32 + 8*hi4];
        acc[j] = mfma16(ah0, bl0, acc[j]);
        acc[j] = mfma16(ah1, bl1, acc[j]);
        acc[j] = mfma16(al0, bh0, acc[j]);
        acc[j] = mfma16(al1, bh1, acc[j]);
      }
    }
    __syncthreads();                  // all waves done reading LDS
    if (kb + 64 < K) GSTORE();        // write next tile (vmcnt drained under MFMAs)
  }
  #undef GLOAD
  #undef GSTORE
  #pragma unroll
  for (int r = 0; r < 4; ++r) {
    int rg = m0 + wid*16 + 4*hi4 + r;
    if (rg < M_) {
      size_t rb = (size_t)rg * N;
      #pragma unroll
      for (int j = 0; j < 4; ++j) {
        int cg = n0 + j*16 + lo16;
        float v = acc[j][r];
        if (resid) v += resid[rb + cg];
        C[rb + cg] = v;
      }
    }
  }
}

// ---------------- RoPE (f32 -> split bf16, [b][NH][t][64] layout) ----------------
__global__ __launch_bounds__(256) void rope_split_kernel(const float* __restrict__ src, int ldsrc, int colOff,
                                                         const float* __restrict__ fc, const float* __restrict__ fs,
                                                         u16* __restrict__ outH, u16* __restrict__ outL, int NH) {
  int idx = blockIdx.x * 256 + threadIdx.x;
  int i = idx & 31; int tmp = idx >> 5;
  int hh = tmp % NH; int bt = tmp / NH;
  if (bt >= 2048) return;
  int t = bt & 1023, b = bt >> 10;
  const float* sp = src + (size_t)bt * ldsrc + colOff + hh*64 + 2*i;
  float a = sp[0], bb = sp[1];
  float c = fc[t*32 + i], s = fs[t*32 + i];
  float o0 = a*c - bb*s, o1 = a*s + bb*c;
  size_t o = (((size_t)(b*NH + hh))*1024 + t)*64 + 2*i;
  u16 h0 = f2bf(o0), h1 = f2bf(o1);
  outH[o] = h0; outH[o+1] = h1;
  outL[o] = f2bf(o0 - bf2f(h0)); outL[o+1] = f2bf(o1 - bf2f(h1));
}

// ---------------- V transpose (f32 -> bf16 hi, [b][kv][hd][t]) ----------------
__global__ __launch_bounds__(256) void vtrans_split_kernel(const float* __restrict__ src, int ldsrc, int colOff,
                                                           u16* __restrict__ outH, u16* __restrict__ outL) {
  int idx = blockIdx.x * 256 + threadIdx.x;
  if (idx >= 2*4*64*1024) return;
  int t = idx & 1023; int tmp = idx >> 10;
  int hd = tmp & 63; int kv = (tmp >> 6) & 3; int b = tmp >> 8;
  float f = src[(size_t)(b*1024 + t) * ldsrc + colOff + kv*64 + hd];
  u16 hi = f2bf(f);
  outH[idx] = hi;
  if (outL) outL[idx] = f2bf(f - bf2f(hi));
}

// ---------------- flash attention (causal, GQA, split-bf16 QK / bf16 PV) ----------------
// LDS-staged K/V; complement qb mapping for XCD causal balance; T14 async
// staging; base-2 softmax; diagonal-only masking; setprio around MFMA.
// PV lo-plane dropped (R8, verified: absmax unchanged at 0.03125).
__global__ __launch_bounds__(256) void attn_kernel(
    const u16* __restrict__ Qh, const u16* __restrict__ Ql,
    const u16* __restrict__ Kh_, const u16* __restrict__ Kl_,
    const u16* __restrict__ Vh_,
    u16* __restrict__ Oh, u16* __restrict__ Ol) {
  int b = blockIdx.z, h = blockIdx.y;
  int qb = (b == 0) ? (int)blockIdx.x : (15 - (int)blockIdx.x);
  int kv = h >> 2;
  size_t qoff = ((size_t)(b*16 + h)) * 65536;
  size_t koff = ((size_t)(b*4 + kv)) * 65536;

  __shared__ u16 KtH[64*72], KtL[64*72], VtH[64*72];
  __shared__ u16 PtH[4][16*72];

  int tid = threadIdx.x, wid = tid >> 6, lane = tid & 63;
  int lo16 = lane & 15, hi4 = lane >> 4;
  int srow = tid >> 2, sseg = (tid & 3) * 16;

  int qrow = qb*64 + wid*16 + lo16;
  const u16* qbh_ = Qh + qoff + (size_t)qrow*64;
  const u16* qbl_ = Ql + qoff + (size_t)qrow*64;
  s8v qh0 = *(const s8v*)(qbh_ + 8*hi4);
  s8v qh1 = *(const s8v*)(qbh_ + 32 + 8*hi4);
  s8v ql0 = *(const s8v*)(qbl_ + 8*hi4);
  s8v ql1 = *(const s8v*)(qbl_ + 32 + 8*hi4);

  const u16* Kh = Kh_ + koff;
  const u16* Kl = Kl_ + koff;
  const u16* Vh = Vh_ + koff;

  // one-tile-ahead register staging (named regs only)
  uint4 kh0r, kh1r, kl0r, kl1r, vh0r, vh1r;
  #define LOADT(kb) { \
    const u16* kh = Kh + (size_t)((kb)*64 + srow)*64 + sseg; \
    const u16* kl = Kl + (size_t)((kb)*64 + srow)*64 + sseg; \
    const u16* vh = Vh + (size_t)srow*1024 + (kb)*64 + sseg; \
    kh0r = *(const uint4*)(kh); kh1r = *(const uint4*)(kh + 8); \
    kl0r = *(const uint4*)(kl); kl1r = *(const uint4*)(kl + 8); \
    vh0r = *(const uint4*)(vh); vh1r = *(const uint4*)(vh + 8); }
  #define STORET() { \
    *(uint4*)&KtH[srow*72 + sseg]     = kh0r; *(uint4*)&KtH[srow*72 + sseg + 8] = kh1r; \
    *(uint4*)&KtL[srow*72 + sseg]     = kl0r; *(uint4*)&KtL[srow*72 + sseg + 8] = kl1r; \
    *(uint4*)&VtH[srow*72 + sseg]     = vh0r; *(uint4*)&VtH[srow*72 + sseg + 8] = vh1r; }

  f4v oacc[4];
  #pragma unroll
  for (int j = 0; j < 4; ++j) { oacc[j][0]=0.f; oacc[j][1]=0.f; oacc[j][2]=0.f; oacc[j][3]=0.f; }
  float mrow[4] = {-1e30f, -1e30f, -1e30f, -1e30f};
  float lrow[4] = {0.f, 0.f, 0.f, 0.f};
  int qmy = qb*64 + wid*16 + 4*hi4;
  u16* PwH = PtH[wid];

  // base-2 softmax: scores scaled by 1/sqrt(64)*log2(e); exp2f = 1 v_exp_f32
  const float SC = 0.125f * 1.44269504088896f;

  LOADT(0); STORET();
  for (int kblk = 0; kblk <= qb; ++kblk) {
    __syncthreads();                 // staged tile visible to all waves
    if (kblk < qb) LOADT(kblk + 1);  // prefetch next tile under this tile's compute

    // ---- S = Q K^T (full hi/lo split) ----
    f4v sfr[4];
    __builtin_amdgcn_s_setprio(1);
    #pragma unroll
    for (int j = 0; j < 4; ++j) {
      int kr = j*16 + lo16;
      s8v kh0 = *(const s8v*)&KtH[kr*72 + 8*hi4];
      s8v kh1 = *(const s8v*)&KtH[kr*72 + 32 + 8*hi4];
      s8v kl0 = *(const s8v*)&KtL[kr*72 + 8*hi4];
      s8v kl1 = *(const s8v*)&KtL[kr*72 + 32 + 8*hi4];
      f4v s; s[0]=0.f; s[1]=0.f; s[2]=0.f; s[3]=0.f;
      s = mfma16(qh0, kh0, s);
      s = mfma16(qh1, kh1, s);
      s = mfma16(qh0, kl0, s);
      s = mfma16(qh1, kl1, s);
      s = mfma16(ql0, kh0, s);
      s = mfma16(ql1, kh1, s);
      sfr[j] = s;
    }
    __builtin_amdgcn_s_setprio(0);

    // ---- online softmax (base-2); mask only the diagonal tile ----
    bool diag = (kblk == qb);
    float scl[4];
    #pragma unroll
    for (int r = 0; r < 4; ++r) {
      int qr = qmy + r;
      #pragma unroll
      for (int j = 0; j < 4; ++j) {
        float v = sfr[j][r] * SC;
        if (diag) {
          int kc = kblk*64 + j*16 + lo16;
          v = (kc > qr) ? -1e30f : v;
        }
        sfr[j][r] = v;
      }
      float mx = fmaxf(fmaxf(sfr[0][r], sfr[1][r]), fmaxf(sfr[2][r], sfr[3][r]));
      #pragma unroll
      for (int o = 1; o < 16; o <<= 1) mx = fmaxf(mx, __shfl_xor(mx, o, 64));
      float mnew = fmaxf(mrow[r], mx);
      scl[r] = exp2f(mrow[r] - mnew);
      mrow[r] = mnew;
      float sum = 0.f;
      #pragma unroll
      for (int j = 0; j < 4; ++j) {
        float pv = exp2f(sfr[j][r] - mnew);
        sfr[j][r] = pv;
        sum += pv;
      }
      #pragma unroll
      for (int o = 1; o < 16; o <<= 1) sum += __shfl_xor(sum, o, 64);
      lrow[r] = lrow[r] * scl[r] + sum;
    }
    #pragma unroll
    for (int j = 0; j < 4; ++j) {
      #pragma unroll
      for (int r = 0; r < 4; ++r) oacc[j][r] *= scl[r];
    }

    // ---- P transpose through per-wave LDS (hi plane only) ----
    #pragma unroll
    for (int r = 0; r < 4; ++r) {
      #pragma unroll
      for (int j = 0; j < 4; ++j) {
        PwH[(4*hi4 + r)*72 + j*16 + lo16] = f2bf(sfr[j][r]);
      }
    }
    asm volatile("s_waitcnt lgkmcnt(0)" ::: "memory");
    s8v ph0 = *(const s8v*)&PwH[lo16*72 + 8*hi4];
    s8v ph1 = *(const s8v*)&PwH[lo16*72 + 32 + 8*hi4];

    // ---- O += P V (hi x hi only) ----
    __builtin_amdgcn_s_setprio(1);
    #pragma unroll
    for (int j = 0; j < 4; ++j) {
      int vr = j*16 + lo16;
      s8v vh0 = *(const s8v*)&VtH[vr*72 + 8*hi4];
      s8v vh1 = *(const s8v*)&VtH[vr*72 + 32 + 8*hi4];
      oacc[j] = mfma16(ph0, vh0, oacc[j]);
      oacc[j] = mfma16(ph1, vh1, oacc[j]);
    }
    __builtin_amdgcn_s_setprio(0);

    __syncthreads();                 // all waves done reading K/V LDS
    if (kblk < qb) STORET();         // vmcnt mostly drained by now
  }
  #undef LOADT
  #undef STORET

  #pragma unroll
  for (int r = 0; r < 4; ++r) {
    float inv = 1.f / lrow[r];
    int tq = qb*64 + wid*16 + 4*hi4 + r;
    size_t base = ((size_t)(b*1024 + tq))*1024 + h*64;
    #pragma unroll
    for (int j = 0; j < 4; ++j) {
      float ov = oacc[j][r] * inv;
      u16 hi = f2bf(ov);
      Oh[base + j*16 + lo16] = hi;
      Ol[base + j*16 + lo16] = f2bf(ov - bf2f(hi));
    }
  }
}

// ---------------- router: logits(fp32) -> softmax -> top4 ----------------
// LDS-tiled: 256 blocks x 8 rows; h rows (32KB) + rw chunks (16KB) staged via
// coalesced float4; inner loop pure LDS+FMA (conflict-free). R4: 58 -> ~8us.
__global__ __launch_bounds__(256) void router_kernel(const float* __restrict__ h2,
                                                     const float* __restrict__ rw,
                                                     int* __restrict__ topIdx, float* __restrict__ topW,
                                                     int* __restrict__ counts) {
  __shared__ float hs[8*1024];    // 8 h rows
  __shared__ float rws[128*32];   // rw chunk [128 d][32 e]
  __shared__ int hist[32];
  int t = threadIdx.x;
  int row0 = blockIdx.x * 8;
  if (t < 32) hist[t] = 0;

  // stage 8 h rows: 2048 float4, coalesced
  {
    const float4* hsrc = (const float4*)(h2 + (size_t)row0 * 1024);
    float4* hdst = (float4*)hs;
    #pragma unroll
    for (int i = 0; i < 8; ++i) hdst[t + 256*i] = hsrc[t + 256*i];
  }

  int e = t & 31, rq = t >> 5;    // thread owns (row rq, expert e); 32-lane group = one row
  float acc = 0.f;
  for (int c = 0; c < 8; ++c) {
    __syncthreads();              // prev chunk fully consumed (and h staged, 1st iter)
    const float4* rsrc = (const float4*)(rw + (size_t)c * 4096);
    float4* rdst = (float4*)rws;
    #pragma unroll
    for (int i = 0; i < 4; ++i) rdst[t + 256*i] = rsrc[t + 256*i];
    __syncthreads();
    const float* hp = hs + rq*1024 + c*128;
    float b0 = 0.f, b1 = 0.f, b2 = 0.f, b3 = 0.f;
    #pragma unroll
    for (int d = 0; d < 128; d += 4) {
      b0 += hp[d+0] * rws[(d+0)*32 + e];
      b1 += hp[d+1] * rws[(d+1)*32 + e];
      b2 += hp[d+2] * rws[(d+2)*32 + e];
      b3 += hp[d+3] * rws[(d+3)*32 + e];
    }
    acc += (b0 + b1) + (b2 + b3);
  }

  // softmax over the 32-lane group (xor offsets <32 stay within the group)
  float mx = acc;
  #pragma unroll
  for (int o = 1; o < 32; o <<= 1) mx = fmaxf(mx, __shfl_xor(mx, o, 64));
  float ex = expf(acc - mx);
  float sm = ex;
  #pragma unroll
  for (int o = 1; o < 32; o <<= 1) sm += __shfl_xor(sm, o, 64);
  float prob = ex / sm;

  // top-4 within the group; tie -> smaller index (matches jax top_k)
  float pv = prob; int pi = e;
  int myRow = row0 + rq;
  for (int k = 0; k < 4; ++k) {
    float bv = pv; int bi = pi;
    #pragma unroll
    for (int o = 1; o < 32; o <<= 1) {
      float ov = __shfl_xor(bv, o, 64); int oi = __shfl_xor(bi, o, 64);
      if (ov > bv || (ov == bv && oi < bi)) { bv = ov; bi = oi; }
    }
    if (e == 0) {
      topIdx[myRow*4 + k] = bi; topW[myRow*4 + k] = bv;
      atomicAdd(&hist[bi], 1);   // LDS atomic
    }
    if (pi == bi) pv = -1.f;
  }
  __syncthreads();
  if (t < 32 && hist[t] > 0) atomicAdd(&counts[t], hist[t]);
}

__global__ void zero_counts(int* counts) { if (threadIdx.x < 32) counts[threadIdx.x] = 0; }

__global__ void scan_kernel(const int* __restrict__ counts, int* __restrict__ offsets, int* __restrict__ cursor) {
  if (threadIdx.x == 0) {
    int acc = 0;
    for (int e = 0; e < 32; ++e) { offsets[e] = acc; cursor[e] = acc; acc += counts[e]; }
    offsets[32] = acc;
  }
}

__global__ __launch_bounds__(256) void scatter_kernel(const int* __restrict__ topIdx, const float* __restrict__ topW,
                                                      int* __restrict__ cursor, int* __restrict__ rows,
                                                      float* __restrict__ wtp, int* __restrict__ pslot) {
  int i = blockIdx.x * 256 + threadIdx.x;
  if (i >= 2048*4) return;
  int e = topIdx[i];
  int slot = atomicAdd(&cursor[e], 1);
  rows[slot] = i >> 2;
  wtp[slot] = topW[i];
  pslot[i] = slot;
}

// ---------------- silu(g)*u from FUSED gate|up buffer -> bf16 ----------------
// gu: [slot][2*halfN] with g = cols [0,halfN), u = cols [halfN,2*halfN).
// lg = log2(halfN). wtp (optional) indexed per slot.
__global__ __launch_bounds__(256) void silu_mul_kernel(const float* __restrict__ gu,
                                                       const float* __restrict__ wtp,
                                                       u16* __restrict__ out, int lg, int total) {
  int i = blockIdx.x * 256 + threadIdx.x;
  if (i >= total) return;
  int halfN = 1 << lg;
  int slot = i >> lg, e = i & (halfN - 1);
  size_t base = (size_t)slot * (2*halfN);
  float gv = gu[base + e];
  float uv = gu[base + halfN + e];
  float s = gv / (1.f + expf(-gv));
  float r = s * uv;
  if (wtp) r *= wtp[slot];
  out[i] = f2bf(r);
}

// ---------------- final: out = x1 + shared + sum_k pairOut[slot_k] ----------------
__global__ __launch_bounds__(256) void final_kernel(const float* __restrict__ x1, const float* __restrict__ shOut,
                                                    const float* __restrict__ pairOut, const int* __restrict__ pslot,
                                                    float* __restrict__ out) {
  int n = blockIdx.x;
  int t = threadIdx.x;
  int s0 = pslot[n*4], s1 = pslot[n*4+1], s2 = pslot[n*4+2], s3 = pslot[n*4+3];
  float4 a  = ((const float4*)(x1 + (size_t)n*1024))[t];
  float4 sh = ((const float4*)(shOut + (size_t)n*1024))[t];
  float4 p0 = ((const float4*)(pairOut + (size_t)s0*1024))[t];
  float4 p1 = ((const float4*)(pairOut + (size_t)s1*1024))[t];
  float4 p2 = ((const float4*)(pairOut + (size_t)s2*1024))[t];
  float4 p3 = ((const float4*)(pairOut + (size_t)s3*1024))[t];
  float4 o;
  o.x = a.x + sh.x + p0.x + p1.x + p2.x + p3.x;
  o.y = a.y + sh.y + p0.y + p1.y + p2.y + p3.y;
  o.z = a.z + sh.z + p0.z + p1.z + p2.z + p3.z;
  o.w = a.w + sh.w + p0.w + p1.w + p2.w + p3.w;
  ((float4*)(out + (size_t)n*1024))[t] = o;
}

// ---------------- host ----------------
extern "C" void kernel_launch(void* const* d_in, const int* in_sizes, int n_in,
                              void* d_out, int out_size, void* d_ws, size_t ws_size,
                              hipStream_t stream) {
  const float* x   = (const float*)d_in[0];
  const float* fc  = (const float*)d_in[1];
  const float* fs  = (const float*)d_in[2];
  const float* n1w = (const float*)d_in[3];
  const float* n2w = (const float*)d_in[4];
  const float* wq  = (const float*)d_in[5];
  const float* wk  = (const float*)d_in[6];
  const float* wv  = (const float*)d_in[7];
  const float* wo  = (const float*)d_in[8];
  const float* rw  = (const float*)d_in[9];
  const float* wg  = (const float*)d_in[10];
  const float* wu  = (const float*)d_in[11];
  const float* wd  = (const float*)d_in[12];
  const float* shg = (const float*)d_in[13];
  const float* shu = (const float*)d_in[14];
  const float* shd = (const float*)d_in[15];
  float* out = (float*)d_out;
  (void)in_sizes; (void)n_in; (void)out_size;

  char* p = (char*)d_ws;
  auto alloc = [&](size_t n) { char* r = p; p += (n + 255) & ~(size_t)255; return r; };

  u16* wqkvTh = (u16*)alloc((size_t)1536*1024*2);
  u16* wqkvTl = (u16*)alloc((size_t)1536*1024*2);
  u16* woTh   = (u16*)alloc((size_t)1024*1024*2);
  u16* woTl   = (u16*)alloc((size_t)1024*1024*2);
  u16* shguT  = (u16*)alloc((size_t)1024*1024*2);   // fused [gate(512)|up(512)][1024]
  u16* shdT   = (u16*)alloc((size_t)1024*512*2);
  u16* wguT   = (u16*)alloc((size_t)32*512*1024*2); // fused per-expert [gate(256)|up(256)][1024]
  u16* wdT    = (u16*)alloc((size_t)32*1024*256*2);
  u16* hH     = (u16*)alloc((size_t)2048*1024*2);
  u16* hL     = (u16*)alloc((size_t)2048*1024*2);
  float* x1   = (float*)alloc((size_t)2048*1024*4);
  float* h2f  = (float*)alloc((size_t)2048*1024*4);
  u16* h2b    = (u16*)alloc((size_t)2048*1024*2);
  float* pairGU = (float*)alloc((size_t)8192*512*4); // fused g|u per slot
  u16* actb   = (u16*)alloc((size_t)8192*256*2);
  float* sgu  = (float*)alloc((size_t)2048*1024*4);  // fused g|u per row
  u16* sactb  = (u16*)alloc((size_t)2048*512*2);
  float* shOut = (float*)alloc((size_t)2048*1024*4);
  int* topIdx = (int*)alloc(2048*4*4);
  float* topW = (float*)alloc(2048*4*4);
  int* counts = (int*)alloc(32*4);
  int* offsets = (int*)alloc(33*4);
  int* cursor = (int*)alloc(32*4);
  int* rows   = (int*)alloc(8192*4);
  float* wtp  = (float*)alloc(8192*4);
  int* pslot  = (int*)alloc(8192*4);
  // alias region: qkv/rope/attention temporaries, later reused as pairOut
  char* regionStart = p;
  float* qkvf = (float*)alloc((size_t)2048*1536*4);
  u16* qbh = (u16*)alloc((size_t)2048*1024*2);
  u16* qbl = (u16*)alloc((size_t)2048*1024*2);
  u16* kbh = (u16*)alloc((size_t)524288*2);
  u16* kbl = (u16*)alloc((size_t)524288*2);
  u16* vth = (u16*)alloc((size_t)524288*2);
  u16* attnH = (u16*)alloc((size_t)2048*1024*2);
  u16* attnL = (u16*)alloc((size_t)2048*1024*2);
  float* pairOut = (float*)regionStart;  // 32MB, region is exactly 32MB

  size_t needed = (size_t)(p - (char*)d_ws);
  if (needed > ws_size) return;  // insufficient workspace; fail clean

  dim3 blk(256);
  // weight transposes (+bf16 cast; split for pre-router path).
  // gate/up pairs write interleaved into ONE fused buffer (halves A-traffic
  // and dispatch count of the downstream GEMMs; bit-identical numerics).
  transpose_cast_split<<<dim3(32,32,1), blk, 0, stream>>>(wq, wqkvTh, wqkvTl, 1024, 1024);
  transpose_cast_split<<<dim3(8,32,1),  blk, 0, stream>>>(wk, wqkvTh + (size_t)1024*1024, wqkvTl + (size_t)1024*1024, 1024, 256);
  transpose_cast_split<<<dim3(8,32,1),  blk, 0, stream>>>(wv, wqkvTh + (size_t)1280*1024, wqkvTl + (size_t)1280*1024, 1024, 256);
  transpose_cast_split<<<dim3(32,32,1), blk, 0, stream>>>(wo, woTh, woTl, 1024, 1024);
  transpose_cast<<<dim3(16,32,1), blk, 0, stream>>>(shg, shguT, 1024, 512, 512*1024);
  transpose_cast<<<dim3(16,32,1), blk, 0, stream>>>(shu, shguT + (size_t)512*1024, 1024, 512, 512*1024);
  transpose_cast<<<dim3(32,16,1), blk, 0, stream>>>(shd, shdT, 512, 1024, 512*1024);
  transpose_cast<<<dim3(8,32,32), blk, 0, stream>>>(wg, wguT, 1024, 256, 512*1024);
  transpose_cast<<<dim3(8,32,32), blk, 0, stream>>>(wu, wguT + (size_t)256*1024, 1024, 256, 512*1024);
  transpose_cast<<<dim3(32,8,32), blk, 0, stream>>>(wd, wdT, 256, 1024, 256*1024);

  // norm1 -> split h
  rmsnorm_kernel<<<2048, blk, 0, stream>>>(x, n1w, hH, hL, nullptr);
  // fused QKV projection (split): [2048 x 1536]
  gemm_kernel<true><<<dim3(24, 32), blk, 0, stream>>>(hH, hL, wqkvTh, wqkvTl, qkvf,
      nullptr, nullptr, nullptr, nullptr, 2048, 1536, 1024, 0);
  // RoPE + V transpose
  rope_split_kernel<<<4096, blk, 0, stream>>>(qkvf, 1536, 0,    fc, fs, qbh, qbl, 16);
  rope_split_kernel<<<1024, blk, 0, stream>>>(qkvf, 1536, 1024, fc, fs, kbh, kbl, 4);
  vtrans_split_kernel<<<2048, blk, 0, stream>>>(qkvf, 1536, 1280, vth, nullptr);
  // attention
  attn_kernel<<<dim3(16,16,2), blk, 0, stream>>>(qbh, qbl, kbh, kbl, vth, attnH, attnL);
  // output projection + residual
  gemm_kernel<true><<<dim3(16, 32), blk, 0, stream>>>(attnH, attnL, woTh, woTl, x1,
      x, nullptr, nullptr, nullptr, 2048, 1024, 1024, 0);
  // norm2 -> fp32 (router) + bf16 (experts)
  rmsnorm_kernel<<<2048, blk, 0, stream>>>(x1, n2w, h2b, nullptr, h2f);
  // router + grouping
  zero_counts<<<1, 64, 0, stream>>>(counts);
  router_kernel<<<256, blk, 0, stream>>>(h2f, rw, topIdx, topW, counts);
  scan_kernel<<<1, 64, 0, stream>>>(counts, offsets, cursor);
  scatter_kernel<<<32, blk, 0, stream>>>(topIdx, topW, cursor, rows, wtp, pslot);
  // shared MLP: ONE fused gate+up GEMM (N=1024), then silu from fused layout
  gemm_kernel<false><<<dim3(16, 32), blk, 0, stream>>>(h2b, nullptr, shguT, nullptr, sgu,
      nullptr, nullptr, nullptr, nullptr, 2048, 1024, 1024, 0);
  silu_mul_kernel<<<4096, blk, 0, stream>>>(sgu, nullptr, sactb, 9, 2048*512);
  gemm_kernel<false><<<dim3(16, 32), blk, 0, stream>>>(sactb, nullptr, shdT, nullptr, shOut,
      nullptr, nullptr, nullptr, nullptr, 2048, 1024, 512, 0);
  // MoE experts: ONE fused gate+up grouped GEMM (N=512), silu, down
  gemm_kernel<false><<<dim3(8, 32, 32), blk, 0, stream>>>(h2b, nullptr, wguT, nullptr, pairGU,
      nullptr, rows, counts, offsets, 0, 512, 1024, 512*1024);
  silu_mul_kernel<<<8192, blk, 0, stream>>>(pairGU, wtp, actb, 8, 8192*256);
  gemm_kernel<false><<<dim3(16, 32, 32), blk, 0, stream>>>(actb, nullptr, wdT, nullptr, pairOut,
      nullptr, nullptr, counts, offsets, 0, 1024, 256, 1024*256);
  // final residual + combine
  final_kernel<<<2048, blk, 0, stream>>>(x1, shOut, pairOut, pslot, out);
}

// Round 10
// 310.816 us; speedup vs baseline: 2.3437x; 1.1201x over previous
//
#include <hip/hip_runtime.h>

typedef unsigned short u16;
typedef _Float16 h8v __attribute__((ext_vector_type(8)));
typedef __attribute__((ext_vector_type(4))) float f4v;

#define DEV static __device__ __forceinline__

// f32 -> fp16 bits (RNE via hardware cvt)
DEV u16 f2h(float f) {
  union { _Float16 h; u16 u; } v; v.h = (_Float16)f; return v.u;
}
DEV u16 f2bf(float f) {  // kept for final attn output plane (consumed as bf16? no - fp16 now)
  union { float f; unsigned u; } v; v.f = f;
  unsigned r = v.u + 0x7FFFu + ((v.u >> 16) & 1u);
  return (u16)(r >> 16);
}

DEV f4v mfma16h(h8v a, h8v b, f4v c) {
  return __builtin_amdgcn_mfma_f32_16x16x32_f16(a, b, c, 0, 0, 0);
}

// ---------------- transpose + cast (f32 -> fp16) ----------------
// in: [z][R][C] f32 -> out: [z (stride ozs)][C][R] fp16
__global__ __launch_bounds__(256) void transpose_cast(const float* __restrict__ in,
                                                      u16* __restrict__ out, int R, int C,
                                                      long long ozs) {
  __shared__ float tile[32][33];
  int z = blockIdx.z;
  const float* inp = in + (size_t)z * R * C;
  u16* op = out + (size_t)z * ozs;
  int c0 = blockIdx.x * 32, r0 = blockIdx.y * 32;
  int tx = threadIdx.x & 31, ty = threadIdx.x >> 5;
  for (int i = ty; i < 32; i += 8) {
    int r = r0 + i, c = c0 + tx;
    tile[i][tx] = (r < R && c < C) ? inp[(size_t)r * C + c] : 0.f;
  }
  __syncthreads();
  for (int i = ty; i < 32; i += 8) {
    int c = c0 + i, r = r0 + tx;
    if (c < C && r < R) op[(size_t)c * R + r] = f2h(tile[tx][i]);
  }
}

// ---------------- rmsnorm (f32 in -> fp16 out [+ optional f32 out]) ----------------
__global__ __launch_bounds__(256) void rmsnorm_kernel(const float* __restrict__ xin,
                                                      const float* __restrict__ w,
                                                      u16* __restrict__ outH,
                                                      float* __restrict__ outF) {
  int n = blockIdx.x;
  int t = threadIdx.x;
  const float* xr = xin + (size_t)n * 1024;
  float4 v = ((const float4*)xr)[t];
  float ss = v.x*v.x + v.y*v.y + v.z*v.z + v.w*v.w;
  #pragma unroll
  for (int o = 1; o < 64; o <<= 1) ss += __shfl_xor(ss, o, 64);
  __shared__ float wsum[4];
  if ((t & 63) == 0) wsum[t >> 6] = ss;
  __syncthreads();
  float tot = wsum[0] + wsum[1] + wsum[2] + wsum[3];
  float rs = rsqrtf(tot * (1.0f/1024.0f) + 1e-6f);
  float4 wv = ((const float4*)w)[t];
  float o0 = v.x*rs*wv.x, o1 = v.y*rs*wv.y, o2 = v.z*rs*wv.z, o3 = v.w*rs*wv.w;
  if (outF) {
    float4 of = {o0, o1, o2, o3};
    ((float4*)(outF + (size_t)n*1024))[t] = of;
  }
  ushort4 oh = { f2h(o0), f2h(o1), f2h(o2), f2h(o3) };
  ((ushort4*)(outH + (size_t)n*1024))[t] = oh;
}

// ---------------- GEMM BM=64 (R5-proven structure, fp16): C = A x BT^T ----------------
// fp16 inputs (2^-11 rel error, vs split-bf16's 6 MFMAs for 2^-17): 2 MFMAs/j.
// Named-register T14 prefetch (NO arrays/lambdas in staging -> no scratch).
__global__ __launch_bounds__(256) void gemm_kernel(
    const u16* __restrict__ Ah,
    const u16* __restrict__ Bh,
    float* __restrict__ C, const float* __restrict__ resid,
    const int* __restrict__ rowIdx, const int* __restrict__ counts,
    const int* __restrict__ offsets,
    int M, int N, int K, int strideBTe) {
  int M_ = M;
  const int* rIdx = rowIdx;
  int aOff = 0;
  if (counts) {
    int e = blockIdx.z;
    M_ = counts[e];
    if ((int)blockIdx.y * 64 >= M_) return;
    aOff = offsets[e];
    Bh += (size_t)e * strideBTe;
    C += (size_t)aOff * N;
    if (rIdx) rIdx += aOff;
  }
  __shared__ u16 AtH[64*72];
  __shared__ u16 BtH[64*72];

  int tid = threadIdx.x;
  int wid = tid >> 6, lane = tid & 63;
  int lo16 = lane & 15, hi4 = lane >> 4;
  int m0 = blockIdx.y * 64, n0 = blockIdx.x * 64;
  int srow = tid >> 2, sseg = (tid & 3) * 16;

  int am = m0 + srow;
  int arow;
  if (counts) {
    int mm = (am < M_) ? am : (M_ - 1);
    arow = rIdx ? rIdx[mm] : (aOff + mm);
  } else {
    arow = am;
  }
  const u16* aPH = Ah + (size_t)arow * K;
  const u16* bPH = Bh + (size_t)(n0 + srow) * K;

  uint4 a0r, a1r, b0r, b1r;
  #define GLOAD(kb) { \
    a0r = *(const uint4*)(aPH + (kb) + sseg); a1r = *(const uint4*)(aPH + (kb) + sseg + 8); \
    b0r = *(const uint4*)(bPH + (kb) + sseg); b1r = *(const uint4*)(bPH + (kb) + sseg + 8); }
  #define GSTORE() { \
    *(uint4*)&AtH[srow*72 + sseg] = a0r; *(uint4*)&AtH[srow*72 + sseg + 8] = a1r; \
    *(uint4*)&BtH[srow*72 + sseg] = b0r; *(uint4*)&BtH[srow*72 + sseg + 8] = b1r; }

  f4v acc[4];
  #pragma unroll
  for (int j = 0; j < 4; ++j) { acc[j][0]=0.f; acc[j][1]=0.f; acc[j][2]=0.f; acc[j][3]=0.f; }

  GLOAD(0); GSTORE();
  for (int kb = 0; kb < K; kb += 64) {
    __syncthreads();                  // staged tile visible
    if (kb + 64 < K) GLOAD(kb + 64);  // prefetch next tile under this tile's MFMAs
    int ar = wid*16 + lo16;
    h8v ah0 = *(const h8v*)&AtH[ar*72 + 8*hi4];
    h8v ah1 = *(const h8v*)&AtH[ar*72 + 32 + 8*hi4];
    #pragma unroll
    for (int j = 0; j < 4; ++j) {
      int br = j*16 + lo16;
      h8v bh0 = *(const h8v*)&BtH[br*72 + 8*hi4];
      h8v bh1 = *(const h8v*)&BtH[br*72 + 32 + 8*hi4];
      acc[j] = mfma16h(ah0, bh0, acc[j]);
      acc[j] = mfma16h(ah1, bh1, acc[j]);
    }
    __syncthreads();                  // all waves done reading LDS
    if (kb + 64 < K) GSTORE();        // write next tile (vmcnt drained under MFMAs)
  }
  #undef GLOAD
  #undef GSTORE
  #pragma unroll
  for (int r = 0; r < 4; ++r) {
    int rg = m0 + wid*16 + 4*hi4 + r;
    if (rg < M_) {
      size_t rb = (size_t)rg * N;
      #pragma unroll
      for (int j = 0; j < 4; ++j) {
        int cg = n0 + j*16 + lo16;
        float v = acc[j][r];
        if (resid) v += resid[rb + cg];
        C[rb + cg] = v;
      }
    }
  }
}

// ---------------- RoPE (f32 -> fp16, [b][NH][t][64] layout) ----------------
__global__ __launch_bounds__(256) void rope_kernel(const float* __restrict__ src, int ldsrc, int colOff,
                                                   const float* __restrict__ fc, const float* __restrict__ fs,
                                                   u16* __restrict__ outH, int NH) {
  int idx = blockIdx.x * 256 + threadIdx.x;
  int i = idx & 31; int tmp = idx >> 5;
  int hh = tmp % NH; int bt = tmp / NH;
  if (bt >= 2048) return;
  int t = bt & 1023, b = bt >> 10;
  const float* sp = src + (size_t)bt * ldsrc + colOff + hh*64 + 2*i;
  float a = sp[0], bb = sp[1];
  float c = fc[t*32 + i], s = fs[t*32 + i];
  float o0 = a*c - bb*s, o1 = a*s + bb*c;
  size_t o = (((size_t)(b*NH + hh))*1024 + t)*64 + 2*i;
  outH[o] = f2h(o0); outH[o+1] = f2h(o1);
}

// ---------------- V transpose (f32 -> fp16, [b][kv][hd][t]) ----------------
__global__ __launch_bounds__(256) void vtrans_kernel(const float* __restrict__ src, int ldsrc, int colOff,
                                                     u16* __restrict__ outH) {
  int idx = blockIdx.x * 256 + threadIdx.x;
  if (idx >= 2*4*64*1024) return;
  int t = idx & 1023; int tmp = idx >> 10;
  int hd = tmp & 63; int kv = (tmp >> 6) & 3; int b = tmp >> 8;
  float f = src[(size_t)(b*1024 + t) * ldsrc + colOff + kv*64 + hd];
  outH[idx] = f2h(f);
}

// ---------------- flash attention (causal, GQA, fp16) ----------------
// LDS-staged K/V; complement qb mapping for XCD causal balance; T14 async
// staging; base-2 softmax; diagonal-only masking; setprio around MFMA.
// fp16 Q/K/V/P: QK = 2 MFMAs (was 6 split-bf16), PV = 2; K-lo plane gone
// (LDS 36864 -> 27648, staging traffic -1/3).
__global__ __launch_bounds__(256) void attn_kernel(
    const u16* __restrict__ Qh,
    const u16* __restrict__ Kh_,
    const u16* __restrict__ Vh_,
    u16* __restrict__ Oh) {
  int b = blockIdx.z, h = blockIdx.y;
  int qb = (b == 0) ? (int)blockIdx.x : (15 - (int)blockIdx.x);
  int kv = h >> 2;
  size_t qoff = ((size_t)(b*16 + h)) * 65536;
  size_t koff = ((size_t)(b*4 + kv)) * 65536;

  __shared__ u16 KtH[64*72], VtH[64*72];
  __shared__ u16 PtH[4][16*72];

  int tid = threadIdx.x, wid = tid >> 6, lane = tid & 63;
  int lo16 = lane & 15, hi4 = lane >> 4;
  int srow = tid >> 2, sseg = (tid & 3) * 16;

  int qrow = qb*64 + wid*16 + lo16;
  const u16* qbh_ = Qh + qoff + (size_t)qrow*64;
  h8v qh0 = *(const h8v*)(qbh_ + 8*hi4);
  h8v qh1 = *(const h8v*)(qbh_ + 32 + 8*hi4);

  const u16* Kh = Kh_ + koff;
  const u16* Vh = Vh_ + koff;

  // one-tile-ahead register staging (named regs only)
  uint4 kh0r, kh1r, vh0r, vh1r;
  #define LOADT(kb) { \
    const u16* kh = Kh + (size_t)((kb)*64 + srow)*64 + sseg; \
    const u16* vh = Vh + (size_t)srow*1024 + (kb)*64 + sseg; \
    kh0r = *(const uint4*)(kh); kh1r = *(const uint4*)(kh + 8); \
    vh0r = *(const uint4*)(vh); vh1r = *(const uint4*)(vh + 8); }
  #define STORET() { \
    *(uint4*)&KtH[srow*72 + sseg]     = kh0r; *(uint4*)&KtH[srow*72 + sseg + 8] = kh1r; \
    *(uint4*)&VtH[srow*72 + sseg]     = vh0r; *(uint4*)&VtH[srow*72 + sseg + 8] = vh1r; }

  f4v oacc[4];
  #pragma unroll
  for (int j = 0; j < 4; ++j) { oacc[j][0]=0.f; oacc[j][1]=0.f; oacc[j][2]=0.f; oacc[j][3]=0.f; }
  float mrow[4] = {-1e30f, -1e30f, -1e30f, -1e30f};
  float lrow[4] = {0.f, 0.f, 0.f, 0.f};
  int qmy = qb*64 + wid*16 + 4*hi4;
  u16* PwH = PtH[wid];

  // base-2 softmax: scores scaled by 1/sqrt(64)*log2(e); exp2f = 1 v_exp_f32
  const float SC = 0.125f * 1.44269504088896f;

  LOADT(0); STORET();
  for (int kblk = 0; kblk <= qb; ++kblk) {
    __syncthreads();                 // staged tile visible to all waves
    if (kblk < qb) LOADT(kblk + 1);  // prefetch next tile under this tile's compute

    // ---- S = Q K^T ----
    f4v sfr[4];
    __builtin_amdgcn_s_setprio(1);
    #pragma unroll
    for (int j = 0; j < 4; ++j) {
      int kr = j*16 + lo16;
      h8v kh0 = *(const h8v*)&KtH[kr*72 + 8*hi4];
      h8v kh1 = *(const h8v*)&KtH[kr*72 + 32 + 8*hi4];
      f4v s; s[0]=0.f; s[1]=0.f; s[2]=0.f; s[3]=0.f;
      s = mfma16h(qh0, kh0, s);
      s = mfma16h(qh1, kh1, s);
      sfr[j] = s;
    }
    __builtin_amdgcn_s_setprio(0);

    // ---- online softmax (base-2); mask only the diagonal tile ----
    bool diag = (kblk == qb);
    float scl[4];
    #pragma unroll
    for (int r = 0; r < 4; ++r) {
      int qr = qmy + r;
      #pragma unroll
      for (int j = 0; j < 4; ++j) {
        float v = sfr[j][r] * SC;
        if (diag) {
          int kc = kblk*64 + j*16 + lo16;
          v = (kc > qr) ? -1e30f : v;
        }
        sfr[j][r] = v;
      }
      float mx = fmaxf(fmaxf(sfr[0][r], sfr[1][r]), fmaxf(sfr[2][r], sfr[3][r]));
      #pragma unroll
      for (int o = 1; o < 16; o <<= 1) mx = fmaxf(mx, __shfl_xor(mx, o, 64));
      float mnew = fmaxf(mrow[r], mx);
      scl[r] = exp2f(mrow[r] - mnew);
      mrow[r] = mnew;
      float sum = 0.f;
      #pragma unroll
      for (int j = 0; j < 4; ++j) {
        float pv = exp2f(sfr[j][r] - mnew);
        sfr[j][r] = pv;
        sum += pv;
      }
      #pragma unroll
      for (int o = 1; o < 16; o <<= 1) sum += __shfl_xor(sum, o, 64);
      lrow[r] = lrow[r] * scl[r] + sum;
    }
    #pragma unroll
    for (int j = 0; j < 4; ++j) {
      #pragma unroll
      for (int r = 0; r < 4; ++r) oacc[j][r] *= scl[r];
    }

    // ---- P transpose through per-wave LDS (fp16) ----
    #pragma unroll
    for (int r = 0; r < 4; ++r) {
      #pragma unroll
      for (int j = 0; j < 4; ++j) {
        PwH[(4*hi4 + r)*72 + j*16 + lo16] = f2h(sfr[j][r]);
      }
    }
    asm volatile("s_waitcnt lgkmcnt(0)" ::: "memory");
    h8v ph0 = *(const h8v*)&PwH[lo16*72 + 8*hi4];
    h8v ph1 = *(const h8v*)&PwH[lo16*72 + 32 + 8*hi4];

    // ---- O += P V ----
    __builtin_amdgcn_s_setprio(1);
    #pragma unroll
    for (int j = 0; j < 4; ++j) {
      int vr = j*16 + lo16;
      h8v vh0 = *(const h8v*)&VtH[vr*72 + 8*hi4];
      h8v vh1 = *(const h8v*)&VtH[vr*72 + 32 + 8*hi4];
      oacc[j] = mfma16h(ph0, vh0, oacc[j]);
      oacc[j] = mfma16h(ph1, vh1, oacc[j]);
    }
    __builtin_amdgcn_s_setprio(0);

    __syncthreads();                 // all waves done reading K/V LDS
    if (kblk < qb) STORET();         // vmcnt mostly drained by now
  }
  #undef LOADT
  #undef STORET

  #pragma unroll
  for (int r = 0; r < 4; ++r) {
    float inv = 1.f / lrow[r];
    int tq = qb*64 + wid*16 + 4*hi4 + r;
    size_t base = ((size_t)(b*1024 + tq))*1024 + h*64;
    #pragma unroll
    for (int j = 0; j < 4; ++j) {
      Oh[base + j*16 + lo16] = f2h(oacc[j][r] * inv);
    }
  }
}

// ---------------- router: logits(fp32) -> softmax -> top4 ----------------
// LDS-tiled: 256 blocks x 8 rows; h rows (32KB) + rw chunks (16KB) staged via
// coalesced float4; inner loop pure LDS+FMA (conflict-free). R4: 58 -> ~8us.
__global__ __launch_bounds__(256) void router_kernel(const float* __restrict__ h2,
                                                     const float* __restrict__ rw,
                                                     int* __restrict__ topIdx, float* __restrict__ topW,
                                                     int* __restrict__ counts) {
  __shared__ float hs[8*1024];    // 8 h rows
  __shared__ float rws[128*32];   // rw chunk [128 d][32 e]
  __shared__ int hist[32];
  int t = threadIdx.x;
  int row0 = blockIdx.x * 8;
  if (t < 32) hist[t] = 0;

  {
    const float4* hsrc = (const float4*)(h2 + (size_t)row0 * 1024);
    float4* hdst = (float4*)hs;
    #pragma unroll
    for (int i = 0; i < 8; ++i) hdst[t + 256*i] = hsrc[t + 256*i];
  }

  int e = t & 31, rq = t >> 5;
  float acc = 0.f;
  for (int c = 0; c < 8; ++c) {
    __syncthreads();
    const float4* rsrc = (const float4*)(rw + (size_t)c * 4096);
    float4* rdst = (float4*)rws;
    #pragma unroll
    for (int i = 0; i < 4; ++i) rdst[t + 256*i] = rsrc[t + 256*i];
    __syncthreads();
    const float* hp = hs + rq*1024 + c*128;
    float b0 = 0.f, b1 = 0.f, b2 = 0.f, b3 = 0.f;
    #pragma unroll
    for (int d = 0; d < 128; d += 4) {
      b0 += hp[d+0] * rws[(d+0)*32 + e];
      b1 += hp[d+1] * rws[(d+1)*32 + e];
      b2 += hp[d+2] * rws[(d+2)*32 + e];
      b3 += hp[d+3] * rws[(d+3)*32 + e];
    }
    acc += (b0 + b1) + (b2 + b3);
  }

  float mx = acc;
  #pragma unroll
  for (int o = 1; o < 32; o <<= 1) mx = fmaxf(mx, __shfl_xor(mx, o, 64));
  float ex = expf(acc - mx);
  float sm = ex;
  #pragma unroll
  for (int o = 1; o < 32; o <<= 1) sm += __shfl_xor(sm, o, 64);
  float prob = ex / sm;

  float pv = prob; int pi = e;
  int myRow = row0 + rq;
  for (int k = 0; k < 4; ++k) {
    float bv = pv; int bi = pi;
    #pragma unroll
    for (int o = 1; o < 32; o <<= 1) {
      float ov = __shfl_xor(bv, o, 64); int oi = __shfl_xor(bi, o, 64);
      if (ov > bv || (ov == bv && oi < bi)) { bv = ov; bi = oi; }
    }
    if (e == 0) {
      topIdx[myRow*4 + k] = bi; topW[myRow*4 + k] = bv;
      atomicAdd(&hist[bi], 1);
    }
    if (pi == bi) pv = -1.f;
  }
  __syncthreads();
  if (t < 32 && hist[t] > 0) atomicAdd(&counts[t], hist[t]);
}

__global__ void zero_counts(int* counts) { if (threadIdx.x < 32) counts[threadIdx.x] = 0; }

__global__ void scan_kernel(const int* __restrict__ counts, int* __restrict__ offsets, int* __restrict__ cursor) {
  if (threadIdx.x == 0) {
    int acc = 0;
    for (int e = 0; e < 32; ++e) { offsets[e] = acc; cursor[e] = acc; acc += counts[e]; }
    offsets[32] = acc;
  }
}

__global__ __launch_bounds__(256) void scatter_kernel(const int* __restrict__ topIdx, const float* __restrict__ topW,
                                                      int* __restrict__ cursor, int* __restrict__ rows,
                                                      float* __restrict__ wtp, int* __restrict__ pslot) {
  int i = blockIdx.x * 256 + threadIdx.x;
  if (i >= 2048*4) return;
  int e = topIdx[i];
  int slot = atomicAdd(&cursor[e], 1);
  rows[slot] = i >> 2;
  wtp[slot] = topW[i];
  pslot[i] = slot;
}

// ---------------- silu(g)*u from FUSED gate|up buffer -> fp16 ----------------
__global__ __launch_bounds__(256) void silu_mul_kernel(const float* __restrict__ gu,
                                                       const float* __restrict__ wtp,
                                                       u16* __restrict__ out, int lg, int total) {
  int i = blockIdx.x * 256 + threadIdx.x;
  if (i >= total) return;
  int halfN = 1 << lg;
  int slot = i >> lg, e = i & (halfN - 1);
  size_t base = (size_t)slot * (2*halfN);
  float gv = gu[base + e];
  float uv = gu[base + halfN + e];
  float s = gv / (1.f + expf(-gv));
  float r = s * uv;
  if (wtp) r *= wtp[slot];
  out[i] = f2h(r);
}

// ---------------- final: out = x1 + shared + sum_k pairOut[slot_k] ----------------
__global__ __launch_bounds__(256) void final_kernel(const float* __restrict__ x1, const float* __restrict__ shOut,
                                                    const float* __restrict__ pairOut, const int* __restrict__ pslot,
                                                    float* __restrict__ out) {
  int n = blockIdx.x;
  int t = threadIdx.x;
  int s0 = pslot[n*4], s1 = pslot[n*4+1], s2 = pslot[n*4+2], s3 = pslot[n*4+3];
  float4 a  = ((const float4*)(x1 + (size_t)n*1024))[t];
  float4 sh = ((const float4*)(shOut + (size_t)n*1024))[t];
  float4 p0 = ((const float4*)(pairOut + (size_t)s0*1024))[t];
  float4 p1 = ((const float4*)(pairOut + (size_t)s1*1024))[t];
  float4 p2 = ((const float4*)(pairOut + (size_t)s2*1024))[t];
  float4 p3 = ((const float4*)(pairOut + (size_t)s3*1024))[t];
  float4 o;
  o.x = a.x + sh.x + p0.x + p1.x + p2.x + p3.x;
  o.y = a.y + sh.y + p0.y + p1.y + p2.y + p3.y;
  o.z = a.z + sh.z + p0.z + p1.z + p2.z + p3.z;
  o.w = a.w + sh.w + p0.w + p1.w + p2.w + p3.w;
  ((float4*)(out + (size_t)n*1024))[t] = o;
}

// ---------------- host ----------------
extern "C" void kernel_launch(void* const* d_in, const int* in_sizes, int n_in,
                              void* d_out, int out_size, void* d_ws, size_t ws_size,
                              hipStream_t stream) {
  const float* x   = (const float*)d_in[0];
  const float* fc  = (const float*)d_in[1];
  const float* fs  = (const float*)d_in[2];
  const float* n1w = (const float*)d_in[3];
  const float* n2w = (const float*)d_in[4];
  const float* wq  = (const float*)d_in[5];
  const float* wk  = (const float*)d_in[6];
  const float* wv  = (const float*)d_in[7];
  const float* wo  = (const float*)d_in[8];
  const float* rw  = (const float*)d_in[9];
  const float* wg  = (const float*)d_in[10];
  const float* wu  = (const float*)d_in[11];
  const float* wd  = (const float*)d_in[12];
  const float* shg = (const float*)d_in[13];
  const float* shu = (const float*)d_in[14];
  const float* shd = (const float*)d_in[15];
  float* out = (float*)d_out;
  (void)in_sizes; (void)n_in; (void)out_size;

  char* p = (char*)d_ws;
  auto alloc = [&](size_t n) { char* r = p; p += (n + 255) & ~(size_t)255; return r; };

  u16* wqkvT  = (u16*)alloc((size_t)1536*1024*2);
  u16* woT    = (u16*)alloc((size_t)1024*1024*2);
  u16* shguT  = (u16*)alloc((size_t)1024*1024*2);   // fused [gate(512)|up(512)][1024]
  u16* shdT   = (u16*)alloc((size_t)1024*512*2);
  u16* wguT   = (u16*)alloc((size_t)32*512*1024*2); // fused per-expert [gate(256)|up(256)][1024]
  u16* wdT    = (u16*)alloc((size_t)32*1024*256*2);
  u16* hH     = (u16*)alloc((size_t)2048*1024*2);
  float* x1   = (float*)alloc((size_t)2048*1024*4);
  float* h2f  = (float*)alloc((size_t)2048*1024*4);
  u16* h2b    = (u16*)alloc((size_t)2048*1024*2);
  float* pairGU = (float*)alloc((size_t)8192*512*4); // fused g|u per slot
  u16* actb   = (u16*)alloc((size_t)8192*256*2);
  float* sgu  = (float*)alloc((size_t)2048*1024*4);  // fused g|u per row
  u16* sactb  = (u16*)alloc((size_t)2048*512*2);
  float* shOut = (float*)alloc((size_t)2048*1024*4);
  int* topIdx = (int*)alloc(2048*4*4);
  float* topW = (float*)alloc(2048*4*4);
  int* counts = (int*)alloc(32*4);
  int* offsets = (int*)alloc(33*4);
  int* cursor = (int*)alloc(32*4);
  int* rows   = (int*)alloc(8192*4);
  float* wtp  = (float*)alloc(8192*4);
  int* pslot  = (int*)alloc(8192*4);
  // alias region: qkv/rope/attention temporaries, later reused as pairOut
  char* regionStart = p;
  float* qkvf = (float*)alloc((size_t)2048*1536*4);
  u16* qbh = (u16*)alloc((size_t)2048*1024*2);
  u16* kbh = (u16*)alloc((size_t)524288*2);
  u16* vth = (u16*)alloc((size_t)524288*2);
  u16* attnH = (u16*)alloc((size_t)2048*1024*2);
  float* pairOut = (float*)regionStart;
  // pairOut (8192*1024*4 = 32MB) must fit inside/after the region
  {
    size_t regionBytes = (size_t)8192*1024*4;
    if ((size_t)(p - regionStart) < regionBytes) p = regionStart + regionBytes;
  }

  size_t needed = (size_t)(p - (char*)d_ws);
  if (needed > ws_size) return;  // insufficient workspace; fail clean

  dim3 blk(256);
  // weight transposes (+fp16 cast); gate/up pairs interleave into ONE fused buffer
  transpose_cast<<<dim3(32,32,1), blk, 0, stream>>>(wq, wqkvT, 1024, 1024, 0);
  transpose_cast<<<dim3(8,32,1),  blk, 0, stream>>>(wk, wqkvT + (size_t)1024*1024, 1024, 256, 0);
  transpose_cast<<<dim3(8,32,1),  blk, 0, stream>>>(wv, wqkvT + (size_t)1280*1024, 1024, 256, 0);
  transpose_cast<<<dim3(32,32,1), blk, 0, stream>>>(wo, woT, 1024, 1024, 0);
  transpose_cast<<<dim3(16,32,1), blk, 0, stream>>>(shg, shguT, 1024, 512, 0);
  transpose_cast<<<dim3(16,32,1), blk, 0, stream>>>(shu, shguT + (size_t)512*1024, 1024, 512, 0);
  transpose_cast<<<dim3(32,16,1), blk, 0, stream>>>(shd, shdT, 512, 1024, 0);
  transpose_cast<<<dim3(8,32,32), blk, 0, stream>>>(wg, wguT, 1024, 256, 512*1024);
  transpose_cast<<<dim3(8,32,32), blk, 0, stream>>>(wu, wguT + (size_t)256*1024, 1024, 256, 512*1024);
  transpose_cast<<<dim3(32,8,32), blk, 0, stream>>>(wd, wdT, 256, 1024, 256*1024);

  // norm1 -> fp16 h
  rmsnorm_kernel<<<2048, blk, 0, stream>>>(x, n1w, hH, nullptr);
  // fused QKV projection: [2048 x 1536]
  gemm_kernel<<<dim3(24, 32), blk, 0, stream>>>(hH, wqkvT, qkvf,
      nullptr, nullptr, nullptr, nullptr, 2048, 1536, 1024, 0);
  // RoPE + V transpose
  rope_kernel<<<4096, blk, 0, stream>>>(qkvf, 1536, 0,    fc, fs, qbh, 16);
  rope_kernel<<<1024, blk, 0, stream>>>(qkvf, 1536, 1024, fc, fs, kbh, 4);
  vtrans_kernel<<<2048, blk, 0, stream>>>(qkvf, 1536, 1280, vth);
  // attention
  attn_kernel<<<dim3(16,16,2), blk, 0, stream>>>(qbh, kbh, vth, attnH);
  // output projection + residual
  gemm_kernel<<<dim3(16, 32), blk, 0, stream>>>(attnH, woT, x1,
      x, nullptr, nullptr, nullptr, 2048, 1024, 1024, 0);
  // norm2 -> fp32 (router) + fp16 (experts)
  rmsnorm_kernel<<<2048, blk, 0, stream>>>(x1, n2w, h2b, h2f);
  // router + grouping
  zero_counts<<<1, 64, 0, stream>>>(counts);
  router_kernel<<<256, blk, 0, stream>>>(h2f, rw, topIdx, topW, counts);
  scan_kernel<<<1, 64, 0, stream>>>(counts, offsets, cursor);
  scatter_kernel<<<32, blk, 0, stream>>>(topIdx, topW, cursor, rows, wtp, pslot);
  // shared MLP: ONE fused gate+up GEMM (N=1024), silu, down
  gemm_kernel<<<dim3(16, 32), blk, 0, stream>>>(h2b, shguT, sgu,
      nullptr, nullptr, nullptr, nullptr, 2048, 1024, 1024, 0);
  silu_mul_kernel<<<4096, blk, 0, stream>>>(sgu, nullptr, sactb, 9, 2048*512);
  gemm_kernel<<<dim3(16, 32), blk, 0, stream>>>(sactb, shdT, shOut,
      nullptr, nullptr, nullptr, nullptr, 2048, 1024, 512, 0);
  // MoE experts: ONE fused gate+up grouped GEMM (N=512), silu, down
  gemm_kernel<<<dim3(8, 32, 32), blk, 0, stream>>>(h2b, wguT, pairGU,
      nullptr, rows, counts, offsets, 0, 512, 1024, 512*1024);
  silu_mul_kernel<<<8192, blk, 0, stream>>>(pairGU, wtp, actb, 8, 8192*256);
  gemm_kernel<<<dim3(16, 32, 32), blk, 0, stream>>>(actb, wdT, pairOut,
      nullptr, nullptr, counts, offsets, 0, 1024, 256, 1024*256);
  // final residual + combine
  final_kernel<<<2048, blk, 0, stream>>>(x1, shOut, pairOut, pslot, out);
}

// Round 11
// 306.450 us; speedup vs baseline: 2.3771x; 1.0142x over previous
//
#include <hip/hip_runtime.h>

typedef unsigned short u16;
typedef _Float16 h8v __attribute__((ext_vector_type(8)));
typedef __attribute__((ext_vector_type(4))) float f4v;

#define DEV static __device__ __forceinline__

// f32 -> fp16 bits (RNE via hardware cvt)
DEV u16 f2h(float f) {
  union { _Float16 h; u16 u; } v; v.h = (_Float16)f; return v.u;
}

DEV f4v mfma16h(h8v a, h8v b, f4v c) {
  return __builtin_amdgcn_mfma_f32_16x16x32_f16(a, b, c, 0, 0, 0);
}

// ---------------- transpose + cast (f32 -> fp16) ----------------
// in: [z][R][C] f32 -> out: [z (stride ozs)][C][R] fp16
__global__ __launch_bounds__(256) void transpose_cast(const float* __restrict__ in,
                                                      u16* __restrict__ out, int R, int C,
                                                      long long ozs) {
  __shared__ float tile[32][33];
  int z = blockIdx.z;
  const float* inp = in + (size_t)z * R * C;
  u16* op = out + (size_t)z * ozs;
  int c0 = blockIdx.x * 32, r0 = blockIdx.y * 32;
  int tx = threadIdx.x & 31, ty = threadIdx.x >> 5;
  for (int i = ty; i < 32; i += 8) {
    int r = r0 + i, c = c0 + tx;
    tile[i][tx] = (r < R && c < C) ? inp[(size_t)r * C + c] : 0.f;
  }
  __syncthreads();
  for (int i = ty; i < 32; i += 8) {
    int c = c0 + i, r = r0 + tx;
    if (c < C && r < R) op[(size_t)c * R + r] = f2h(tile[tx][i]);
  }
}

// ---------------- rmsnorm (f32 in -> fp16 out [+ optional f32 out]) ----------------
__global__ __launch_bounds__(256) void rmsnorm_kernel(const float* __restrict__ xin,
                                                      const float* __restrict__ w,
                                                      u16* __restrict__ outH,
                                                      float* __restrict__ outF) {
  int n = blockIdx.x;
  int t = threadIdx.x;
  const float* xr = xin + (size_t)n * 1024;
  float4 v = ((const float4*)xr)[t];
  float ss = v.x*v.x + v.y*v.y + v.z*v.z + v.w*v.w;
  #pragma unroll
  for (int o = 1; o < 64; o <<= 1) ss += __shfl_xor(ss, o, 64);
  __shared__ float wsum[4];
  if ((t & 63) == 0) wsum[t >> 6] = ss;
  __syncthreads();
  float tot = wsum[0] + wsum[1] + wsum[2] + wsum[3];
  float rs = rsqrtf(tot * (1.0f/1024.0f) + 1e-6f);
  float4 wv = ((const float4*)w)[t];
  float o0 = v.x*rs*wv.x, o1 = v.y*rs*wv.y, o2 = v.z*rs*wv.z, o3 = v.w*rs*wv.w;
  if (outF) {
    float4 of = {o0, o1, o2, o3};
    ((float4*)(outF + (size_t)n*1024))[t] = of;
  }
  ushort4 oh = { f2h(o0), f2h(o1), f2h(o2), f2h(o3) };
  ((ushort4*)(outH + (size_t)n*1024))[t] = oh;
}

// ---------------- GEMM BM=64 (R5-proven structure, fp16): C = A x BT^T ----------------
// Named-register T14 prefetch (NO arrays/lambdas in staging -> no scratch).
__global__ __launch_bounds__(256) void gemm_kernel(
    const u16* __restrict__ Ah,
    const u16* __restrict__ Bh,
    float* __restrict__ C, const float* __restrict__ resid,
    const int* __restrict__ rowIdx, const int* __restrict__ counts,
    const int* __restrict__ offsets,
    int M, int N, int K, int strideBTe) {
  int M_ = M;
  const int* rIdx = rowIdx;
  int aOff = 0;
  if (counts) {
    int e = blockIdx.z;
    M_ = counts[e];
    if ((int)blockIdx.y * 64 >= M_) return;
    aOff = offsets[e];
    Bh += (size_t)e * strideBTe;
    C += (size_t)aOff * N;
    if (rIdx) rIdx += aOff;
  }
  __shared__ u16 AtH[64*72];
  __shared__ u16 BtH[64*72];

  int tid = threadIdx.x;
  int wid = tid >> 6, lane = tid & 63;
  int lo16 = lane & 15, hi4 = lane >> 4;
  int m0 = blockIdx.y * 64, n0 = blockIdx.x * 64;
  int srow = tid >> 2, sseg = (tid & 3) * 16;

  int am = m0 + srow;
  int arow;
  if (counts) {
    int mm = (am < M_) ? am : (M_ - 1);
    arow = rIdx ? rIdx[mm] : (aOff + mm);
  } else {
    arow = am;
  }
  const u16* aPH = Ah + (size_t)arow * K;
  const u16* bPH = Bh + (size_t)(n0 + srow) * K;

  uint4 a0r, a1r, b0r, b1r;
  #define GLOAD(kb) { \
    a0r = *(const uint4*)(aPH + (kb) + sseg); a1r = *(const uint4*)(aPH + (kb) + sseg + 8); \
    b0r = *(const uint4*)(bPH + (kb) + sseg); b1r = *(const uint4*)(bPH + (kb) + sseg + 8); }
  #define GSTORE() { \
    *(uint4*)&AtH[srow*72 + sseg] = a0r; *(uint4*)&AtH[srow*72 + sseg + 8] = a1r; \
    *(uint4*)&BtH[srow*72 + sseg] = b0r; *(uint4*)&BtH[srow*72 + sseg + 8] = b1r; }

  f4v acc[4];
  #pragma unroll
  for (int j = 0; j < 4; ++j) { acc[j][0]=0.f; acc[j][1]=0.f; acc[j][2]=0.f; acc[j][3]=0.f; }

  GLOAD(0); GSTORE();
  for (int kb = 0; kb < K; kb += 64) {
    __syncthreads();                  // staged tile visible
    if (kb + 64 < K) GLOAD(kb + 64);  // prefetch next tile under this tile's MFMAs
    int ar = wid*16 + lo16;
    h8v ah0 = *(const h8v*)&AtH[ar*72 + 8*hi4];
    h8v ah1 = *(const h8v*)&AtH[ar*72 + 32 + 8*hi4];
    #pragma unroll
    for (int j = 0; j < 4; ++j) {
      int br = j*16 + lo16;
      h8v bh0 = *(const h8v*)&BtH[br*72 + 8*hi4];
      h8v bh1 = *(const h8v*)&BtH[br*72 + 32 + 8*hi4];
      acc[j] = mfma16h(ah0, bh0, acc[j]);
      acc[j] = mfma16h(ah1, bh1, acc[j]);
    }
    __syncthreads();                  // all waves done reading LDS
    if (kb + 64 < K) GSTORE();        // write next tile (vmcnt drained under MFMAs)
  }
  #undef GLOAD
  #undef GSTORE
  #pragma unroll
  for (int r = 0; r < 4; ++r) {
    int rg = m0 + wid*16 + 4*hi4 + r;
    if (rg < M_) {
      size_t rb = (size_t)rg * N;
      #pragma unroll
      for (int j = 0; j < 4; ++j) {
        int cg = n0 + j*16 + lo16;
        float v = acc[j][r];
        if (resid) v += resid[rb + cg];
        C[rb + cg] = v;
      }
    }
  }
}

// ---------------- fused RoPE(Q) + RoPE(K) + V-transpose ----------------
// blockIdx partition: [0,4096) rope Q, [4096,5120) rope K, [5120,7168) vtrans.
__global__ __launch_bounds__(256) void rope_vtrans_kernel(
    const float* __restrict__ src,
    const float* __restrict__ fc, const float* __restrict__ fs,
    u16* __restrict__ qOut, u16* __restrict__ kOut, u16* __restrict__ vOut) {
  int blk = blockIdx.x;
  if (blk < 5120) {
    // RoPE: Q (NH=16, colOff 0) or K (NH=4, colOff 1024)
    int NH, colOff; u16* outH; int base;
    if (blk < 4096) { NH = 16; colOff = 0; outH = qOut; base = blk; }
    else            { NH = 4;  colOff = 1024; outH = kOut; base = blk - 4096; }
    int idx = base * 256 + threadIdx.x;
    int i = idx & 31; int tmp = idx >> 5;
    int hh = tmp % NH; int bt = tmp / NH;
    if (bt >= 2048) return;
    int t = bt & 1023, b = bt >> 10;
    const float* sp = src + (size_t)bt * 1536 + colOff + hh*64 + 2*i;
    float a = sp[0], bb = sp[1];
    float c = fc[t*32 + i], s = fs[t*32 + i];
    float o0 = a*c - bb*s, o1 = a*s + bb*c;
    size_t o = (((size_t)(b*NH + hh))*1024 + t)*64 + 2*i;
    outH[o] = f2h(o0); outH[o+1] = f2h(o1);
  } else {
    // V transpose: [b][kv][hd][t]
    int idx = (blk - 5120) * 256 + threadIdx.x;
    if (idx >= 2*4*64*1024) return;
    int t = idx & 1023; int tmp = idx >> 10;
    int hd = tmp & 63; int kv = (tmp >> 6) & 3; int b = tmp >> 8;
    float f = src[(size_t)(b*1024 + t) * 1536 + 1280 + kv*64 + hd];
    vOut[idx] = f2h(f);
  }
}

// ---------------- flash attention (causal, GQA, fp16) ----------------
// LDS-staged K/V; complement qb mapping for XCD causal balance; T14 async
// staging; base-2 softmax; diagonal-only masking; setprio around MFMA.
__global__ __launch_bounds__(256) void attn_kernel(
    const u16* __restrict__ Qh,
    const u16* __restrict__ Kh_,
    const u16* __restrict__ Vh_,
    u16* __restrict__ Oh) {
  int b = blockIdx.z, h = blockIdx.y;
  int qb = (b == 0) ? (int)blockIdx.x : (15 - (int)blockIdx.x);
  int kv = h >> 2;
  size_t qoff = ((size_t)(b*16 + h)) * 65536;
  size_t koff = ((size_t)(b*4 + kv)) * 65536;

  __shared__ u16 KtH[64*72], VtH[64*72];
  __shared__ u16 PtH[4][16*72];

  int tid = threadIdx.x, wid = tid >> 6, lane = tid & 63;
  int lo16 = lane & 15, hi4 = lane >> 4;
  int srow = tid >> 2, sseg = (tid & 3) * 16;

  int qrow = qb*64 + wid*16 + lo16;
  const u16* qbh_ = Qh + qoff + (size_t)qrow*64;
  h8v qh0 = *(const h8v*)(qbh_ + 8*hi4);
  h8v qh1 = *(const h8v*)(qbh_ + 32 + 8*hi4);

  const u16* Kh = Kh_ + koff;
  const u16* Vh = Vh_ + koff;

  uint4 kh0r, kh1r, vh0r, vh1r;
  #define LOADT(kb) { \
    const u16* kh = Kh + (size_t)((kb)*64 + srow)*64 + sseg; \
    const u16* vh = Vh + (size_t)srow*1024 + (kb)*64 + sseg; \
    kh0r = *(const uint4*)(kh); kh1r = *(const uint4*)(kh + 8); \
    vh0r = *(const uint4*)(vh); vh1r = *(const uint4*)(vh + 8); }
  #define STORET() { \
    *(uint4*)&KtH[srow*72 + sseg]     = kh0r; *(uint4*)&KtH[srow*72 + sseg + 8] = kh1r; \
    *(uint4*)&VtH[srow*72 + sseg]     = vh0r; *(uint4*)&VtH[srow*72 + sseg + 8] = vh1r; }

  f4v oacc[4];
  #pragma unroll
  for (int j = 0; j < 4; ++j) { oacc[j][0]=0.f; oacc[j][1]=0.f; oacc[j][2]=0.f; oacc[j][3]=0.f; }
  float mrow[4] = {-1e30f, -1e30f, -1e30f, -1e30f};
  float lrow[4] = {0.f, 0.f, 0.f, 0.f};
  int qmy = qb*64 + wid*16 + 4*hi4;
  u16* PwH = PtH[wid];

  const float SC = 0.125f * 1.44269504088896f;

  LOADT(0); STORET();
  for (int kblk = 0; kblk <= qb; ++kblk) {
    __syncthreads();
    if (kblk < qb) LOADT(kblk + 1);

    // ---- S = Q K^T ----
    f4v sfr[4];
    __builtin_amdgcn_s_setprio(1);
    #pragma unroll
    for (int j = 0; j < 4; ++j) {
      int kr = j*16 + lo16;
      h8v kh0 = *(const h8v*)&KtH[kr*72 + 8*hi4];
      h8v kh1 = *(const h8v*)&KtH[kr*72 + 32 + 8*hi4];
      f4v s; s[0]=0.f; s[1]=0.f; s[2]=0.f; s[3]=0.f;
      s = mfma16h(qh0, kh0, s);
      s = mfma16h(qh1, kh1, s);
      sfr[j] = s;
    }
    __builtin_amdgcn_s_setprio(0);

    // ---- online softmax (base-2); diagonal-only masking ----
    bool diag = (kblk == qb);
    float scl[4];
    #pragma unroll
    for (int r = 0; r < 4; ++r) {
      int qr = qmy + r;
      #pragma unroll
      for (int j = 0; j < 4; ++j) {
        float v = sfr[j][r] * SC;
        if (diag) {
          int kc = kblk*64 + j*16 + lo16;
          v = (kc > qr) ? -1e30f : v;
        }
        sfr[j][r] = v;
      }
      float mx = fmaxf(fmaxf(sfr[0][r], sfr[1][r]), fmaxf(sfr[2][r], sfr[3][r]));
      #pragma unroll
      for (int o = 1; o < 16; o <<= 1) mx = fmaxf(mx, __shfl_xor(mx, o, 64));
      float mnew = fmaxf(mrow[r], mx);
      scl[r] = exp2f(mrow[r] - mnew);
      mrow[r] = mnew;
      float sum = 0.f;
      #pragma unroll
      for (int j = 0; j < 4; ++j) {
        float pv = exp2f(sfr[j][r] - mnew);
        sfr[j][r] = pv;
        sum += pv;
      }
      #pragma unroll
      for (int o = 1; o < 16; o <<= 1) sum += __shfl_xor(sum, o, 64);
      lrow[r] = lrow[r] * scl[r] + sum;
    }
    #pragma unroll
    for (int j = 0; j < 4; ++j) {
      #pragma unroll
      for (int r = 0; r < 4; ++r) oacc[j][r] *= scl[r];
    }

    // ---- P transpose through per-wave LDS ----
    #pragma unroll
    for (int r = 0; r < 4; ++r) {
      #pragma unroll
      for (int j = 0; j < 4; ++j) {
        PwH[(4*hi4 + r)*72 + j*16 + lo16] = f2h(sfr[j][r]);
      }
    }
    asm volatile("s_waitcnt lgkmcnt(0)" ::: "memory");
    h8v ph0 = *(const h8v*)&PwH[lo16*72 + 8*hi4];
    h8v ph1 = *(const h8v*)&PwH[lo16*72 + 32 + 8*hi4];

    // ---- O += P V ----
    __builtin_amdgcn_s_setprio(1);
    #pragma unroll
    for (int j = 0; j < 4; ++j) {
      int vr = j*16 + lo16;
      h8v vh0 = *(const h8v*)&VtH[vr*72 + 8*hi4];
      h8v vh1 = *(const h8v*)&VtH[vr*72 + 32 + 8*hi4];
      oacc[j] = mfma16h(ph0, vh0, oacc[j]);
      oacc[j] = mfma16h(ph1, vh1, oacc[j]);
    }
    __builtin_amdgcn_s_setprio(0);

    __syncthreads();
    if (kblk < qb) STORET();
  }
  #undef LOADT
  #undef STORET

  #pragma unroll
  for (int r = 0; r < 4; ++r) {
    float inv = 1.f / lrow[r];
    int tq = qb*64 + wid*16 + 4*hi4 + r;
    size_t base = ((size_t)(b*1024 + tq))*1024 + h*64;
    #pragma unroll
    for (int j = 0; j < 4; ++j) {
      Oh[base + j*16 + lo16] = f2h(oacc[j][r] * inv);
    }
  }
}

// ---------------- router: logits(fp32) -> softmax -> top4 ----------------
// R11 rewrite: the old 8-rows/block mapping fixed total waves at 4/CU
// (grid 256 = 1 block/CU, zero TLP; measured 38us at VALUBusy 7%).
// Now d-SPLIT: each row computed by 4 groups (256-d quarter each), combined
// via shfl_xor(32) + 4x32 LDS patch. Block = 256 thr = 2 rows, grid = 1024
// -> 4 blocks/CU, 16 waves/CU. rw read DIRECT from L2 (128KB, cache-resident;
// lanes e=0..31 at fixed d = contiguous 128B, coalesced). No rw staging, no
// chunk barriers. Logits fp32; comparator unchanged (tie -> smaller index).
__global__ __launch_bounds__(256) void router_kernel(const float* __restrict__ h2,
                                                     const float* __restrict__ rw,
                                                     int* __restrict__ topIdx, float* __restrict__ topW,
                                                     int* __restrict__ counts) {
  __shared__ float hs[2][1024];
  __shared__ float part[4][32];
  __shared__ int hist[32];
  int t = threadIdx.x;
  int row0 = blockIdx.x * 2;
  if (t < 32) hist[t] = 0;

  // stage 2 h rows: 512 float4 over 256 threads = 2 each
  {
    const float4* hsrc = (const float4*)(h2 + (size_t)row0 * 1024);
    float4* hdst = (float4*)&hs[0][0];
    hdst[t] = hsrc[t];
    hdst[t + 256] = hsrc[t + 256];
  }
  __syncthreads();

  int e = t & 31, g = t >> 5;       // 8 groups of 32 lanes
  int r = g >> 2, q = g & 3;        // row (0/1), d-quarter (0..3)
  const float* hp = &hs[r][q*256];  // LDS broadcast reads
  const float* rp = rw + (size_t)(q*256)*32 + e;  // global, coalesced per d
  float b0 = 0.f, b1 = 0.f, b2 = 0.f, b3 = 0.f;
  #pragma unroll 16
  for (int d = 0; d < 256; d += 4) {
    b0 += hp[d+0] * rp[(d+0)*32];
    b1 += hp[d+1] * rp[(d+1)*32];
    b2 += hp[d+2] * rp[(d+2)*32];
    b3 += hp[d+3] * rp[(d+3)*32];
  }
  float pq = (b0 + b1) + (b2 + b3);
  pq += __shfl_xor(pq, 32, 64);     // combine the wave's two quarters
  int w = t >> 6;                   // wave 0..3
  if ((t & 63) < 32) part[w][e] = pq;
  __syncthreads();

  // wave 0 -> row 0, wave 2 -> row 1 (lanes 0-31 of each)
  if ((w & 1) == 0 && (t & 63) < 32) {
    float lg = part[w][e] + part[w+1][e];
    float mx = lg;
    #pragma unroll
    for (int o = 1; o < 32; o <<= 1) mx = fmaxf(mx, __shfl_xor(mx, o, 64));
    float ex = expf(lg - mx);
    float sm = ex;
    #pragma unroll
    for (int o = 1; o < 32; o <<= 1) sm += __shfl_xor(sm, o, 64);
    float prob = ex / sm;

    float pv = prob; int pi = e;
    int myRow = row0 + (w >> 1);
    for (int k = 0; k < 4; ++k) {
      float bv = pv; int bi = pi;
      #pragma unroll
      for (int o = 1; o < 32; o <<= 1) {
        float ov = __shfl_xor(bv, o, 64); int oi = __shfl_xor(bi, o, 64);
        if (ov > bv || (ov == bv && oi < bi)) { bv = ov; bi = oi; }
      }
      if (e == 0) {
        topIdx[myRow*4 + k] = bi; topW[myRow*4 + k] = bv;
        atomicAdd(&hist[bi], 1);
      }
      if (pi == bi) pv = -1.f;
    }
  }
  __syncthreads();
  if (t < 32 && hist[t] > 0) atomicAdd(&counts[t], hist[t]);
}

__global__ void zero_counts(int* counts) { if (threadIdx.x < 32) counts[threadIdx.x] = 0; }

__global__ void scan_kernel(const int* __restrict__ counts, int* __restrict__ offsets, int* __restrict__ cursor) {
  if (threadIdx.x == 0) {
    int acc = 0;
    for (int e = 0; e < 32; ++e) { offsets[e] = acc; cursor[e] = acc; acc += counts[e]; }
    offsets[32] = acc;
  }
}

__global__ __launch_bounds__(256) void scatter_kernel(const int* __restrict__ topIdx, const float* __restrict__ topW,
                                                      int* __restrict__ cursor, int* __restrict__ rows,
                                                      float* __restrict__ wtp, int* __restrict__ pslot) {
  int i = blockIdx.x * 256 + threadIdx.x;
  if (i >= 2048*4) return;
  int e = topIdx[i];
  int slot = atomicAdd(&cursor[e], 1);
  rows[slot] = i >> 2;
  wtp[slot] = topW[i];
  pslot[i] = slot;
}

// ---------------- silu(g)*u from FUSED gate|up buffer -> fp16 ----------------
__global__ __launch_bounds__(256) void silu_mul_kernel(const float* __restrict__ gu,
                                                       const float* __restrict__ wtp,
                                                       u16* __restrict__ out, int lg, int total) {
  int i = blockIdx.x * 256 + threadIdx.x;
  if (i >= total) return;
  int halfN = 1 << lg;
  int slot = i >> lg, e = i & (halfN - 1);
  size_t base = (size_t)slot * (2*halfN);
  float gv = gu[base + e];
  float uv = gu[base + halfN + e];
  float s = gv / (1.f + expf(-gv));
  float r = s * uv;
  if (wtp) r *= wtp[slot];
  out[i] = f2h(r);
}

// ---------------- final: out = x1 + shared + sum_k pairOut[slot_k] ----------------
__global__ __launch_bounds__(256) void final_kernel(const float* __restrict__ x1, const float* __restrict__ shOut,
                                                    const float* __restrict__ pairOut, const int* __restrict__ pslot,
                                                    float* __restrict__ out) {
  int n = blockIdx.x;
  int t = threadIdx.x;
  int s0 = pslot[n*4], s1 = pslot[n*4+1], s2 = pslot[n*4+2], s3 = pslot[n*4+3];
  float4 a  = ((const float4*)(x1 + (size_t)n*1024))[t];
  float4 sh = ((const float4*)(shOut + (size_t)n*1024))[t];
  float4 p0 = ((const float4*)(pairOut + (size_t)s0*1024))[t];
  float4 p1 = ((const float4*)(pairOut + (size_t)s1*1024))[t];
  float4 p2 = ((const float4*)(pairOut + (size_t)s2*1024))[t];
  float4 p3 = ((const float4*)(pairOut + (size_t)s3*1024))[t];
  float4 o;
  o.x = a.x + sh.x + p0.x + p1.x + p2.x + p3.x;
  o.y = a.y + sh.y + p0.y + p1.y + p2.y + p3.y;
  o.z = a.z + sh.z + p0.z + p1.z + p2.z + p3.z;
  o.w = a.w + sh.w + p0.w + p1.w + p2.w + p3.w;
  ((float4*)(out + (size_t)n*1024))[t] = o;
}

// ---------------- host ----------------
extern "C" void kernel_launch(void* const* d_in, const int* in_sizes, int n_in,
                              void* d_out, int out_size, void* d_ws, size_t ws_size,
                              hipStream_t stream) {
  const float* x   = (const float*)d_in[0];
  const float* fc  = (const float*)d_in[1];
  const float* fs  = (const float*)d_in[2];
  const float* n1w = (const float*)d_in[3];
  const float* n2w = (const float*)d_in[4];
  const float* wq  = (const float*)d_in[5];
  const float* wk  = (const float*)d_in[6];
  const float* wv  = (const float*)d_in[7];
  const float* wo  = (const float*)d_in[8];
  const float* rw  = (const float*)d_in[9];
  const float* wg  = (const float*)d_in[10];
  const float* wu  = (const float*)d_in[11];
  const float* wd  = (const float*)d_in[12];
  const float* shg = (const float*)d_in[13];
  const float* shu = (const float*)d_in[14];
  const float* shd = (const float*)d_in[15];
  float* out = (float*)d_out;
  (void)in_sizes; (void)n_in; (void)out_size;

  char* p = (char*)d_ws;
  auto alloc = [&](size_t n) { char* r = p; p += (n + 255) & ~(size_t)255; return r; };

  u16* wqkvT  = (u16*)alloc((size_t)1536*1024*2);
  u16* woT    = (u16*)alloc((size_t)1024*1024*2);
  u16* shguT  = (u16*)alloc((size_t)1024*1024*2);   // fused [gate(512)|up(512)][1024]
  u16* shdT   = (u16*)alloc((size_t)1024*512*2);
  u16* wguT   = (u16*)alloc((size_t)32*512*1024*2); // fused per-expert [gate(256)|up(256)][1024]
  u16* wdT    = (u16*)alloc((size_t)32*1024*256*2);
  u16* hH     = (u16*)alloc((size_t)2048*1024*2);
  float* x1   = (float*)alloc((size_t)2048*1024*4);
  float* h2f  = (float*)alloc((size_t)2048*1024*4);
  u16* h2b    = (u16*)alloc((size_t)2048*1024*2);
  float* pairGU = (float*)alloc((size_t)8192*512*4); // fused g|u per slot
  u16* actb   = (u16*)alloc((size_t)8192*256*2);
  float* sgu  = (float*)alloc((size_t)2048*1024*4);  // fused g|u per row
  u16* sactb  = (u16*)alloc((size_t)2048*512*2);
  float* shOut = (float*)alloc((size_t)2048*1024*4);
  int* topIdx = (int*)alloc(2048*4*4);
  float* topW = (float*)alloc(2048*4*4);
  int* counts = (int*)alloc(32*4);
  int* offsets = (int*)alloc(33*4);
  int* cursor = (int*)alloc(32*4);
  int* rows   = (int*)alloc(8192*4);
  float* wtp  = (float*)alloc(8192*4);
  int* pslot  = (int*)alloc(8192*4);
  // alias region: qkv/rope/attention temporaries, later reused as pairOut
  char* regionStart = p;
  float* qkvf = (float*)alloc((size_t)2048*1536*4);
  u16* qbh = (u16*)alloc((size_t)2048*1024*2);
  u16* kbh = (u16*)alloc((size_t)524288*2);
  u16* vth = (u16*)alloc((size_t)524288*2);
  u16* attnH = (u16*)alloc((size_t)2048*1024*2);
  float* pairOut = (float*)regionStart;
  // pairOut (8192*1024*4 = 32MB) must fit inside/after the region
  {
    size_t regionBytes = (size_t)8192*1024*4;
    if ((size_t)(p - regionStart) < regionBytes) p = regionStart + regionBytes;
  }

  size_t needed = (size_t)(p - (char*)d_ws);
  if (needed > ws_size) return;  // insufficient workspace; fail clean

  dim3 blk(256);
  // weight transposes (+fp16 cast); gate/up pairs interleave into ONE fused buffer
  transpose_cast<<<dim3(32,32,1), blk, 0, stream>>>(wq, wqkvT, 1024, 1024, 0);
  transpose_cast<<<dim3(8,32,1),  blk, 0, stream>>>(wk, wqkvT + (size_t)1024*1024, 1024, 256, 0);
  transpose_cast<<<dim3(8,32,1),  blk, 0, stream>>>(wv, wqkvT + (size_t)1280*1024, 1024, 256, 0);
  transpose_cast<<<dim3(32,32,1), blk, 0, stream>>>(wo, woT, 1024, 1024, 0);
  transpose_cast<<<dim3(16,32,1), blk, 0, stream>>>(shg, shguT, 1024, 512, 0);
  transpose_cast<<<dim3(16,32,1), blk, 0, stream>>>(shu, shguT + (size_t)512*1024, 1024, 512, 0);
  transpose_cast<<<dim3(32,16,1), blk, 0, stream>>>(shd, shdT, 512, 1024, 0);
  transpose_cast<<<dim3(8,32,32), blk, 0, stream>>>(wg, wguT, 1024, 256, 512*1024);
  transpose_cast<<<dim3(8,32,32), blk, 0, stream>>>(wu, wguT + (size_t)256*1024, 1024, 256, 512*1024);
  transpose_cast<<<dim3(32,8,32), blk, 0, stream>>>(wd, wdT, 256, 1024, 256*1024);

  // norm1 -> fp16 h
  rmsnorm_kernel<<<2048, blk, 0, stream>>>(x, n1w, hH, nullptr);
  // fused QKV projection: [2048 x 1536]
  gemm_kernel<<<dim3(24, 32), blk, 0, stream>>>(hH, wqkvT, qkvf,
      nullptr, nullptr, nullptr, nullptr, 2048, 1536, 1024, 0);
  // fused RoPE(Q) + RoPE(K) + V-transpose (one dispatch)
  rope_vtrans_kernel<<<7168, blk, 0, stream>>>(qkvf, fc, fs, qbh, kbh, vth);
  // attention
  attn_kernel<<<dim3(16,16,2), blk, 0, stream>>>(qbh, kbh, vth, attnH);
  // output projection + residual
  gemm_kernel<<<dim3(16, 32), blk, 0, stream>>>(attnH, woT, x1,
      x, nullptr, nullptr, nullptr, 2048, 1024, 1024, 0);
  // norm2 -> fp32 (router) + fp16 (experts)
  rmsnorm_kernel<<<2048, blk, 0, stream>>>(x1, n2w, h2b, h2f);
  // router + grouping
  zero_counts<<<1, 64, 0, stream>>>(counts);
  router_kernel<<<1024, blk, 0, stream>>>(h2f, rw, topIdx, topW, counts);
  scan_kernel<<<1, 64, 0, stream>>>(counts, offsets, cursor);
  scatter_kernel<<<32, blk, 0, stream>>>(topIdx, topW, cursor, rows, wtp, pslot);
  // shared MLP: ONE fused gate+up GEMM (N=1024), silu, down
  gemm_kernel<<<dim3(16, 32), blk, 0, stream>>>(h2b, shguT, sgu,
      nullptr, nullptr, nullptr, nullptr, 2048, 1024, 1024, 0);
  silu_mul_kernel<<<4096, blk, 0, stream>>>(sgu, nullptr, sactb, 9, 2048*512);
  gemm_kernel<<<dim3(16, 32), blk, 0, stream>>>(sactb, shdT, shOut,
      nullptr, nullptr, nullptr, nullptr, 2048, 1024, 512, 0);
  // MoE experts: ONE fused gate+up grouped GEMM (N=512), silu, down
  gemm_kernel<<<dim3(8, 32, 32), blk, 0, stream>>>(h2b, wguT, pairGU,
      nullptr, rows, counts, offsets, 0, 512, 1024, 512*1024);
  silu_mul_kernel<<<8192, blk, 0, stream>>>(pairGU, wtp, actb, 8, 8192*256);
  gemm_kernel<<<dim3(16, 32, 32), blk, 0, stream>>>(actb, wdT, pairOut,
      nullptr, nullptr, counts, offsets, 0, 1024, 256, 1024*256);
  // final residual + combine
  final_kernel<<<2048, blk, 0, stream>>>(x1, shOut, pairOut, pslot, out);
}